// Round 6
// baseline (25963.544 us; speedup 1.0000x reference)
//
#include <hip/hip_runtime.h>
#include <math.h>

// ---------------------------------------------------------------------------
// FraudGAT, memory-lean + MFMA projections (pre-transposed bf16 weights).
// bf16 activation storage, f32 softmax/BN. Same phase structure as the
// passing Round-4/5 kernels. Tiers TW=128/64/32; sentinel if nothing fits.
// ---------------------------------------------------------------------------

typedef unsigned short BF16;
typedef short short8 __attribute__((ext_vector_type(8)));
typedef float f32x4 __attribute__((ext_vector_type(4)));
typedef __bf16 bf16x8 __attribute__((ext_vector_type(8)));

static __device__ __forceinline__ float lrelu(float x){ return x > 0.f ? x : 0.2f*x; }

__device__ __forceinline__ float ldE(const float* p, long i){ return p[i]; }
__device__ __forceinline__ float ldE(const BF16* p, long i){
  return __uint_as_float((unsigned)p[i] << 16);
}
__device__ __forceinline__ void stE(float* p, long i, float v){ p[i] = v; }
__device__ __forceinline__ void stE(BF16* p, long i, float v){
  unsigned u = __float_as_uint(v);
  p[i] = (BF16)((u + 0x7FFFu + ((u >> 16) & 1u)) >> 16);
}
__device__ __forceinline__ BF16 f2bf(float v){
  unsigned u = __float_as_uint(v);
  return (BF16)((u + 0x7FFFu + ((u >> 16) & 1u)) >> 16);
}
__device__ __forceinline__ float bf2f(short s){
  return __uint_as_float((unsigned)(unsigned short)s << 16);
}
__device__ __forceinline__ float4 ld4E(const float* p, long i){ return *(const float4*)(p + i); }
__device__ __forceinline__ float4 ld4E(const BF16* p, long i){
  ushort4 s = *(const ushort4*)(p + i);
  return make_float4(__uint_as_float((unsigned)s.x<<16), __uint_as_float((unsigned)s.y<<16),
                     __uint_as_float((unsigned)s.z<<16), __uint_as_float((unsigned)s.w<<16));
}

// ---------------- utility ----------------
__global__ void k_zero(int* __restrict__ p, long n){
  long i = (long)blockIdx.x*blockDim.x + threadIdx.x;
  if (i < n) p[i] = 0;
}
__global__ void k_fill_f32(float* __restrict__ p, long n, float v){
  long i = (long)blockIdx.x*blockDim.x + threadIdx.x;
  if (i < n) p[i] = v;
}

// ---------------- weight transpose+convert: in[K][N] f32 -> out[N][K] bf16
__global__ __launch_bounds__(256) void k_wt(const float* __restrict__ in, BF16* __restrict__ out,
                                            int K, int N)
{
  __shared__ float t[32][33];
  int kb = blockIdx.y*32, nb = blockIdx.x*32;
  int tx = threadIdx.x & 31, ty8 = threadIdx.x >> 5;   // ty8: 0..7
  for (int j = ty8; j < 32; j += 8){
    int k = kb + j, n = nb + tx;
    t[j][tx] = (k < K && n < N) ? in[(long)k*N + n] : 0.f;
  }
  __syncthreads();
  for (int j = ty8; j < 32; j += 8){
    int n = nb + j, k = kb + tx;
    if (n < N && k < K) out[(long)n*K + k] = f2bf(t[tx][j]);
  }
}

// ---------------- MFMA GEMM: C[M,BN] = A[M,K](bf16) @ Bt[c0:c0+BN, K]^T ----
// BM=128, BK=64, 256 threads (4 waves WMxWN), frags FMxFN of 16.
// A row-major stride K. Bt row-major [outcol][K] bf16. C row stride BN.
// Requires K%64==0.
template<int BN, int WM, int WN, int FM, int FN, typename TC>
__global__ __launch_bounds__(256) void k_mfma(
    const BF16* __restrict__ A, const BF16* __restrict__ Bt, TC* __restrict__ C,
    int M, int K, int c0, const float* __restrict__ bias, int doRelu)
{
  constexpr int BM = 128;
  constexpr int LSTR = 72;       // padded LDS row stride (bf16 elems)
  __shared__ __attribute__((aligned(16))) short Als[BM][LSTR];
  __shared__ __attribute__((aligned(16))) short Bls[BN][LSTR];
  const int bm = blockIdx.y*BM;
  const int tid = threadIdx.x;
  const int wave = tid >> 6, lane = tid & 63;
  const int wr = wave / WN, wc = wave % WN;
  const int lrow = lane & 15, kg = lane >> 4;
  f32x4 acc[FM][FN] = {};
  for (int k0 = 0; k0 < K; k0 += 64){
    // stage A tile [128][64]
    #pragma unroll
    for (int t = 0; t < 4; ++t){
      int idx = tid + t*256;
      int row = idx >> 3, kc = (idx & 7) << 3;
      int gr = bm + row;
      short8 v = {};
      if (gr < M) v = *(const short8*)(A + (long)gr*K + k0 + kc);
      *(short8*)&Als[row][kc] = v;
    }
    // stage B tile [BN][64] straight from pre-transposed bf16 weights
    #pragma unroll
    for (int t = 0; t < BN/32; ++t){
      int idx = tid + t*256;
      int row = idx >> 3, kc = (idx & 7) << 3;
      *(short8*)&Bls[row][kc] = *(const short8*)(Bt + (long)(c0+row)*K + k0 + kc);
    }
    __syncthreads();
    #pragma unroll
    for (int kk = 0; kk < 2; ++kk){
      short8 af[FM], bq[FN];
      #pragma unroll
      for (int m = 0; m < FM; ++m)
        af[m] = *(const short8*)&Als[wr*FM*16 + m*16 + lrow][kk*32 + kg*8];
      #pragma unroll
      for (int n = 0; n < FN; ++n)
        bq[n] = *(const short8*)&Bls[wc*FN*16 + n*16 + lrow][kk*32 + kg*8];
      #pragma unroll
      for (int m = 0; m < FM; ++m)
        #pragma unroll
        for (int n = 0; n < FN; ++n)
          acc[m][n] = __builtin_amdgcn_mfma_f32_16x16x32_bf16(
              __builtin_bit_cast(bf16x8, af[m]), __builtin_bit_cast(bf16x8, bq[n]),
              acc[m][n], 0, 0, 0);
    }
    __syncthreads();
  }
  // epilogue: C/D layout col=lane&15, row=(lane>>4)*4+reg  [m89]
  #pragma unroll
  for (int m = 0; m < FM; ++m){
    #pragma unroll
    for (int n = 0; n < FN; ++n){
      #pragma unroll
      for (int j = 0; j < 4; ++j){
        int row = bm + wr*FM*16 + m*16 + kg*4 + j;
        if (row >= M) continue;
        int col = wc*FN*16 + n*16 + lrow;
        float v = acc[m][n][j];
        if (bias) v += bias[col];
        if (doRelu) v = fmaxf(v, 0.f);
        stE(C, (long)row*BN + col, v);
      }
    }
  }
}

// ---------------- naive GEMM (f32 A) for the tiny encoders ----------------
template<typename TA, typename TC>
__global__ __launch_bounds__(256) void k_gemm(
    const TA* __restrict__ A, const float* __restrict__ B, TC* __restrict__ C,
    int M, int N, int K, int ldb, const float* __restrict__ bias, int doRelu)
{
  __shared__ float As[16][64];
  __shared__ float Bs[16][64];
  const int bm = blockIdx.y*64, bn = blockIdx.x*64;
  const int tid = threadIdx.x;
  const int ty = tid >> 4, tx = tid & 15;
  const int ar = tid >> 2;
  const int ac = (tid & 3) << 2;
  const int br = tid >> 4;
  const int bc = (tid & 15) << 2;
  float acc[4][4] = {};
  for (int k0 = 0; k0 < K; k0 += 16){
    int row = bm + ar;
    float4 av = make_float4(0.f,0.f,0.f,0.f);
    if (row < M) av = ld4E(A, (long)row*K + k0 + ac);
    As[ac+0][ar]=av.x; As[ac+1][ar]=av.y; As[ac+2][ar]=av.z; As[ac+3][ar]=av.w;
    float4 bv = make_float4(0.f,0.f,0.f,0.f);
    if (bn + bc + 3 < N) bv = *(const float4*)(B + (long)(k0+br)*ldb + bn + bc);
    *(float4*)&Bs[br][bc] = bv;
    __syncthreads();
    #pragma unroll
    for (int kk = 0; kk < 16; ++kk){
      float a[4], b[4];
      #pragma unroll
      for (int x = 0; x < 4; ++x){ a[x]=As[kk][ty*4+x]; b[x]=Bs[kk][tx*4+x]; }
      #pragma unroll
      for (int y = 0; y < 4; ++y)
        #pragma unroll
        for (int x = 0; x < 4; ++x) acc[y][x] += a[y]*b[x];
    }
    __syncthreads();
  }
  #pragma unroll
  for (int y = 0; y < 4; ++y){
    int row = bm + ty*4 + y;
    if (row >= M) continue;
    #pragma unroll
    for (int x = 0; x < 4; ++x){
      int col = bn + tx*4 + x;
      if (col >= N) continue;
      float v = acc[y][x];
      if (bias) v += bias[col];
      if (doRelu) v = fmaxf(v, 0.f);
      stE(C, (long)row*N + col, v);
    }
  }
}

// ---------------- fold F[h*Din+k] = sum_c W[k*512 + h*128 + c]*att[h*128+c]
__global__ void k_fold(const float* __restrict__ W, const float* __restrict__ att,
                       float* __restrict__ F, int Din)
{
  int idx = blockIdx.x*blockDim.x + threadIdx.x;
  if (idx >= 4*Din) return;
  int h = idx / Din, k = idx % Din;
  float s = 0.f;
  const float* wr = W + (long)k*512 + h*128;
  const float* ar = att + h*128;
  for (int c = 0; c < 128; ++c) s += wr[c]*ar[c];
  F[h*Din + k] = s;
}

// ---------------- score: 4 nodes per wave, all 4 heads --------------------
__global__ __launch_bounds__(256) void k_score4(
    const BF16* __restrict__ X, const float* __restrict__ F,
    float* __restrict__ out, int N, int Din)
{
  __shared__ float Fs[2048];
  for (int i = threadIdx.x; i < 4*Din; i += 256) Fs[i] = F[i];
  __syncthreads();
  int wave = threadIdx.x >> 6, lane = threadIdx.x & 63;
  int base = lane*8;
  bool act = base < Din;
  float f0[8], f1[8], f2[8], f3[8];
  if (act){
    #pragma unroll
    for (int j = 0; j < 8; ++j){
      f0[j] = Fs[0*Din + base + j];
      f1[j] = Fs[1*Din + base + j];
      f2[j] = Fs[2*Din + base + j];
      f3[j] = Fs[3*Din + base + j];
    }
  }
  #pragma unroll
  for (int t = 0; t < 4; ++t){
    int node = blockIdx.x*16 + wave*4 + t;
    if (node >= N) break;
    float p0=0.f, p1=0.f, p2=0.f, p3=0.f;
    if (act){
      short8 v = *(const short8*)(X + (long)node*Din + base);
      #pragma unroll
      for (int j = 0; j < 8; ++j){
        float x = bf2f(v[j]);
        p0 += x*f0[j]; p1 += x*f1[j]; p2 += x*f2[j]; p3 += x*f3[j];
      }
    }
    #pragma unroll
    for (int off = 32; off; off >>= 1){
      p0 += __shfl_down(p0, off, 64);
      p1 += __shfl_down(p1, off, 64);
      p2 += __shfl_down(p2, off, 64);
      p3 += __shfl_down(p3, off, 64);
    }
    if (lane == 0){
      out[(long)node*4 + 0] = p0;
      out[(long)node*4 + 1] = p1;
      out[(long)node*4 + 2] = p2;
      out[(long)node*4 + 3] = p3;
    }
  }
}

// ---------------- CSR build ----------------
__global__ void k_hist(const int* __restrict__ dst, int* __restrict__ counts, int E, int nd){
  int e = blockIdx.x*blockDim.x + threadIdx.x;
  if (e >= E) return;
  int d = dst[e];
  if ((unsigned)d < (unsigned)nd) atomicAdd(&counts[d], 1);
}
__global__ void k_scan1(const int* __restrict__ counts, int* __restrict__ indptr,
                        int* __restrict__ bsums, int n)
{
  __shared__ int sm[256];
  int i = blockIdx.x*256 + threadIdx.x;
  int v = (i < n) ? counts[i] : 0;
  sm[threadIdx.x] = v; __syncthreads();
  for (int off = 1; off < 256; off <<= 1){
    int t = (threadIdx.x >= off) ? sm[threadIdx.x - off] : 0;
    __syncthreads();
    sm[threadIdx.x] += t;
    __syncthreads();
  }
  if (i < n) indptr[i+1] = sm[threadIdx.x];
  if (threadIdx.x == 255) bsums[blockIdx.x] = sm[255];
  if (blockIdx.x == 0 && threadIdx.x == 0) indptr[0] = 0;
}
__global__ void k_scan2(int* __restrict__ bsums, int nb){
  __shared__ int sm[1024];
  int t = threadIdx.x;
  int v = (t < nb) ? bsums[t] : 0;
  sm[t] = v; __syncthreads();
  for (int off = 1; off < 1024; off <<= 1){
    int x = (t >= off) ? sm[t - off] : 0;
    __syncthreads();
    sm[t] += x;
    __syncthreads();
  }
  if (t < nb) bsums[t] = sm[t];
}
__global__ void k_scan3(int* __restrict__ indptr, const int* __restrict__ bsums, int n){
  if (blockIdx.x == 0) return;
  int i = blockIdx.x*256 + threadIdx.x;
  int add = bsums[blockIdx.x - 1];
  if (i < n) indptr[i+1] += add;
}
__global__ void k_scatter(const int* __restrict__ src, const int* __restrict__ dst,
                          const int* __restrict__ indptr, int* __restrict__ cursor,
                          int* __restrict__ esrc, int E, int nd, int ns)
{
  int e = blockIdx.x*blockDim.x + threadIdx.x;
  if (e >= E) return;
  int d = dst[e];
  if ((unsigned)d >= (unsigned)nd) return;
  int s = src[e];
  if ((unsigned)s >= (unsigned)ns) s = 0;
  int pos = indptr[d] + atomicAdd(&cursor[d], 1);
  if (pos >= 0 && pos < E) esrc[pos] = s;
}

// ---------------- per-edge alpha: one wave per dst node -------------------
__global__ __launch_bounds__(256) void k_alpha(
    const float* __restrict__ ss, const float* __restrict__ sd,
    const int* __restrict__ indptr, const int* __restrict__ esrc,
    float* __restrict__ alpha, int n_dst, int E, int ns)
{
  int wid = (blockIdx.x*blockDim.x + threadIdx.x) >> 6;
  int lane = threadIdx.x & 63;
  if (wid >= n_dst) return;
  int e0 = indptr[wid], e1 = indptr[wid+1];
  e0 = max(0, min(e0, E)); e1 = max(e0, min(e1, E));
  if (e0 >= e1) return;
  int h = lane >> 4, g = lane & 15;
  float sdl = sd[(long)wid*4 + h];
  float m = -INFINITY;
  for (int e = e0 + g; e < e1; e += 16){
    int s = esrc[e]; if ((unsigned)s >= (unsigned)ns) s = 0;
    m = fmaxf(m, lrelu(ss[(long)s*4 + h] + sdl));
  }
  #pragma unroll
  for (int o = 1; o < 16; o <<= 1) m = fmaxf(m, __shfl_xor(m, o, 16));
  float den = 0.f;
  for (int e = e0 + g; e < e1; e += 16){
    int s = esrc[e]; if ((unsigned)s >= (unsigned)ns) s = 0;
    den += __expf(lrelu(ss[(long)s*4 + h] + sdl) - m);
  }
  #pragma unroll
  for (int o = 1; o < 16; o <<= 1) den += __shfl_xor(den, o, 16);
  float inv = 1.f/(den + 1e-16f);
  for (int e = e0 + g; e < e1; e += 16){
    int s = esrc[e]; if ((unsigned)s >= (unsigned)ns) s = 0;
    alpha[(long)e*4 + h] = __expf(lrelu(ss[(long)s*4 + h] + sdl) - m) * inv;
  }
}

// ---------------- tiled aggregation: one wave per dst ---------------------
template<typename TOUT>
__global__ __launch_bounds__(256) void k_agg(
    const BF16* __restrict__ Zt, const float* __restrict__ alpha,
    const int* __restrict__ indptr, const int* __restrict__ esrc,
    TOUT* __restrict__ out, int ldc, int c0, int TW, int head,
    int accum, int n_dst, int E, int ns)
{
  int wid = (blockIdx.x*blockDim.x + threadIdx.x) >> 6;
  int lane = threadIdx.x & 63;
  if (wid >= n_dst) return;
  int e0 = indptr[wid], e1 = indptr[wid+1];
  e0 = max(0, min(e0, E)); e1 = max(e0, min(e1, E));
  float acc0 = 0.f, acc1 = 0.f;
  const int col0 = lane, col1 = lane + 64;
  for (int e = e0; e < e1; ++e){
    int s = esrc[e]; if ((unsigned)s >= (unsigned)ns) s = 0;
    float a = alpha[(long)e*4 + head];
    const BF16* zr = Zt + (long)s*TW;
    if (col0 < TW) acc0 += a * ldE(zr, col0);
    if (TW > 64)   acc1 += a * ldE(zr, col1);
  }
  if (col0 < TW){
    long idx = (long)wid*ldc + c0 + col0;
    float v = acc0; if (accum) v += ldE(out, idx);
    stE(out, idx, v);
  }
  if (TW > 64){
    long idx = (long)wid*ldc + c0 + col1;
    float v = acc1; if (accum) v += ldE(out, idx);
    stE(out, idx, v);
  }
}

// ---------------- BN stats over nw_tile [N, TW] ---------------------------
__global__ void k_bnp(const float* __restrict__ nw, float* __restrict__ bnp,
                      int N, int TW, int P)
{
  int col  = threadIdx.x & (TW - 1);
  int slot = threadIdx.x / TW;
  int rpb  = 256 / TW;
  int p    = blockIdx.x*rpb + slot;
  float s = 0.f, s2 = 0.f;
  for (long r = p; r < N; r += P){
    float v = nw[r*TW + col];
    s += v; s2 += v*v;
  }
  bnp[(long)p*2*TW + col]      = s;
  bnp[(long)p*2*TW + TW + col] = s2;
}
__global__ void k_bnf(const float* __restrict__ bnp, float* __restrict__ bns,
                      int P, int TW)
{
  int c = threadIdx.x;
  if (c >= 2*TW) return;
  float s = 0.f;
  for (int p = 0; p < P; ++p) s += bnp[(long)p*2*TW + c];
  bns[c] = s;
}
__global__ void k_bn_apply(const float* __restrict__ nw, const float* __restrict__ bns,
                           const float* __restrict__ g, const float* __restrict__ b,
                           BF16* __restrict__ A, int N, int TW, int c0, int res)
{
  long total = (long)N*TW;
  for (long i = (long)blockIdx.x*blockDim.x + threadIdx.x; i < total;
       i += (long)gridDim.x*blockDim.x){
    int col = (int)(i % TW);
    long r  = i / TW;
    float mu  = bns[col] / (float)N;
    float var = bns[TW + col] / (float)N - mu*mu;
    int gc = c0 + col;
    float sc = g[gc] * rsqrtf(var + 1e-5f);
    float sh = b[gc] - mu*sc;
    float v = fmaxf(nw[i]*sc + sh, 0.f);
    long ai = r*512 + gc;
    if (res) v += ldE(A, ai);
    stE(A, ai, v);
  }
}

// ---------------- acc/mer update ----------------
__global__ void k_update(const BF16* __restrict__ B, const float* __restrict__ ab1,
                         const float* __restrict__ ab2, BF16* __restrict__ A,
                         long n512, int res)
{
  for (long i = (long)blockIdx.x*blockDim.x + threadIdx.x; i < n512;
       i += (long)gridDim.x*blockDim.x){
    int c = (int)(i & 511);
    float v = ldE(B, i) + ab1[c] + (ab2 ? ab2[c] : 0.f);
    v = fmaxf(v, 0.f);
    if (res) v += ldE(A, i);
    stE(A, i, v);
  }
}

// ---------------- head logits ----------------
__global__ void k_logits(const float* __restrict__ Hid, const float* __restrict__ Wh2,
                         const float* __restrict__ bh2, float* __restrict__ out, int N)
{
  int node = (blockIdx.x*blockDim.x + threadIdx.x) >> 6;
  int lane = threadIdx.x & 63;
  if (node >= N) return;
  float v = Hid[(long)node*64 + lane] * Wh2[lane];
  #pragma unroll
  for (int off = 32; off; off >>= 1) v += __shfl_down(v, off, 64);
  if (lane == 0) out[node] = v + bh2[0];
}

// ---------------------------------------------------------------------------
struct Arena {
  BF16 *A[3];
  BF16 *Bst[3];
  BF16 *Zt;
  float *nwtile;
  float *hidden;
  float *alpha;
  float *ss, *sd, *fs, *fd, *bnp, *bns;
  int *counts, *bsums;
  int *indptr[6], *esrc[6];
  BF16 *Wt0[6], *WtL[2][6], *Wh1t;
  size_t total;
};

extern "C" void kernel_launch(void* const* d_in, const int* in_sizes, int n_in,
                              void* d_out, int out_size, void* d_ws, size_t ws_size,
                              hipStream_t stream)
{
  const float* x_tx  = (const float*)d_in[0];
  const float* x_acc = (const float*)d_in[1];
  const float* x_mer = (const float*)d_in[2];
  const float* Wtx = (const float*)d_in[3];  const float* btx  = (const float*)d_in[4];
  const float* Wacc= (const float*)d_in[5];  const float* bacc = (const float*)d_in[6];
  const float* Wmer= (const float*)d_in[7];  const float* bmer = (const float*)d_in[8];
  const float* W0   = (const float*)d_in[9];
  const float* Wrest= (const float*)d_in[10];
  const float* att_s= (const float*)d_in[11];
  const float* att_d= (const float*)d_in[12];
  const float* att_b= (const float*)d_in[13];
  const float* bn_g = (const float*)d_in[14];
  const float* bn_b = (const float*)d_in[15];
  const float* Wh1  = (const float*)d_in[16]; const float* bh1 = (const float*)d_in[17];
  const float* Wh2  = (const float*)d_in[18]; const float* bh2 = (const float*)d_in[19];
  const int*   edges= (const int*)d_in[20];

  const int E    = in_sizes[20] / 12;
  const int nTx  = in_sizes[0] / 64;
  const int nAcc = in_sizes[1] / 32;
  const int nMer = in_sizes[2] / 32;
  const int nOf[3]   = {nTx, nAcc, nMer};
  const int SRC_T[6] = {0,0,0,1,1,2};
  const int DST_T[6] = {1,1,2,0,0,0};
  const int maxN = max(nTx, max(nAcc, nMer));
  (void)n_in;

  auto layout = [&](int TW)->Arena{
    Arena P{};
    size_t off = 0;
    auto a = [&](size_t bytes)->char*{
      char* p = (char*)d_ws + off;
      off += (bytes + 255) & ~(size_t)255;
      return p;
    };
    auto al = [](size_t b){ return (b + 255) & ~(size_t)255; };
    P.A[0]   = (BF16*)a((size_t)nTx *512*2);
    P.A[1]   = (BF16*)a((size_t)nAcc*512*2);
    P.A[2]   = (BF16*)a((size_t)nMer*512*2);
    P.Bst[1] = (BF16*)a((size_t)nAcc*512*2);
    P.Bst[2] = (BF16*)a((size_t)nMer*512*2);
    size_t zB = al((size_t)maxN*TW*2);
    size_t scr = zB + (size_t)nTx*TW*4;
    size_t hidB = (size_t)nTx*64*4;
    char* scrBase = a(scr > hidB ? scr : hidB);
    P.Zt     = (BF16*)scrBase;
    P.nwtile = (float*)(scrBase + zB);
    P.hidden = (float*)scrBase;
    P.alpha  = (float*)a((size_t)3*E*4*4);
    P.ss     = (float*)a((size_t)maxN*4*4);
    P.sd     = (float*)a((size_t)maxN*4*4);
    P.fs     = (float*)a(4*512*4);
    P.fd     = (float*)a(4*512*4);
    P.bnp    = (float*)a(262144);
    P.bns    = (float*)a(1024);
    P.counts = (int*)a((size_t)maxN*4);
    P.bsums  = (int*)a(4096);
    for (int r = 0; r < 6; ++r){
      P.indptr[r] = (int*)a((size_t)(nOf[DST_T[r]]+1)*4);
      P.esrc[r]   = (int*)a((size_t)E*4);
    }
    for (int r = 0; r < 6; ++r) P.Wt0[r] = (BF16*)a((size_t)512*128*2);
    for (int l = 0; l < 2; ++l)
      for (int r = 0; r < 6; ++r) P.WtL[l][r] = (BF16*)a((size_t)512*512*2);
    P.Wh1t = (BF16*)a((size_t)64*512*2);
    P.total = off;
    return P;
  };

  int TW = 0;
  Arena P{};
  for (int cand : {128, 64, 32}){
    P = layout(cand);
    if (P.total <= ws_size){ TW = cand; break; }
  }
  if (TW == 0){
    float sentinel = 10000.0f + (float)(ws_size >> 20);
    k_fill_f32<<<dim3((out_size+255)/256), dim3(256), 0, stream>>>((float*)d_out, (long)out_size, sentinel);
    return;
  }
  const int nTiles = 512 / TW;
  const int rpb = 256 / TW, PBX = 128, Pp = PBX * rpb;
  dim3 b256(256);

  // ---- 0. weight prep: transpose+convert to bf16 [outcol][K] ----
  for (int r = 0; r < 6; ++r)
    k_wt<<<dim3(16,4), b256, 0, stream>>>(W0 + (size_t)r*128*512, P.Wt0[r], 128, 512);
  for (int l = 0; l < 2; ++l)
    for (int r = 0; r < 6; ++r)
      k_wt<<<dim3(16,16), b256, 0, stream>>>(Wrest + ((size_t)l*6 + r)*512*512, P.WtL[l][r], 512, 512);
  k_wt<<<dim3(2,16), b256, 0, stream>>>(Wh1, P.Wh1t, 512, 64);

  // MFMA projection dispatch: C[M][TW](bf16) = A[M][K] @ Wt[c0:c0+TW,:]^T
  auto mfma_gemm = [&](const BF16* A, const BF16* Bt, BF16* Cp, int M, int K, int c0){
    dim3 g(1, (M+127)/128);
    if (TW == 128)      k_mfma<128,2,2,4,4,BF16><<<g,b256,0,stream>>>(A, Bt, Cp, M, K, c0, (const float*)nullptr, 0);
    else if (TW == 64)  k_mfma< 64,4,1,2,4,BF16><<<g,b256,0,stream>>>(A, Bt, Cp, M, K, c0, (const float*)nullptr, 0);
    else                k_mfma< 32,4,1,2,2,BF16><<<g,b256,0,stream>>>(A, Bt, Cp, M, K, c0, (const float*)nullptr, 0);
  };

  // ---- 1. CSR build ----
  for (int r = 0; r < 6; ++r){
    int nd = nOf[DST_T[r]], ns = nOf[SRC_T[r]];
    const int* srcP = edges + (size_t)r*2*E;
    const int* dstP = srcP + E;
    int nb = (nd + 255)/256;
    k_zero   <<<dim3(nb),          b256, 0, stream>>>(P.counts, (long)nd);
    k_hist   <<<dim3((E+255)/256), b256, 0, stream>>>(dstP, P.counts, E, nd);
    k_scan1  <<<dim3(nb),          b256, 0, stream>>>(P.counts, P.indptr[r], P.bsums, nd);
    k_scan2  <<<dim3(1),           dim3(1024),0, stream>>>(P.bsums, nb);
    k_scan3  <<<dim3(nb),          b256, 0, stream>>>(P.indptr[r], P.bsums, nd);
    k_zero   <<<dim3(nb),          b256, 0, stream>>>(P.counts, (long)nd);
    k_scatter<<<dim3((E+255)/256), b256, 0, stream>>>(srcP, dstP, P.indptr[r], P.counts, P.esrc[r], E, nd, ns);
  }

  // ---- 2. encoders (naive f32 GEMM, tiny) ----
  k_gemm<float,BF16><<<dim3(2,(nTx +63)/64), b256, 0, stream>>>(x_tx,  Wtx,  P.A[0], nTx,  128, 64, 128, btx,  1);
  k_gemm<float,BF16><<<dim3(2,(nAcc+63)/64), b256, 0, stream>>>(x_acc, Wacc, P.A[1], nAcc, 128, 32, 128, bacc, 1);
  k_gemm<float,BF16><<<dim3(2,(nMer+63)/64), b256, 0, stream>>>(x_mer, Wmer, P.A[2], nMer, 128, 32, 128, bmer, 1);

  // ---- 3. layers ----
  for (int i = 0; i < 3; ++i){
    const int Din = (i == 0) ? 128 : 512;
    const int res = (i > 0) ? 1 : 0;
    auto Wof = [&](int r)->const float*{
      return (i == 0) ? (W0 + (size_t)r*128*512)
                      : (Wrest + ((size_t)(i-1)*6 + r)*512*512);
    };
    auto Wtof = [&](int r)->const BF16*{
      return (i == 0) ? P.Wt0[r] : P.WtL[i-1][r];
    };
    // Phase 1: dst=acc (r=0,1), dst=mer (r=2); src=tx
    for (int r = 0; r < 3; ++r){
      int dt = DST_T[r];
      int nd = nOf[dt];
      const float* as_ = att_s + ((size_t)(i*6 + r))*4*128;
      const float* ad_ = att_d + ((size_t)(i*6 + r))*4*128;
      k_fold<<<dim3((4*Din+255)/256), b256, 0, stream>>>(Wof(r), as_, P.fs, Din);
      k_fold<<<dim3((4*Din+255)/256), b256, 0, stream>>>(Wof(r), ad_, P.fd, Din);
      k_score4<<<dim3((nTx+15)/16), b256, 0, stream>>>(P.A[0], P.fs, P.ss, nTx, Din);
      k_score4<<<dim3((nd+15)/16),  b256, 0, stream>>>(P.A[dt], P.fd, P.sd, nd, Din);
      k_alpha<<<dim3((nd+3)/4), b256, 0, stream>>>(P.ss, P.sd, P.indptr[r], P.esrc[r],
                                                   P.alpha, nd, E, nTx);
      int accF = (r == 1) ? 1 : 0;
      for (int t = 0; t < nTiles; ++t){
        int c0 = t*TW, head = c0 >> 7;
        mfma_gemm(P.A[0], Wtof(r), P.Zt, nTx, Din, c0);
        k_agg<BF16><<<dim3((nd+3)/4), b256, 0, stream>>>(
            P.Zt, P.alpha, P.indptr[r], P.esrc[r], P.Bst[dt], 512, c0, TW, head,
            accF, nd, E, nTx);
      }
    }
    // Phase 2: dst=tx (r=3,4,5; src=acc,acc,mer)
    for (int r = 3; r < 6; ++r){
      int st = SRC_T[r];
      int ns = nOf[st];
      const float* as_ = att_s + ((size_t)(i*6 + r))*4*128;
      const float* ad_ = att_d + ((size_t)(i*6 + r))*4*128;
      k_fold<<<dim3((4*Din+255)/256), b256, 0, stream>>>(Wof(r), as_, P.fs, Din);
      k_fold<<<dim3((4*Din+255)/256), b256, 0, stream>>>(Wof(r), ad_, P.fd, Din);
      k_score4<<<dim3((ns+15)/16),  b256, 0, stream>>>(P.A[st], P.fs, P.ss, ns, Din);
      k_score4<<<dim3((nTx+15)/16), b256, 0, stream>>>(P.A[0],  P.fd, P.sd, nTx, Din);  // OLD A_tx
      k_alpha<<<dim3((nTx+3)/4), b256, 0, stream>>>(P.ss, P.sd, P.indptr[r], P.esrc[r],
                                                    P.alpha + (size_t)(r-3)*E*4, nTx, E, ns);
    }
    for (int t = 0; t < nTiles; ++t){
      int c0 = t*TW, head = c0 >> 7;
      for (int r = 3; r < 6; ++r){
        int st = SRC_T[r], ns = nOf[st];
        mfma_gemm(P.A[st], Wtof(r), P.Zt, ns, Din, c0);
        k_agg<float><<<dim3((nTx+3)/4), b256, 0, stream>>>(
            P.Zt, P.alpha + (size_t)(r-3)*E*4, P.indptr[r], P.esrc[r],
            P.nwtile, TW, 0, TW, head, (r > 3) ? 1 : 0, nTx, E, ns);
      }
      k_bnp<<<dim3(PBX), b256, 0, stream>>>(P.nwtile, P.bnp, nTx, TW, Pp);
      k_bnf<<<dim3(1),   b256, 0, stream>>>(P.bnp, P.bns, Pp, TW);
      k_bn_apply<<<dim3(2048), b256, 0, stream>>>(P.nwtile, P.bns,
          bn_g + (size_t)i*512, bn_b + (size_t)i*512, P.A[0], nTx, TW, c0, res);
    }
    // Phase 3: acc/mer update
    const float* ab0 = att_b + ((size_t)(i*6 + 0))*512;
    const float* ab1 = att_b + ((size_t)(i*6 + 1))*512;
    const float* ab2 = att_b + ((size_t)(i*6 + 2))*512;
    k_update<<<dim3(2048), b256, 0, stream>>>(P.Bst[1], ab0, ab1, P.A[1], (long)nAcc*512, res);
    k_update<<<dim3(256),  b256, 0, stream>>>(P.Bst[2], ab2, (const float*)nullptr, P.A[2], (long)nMer*512, res);
  }

  // ---- 4. head: hidden = relu(h_tx @ Wh1 + bh1) via MFMA (N=64) ----
  k_mfma<64,4,1,2,4,float><<<dim3(1,(nTx+127)/128), b256, 0, stream>>>(
      P.A[0], P.Wh1t, P.hidden, nTx, 512, 0, bh1, 1);
  k_logits<<<dim3((nTx+3)/4), b256, 0, stream>>>(P.hidden, Wh2, bh2, (float*)d_out, nTx);
}

// Round 8
// 12156.271 us; speedup vs baseline: 2.1358x; 2.1358x over previous
//
#include <hip/hip_runtime.h>
#include <math.h>

// ---------------------------------------------------------------------------
// FraudGAT, memory-lean + MFMA projections (pre-transposed bf16 weights).
// bf16 storage everywhere (activations, Z tiles, nw tile, hidden); f32 for
// softmax/BN statistics. Column-tiled conv with tiers TW=256/128/64/32.
// Gather cost ~ E x (512/TW) row fetches -> bigger TW = fewer fetches.
// (Round 8 = Round 7 resubmitted unchanged: R7 failed on infra, no signal.)
// ---------------------------------------------------------------------------

typedef unsigned short BF16;
typedef short short8 __attribute__((ext_vector_type(8)));
typedef float f32x4 __attribute__((ext_vector_type(4)));
typedef __bf16 bf16x8 __attribute__((ext_vector_type(8)));

static __device__ __forceinline__ float lrelu(float x){ return x > 0.f ? x : 0.2f*x; }

__device__ __forceinline__ float ldE(const float* p, long i){ return p[i]; }
__device__ __forceinline__ float ldE(const BF16* p, long i){
  return __uint_as_float((unsigned)p[i] << 16);
}
__device__ __forceinline__ void stE(float* p, long i, float v){ p[i] = v; }
__device__ __forceinline__ void stE(BF16* p, long i, float v){
  unsigned u = __float_as_uint(v);
  p[i] = (BF16)((u + 0x7FFFu + ((u >> 16) & 1u)) >> 16);
}
__device__ __forceinline__ BF16 f2bf(float v){
  unsigned u = __float_as_uint(v);
  return (BF16)((u + 0x7FFFu + ((u >> 16) & 1u)) >> 16);
}
__device__ __forceinline__ float bf2f(short s){
  return __uint_as_float((unsigned)(unsigned short)s << 16);
}
__device__ __forceinline__ float4 ld4E(const float* p, long i){ return *(const float4*)(p + i); }
__device__ __forceinline__ float4 ld4E(const BF16* p, long i){
  ushort4 s = *(const ushort4*)(p + i);
  return make_float4(__uint_as_float((unsigned)s.x<<16), __uint_as_float((unsigned)s.y<<16),
                     __uint_as_float((unsigned)s.z<<16), __uint_as_float((unsigned)s.w<<16));
}

// ---------------- utility ----------------
__global__ void k_zero(int* __restrict__ p, long n){
  long i = (long)blockIdx.x*blockDim.x + threadIdx.x;
  if (i < n) p[i] = 0;
}
__global__ void k_fill_f32(float* __restrict__ p, long n, float v){
  long i = (long)blockIdx.x*blockDim.x + threadIdx.x;
  if (i < n) p[i] = v;
}

// ---------------- weight transpose+convert: in[K][N] f32 -> out[N][K] bf16
__global__ __launch_bounds__(256) void k_wt(const float* __restrict__ in, BF16* __restrict__ out,
                                            int K, int N)
{
  __shared__ float t[32][33];
  int kb = blockIdx.y*32, nb = blockIdx.x*32;
  int tx = threadIdx.x & 31, ty8 = threadIdx.x >> 5;
  for (int j = ty8; j < 32; j += 8){
    int k = kb + j, n = nb + tx;
    t[j][tx] = (k < K && n < N) ? in[(long)k*N + n] : 0.f;
  }
  __syncthreads();
  for (int j = ty8; j < 32; j += 8){
    int n = nb + j, k = kb + tx;
    if (n < N && k < K) out[(long)n*K + k] = f2bf(t[tx][j]);
  }
}

// ---------------- MFMA GEMM: C[M,BN] = A[M,K](bf16) @ Bt[c0:c0+BN, K]^T ----
// BM=128, BK=64, 256 threads (4 waves WMxWN), frags FMxFN of 16.
// A row-major stride K. Bt row-major [outcol][K] bf16. C row stride ldc.
// Requires K%64==0.
template<int BN, int WM, int WN, int FM, int FN, typename TC>
__global__ __launch_bounds__(256) void k_mfma(
    const BF16* __restrict__ A, const BF16* __restrict__ Bt, TC* __restrict__ C,
    int M, int K, int c0, int ldc, const float* __restrict__ bias, int doRelu)
{
  constexpr int BM = 128;
  constexpr int LSTR = 72;       // padded LDS row stride (bf16 elems)
  __shared__ __attribute__((aligned(16))) short Als[BM][LSTR];
  __shared__ __attribute__((aligned(16))) short Bls[BN][LSTR];
  const int bm = blockIdx.y*BM;
  const int tid = threadIdx.x;
  const int wave = tid >> 6, lane = tid & 63;
  const int wr = wave / WN, wc = wave % WN;
  const int lrow = lane & 15, kg = lane >> 4;
  f32x4 acc[FM][FN] = {};
  for (int k0 = 0; k0 < K; k0 += 64){
    #pragma unroll
    for (int t = 0; t < 4; ++t){
      int idx = tid + t*256;
      int row = idx >> 3, kc = (idx & 7) << 3;
      int gr = bm + row;
      short8 v = {};
      if (gr < M) v = *(const short8*)(A + (long)gr*K + k0 + kc);
      *(short8*)&Als[row][kc] = v;
    }
    #pragma unroll
    for (int t = 0; t < BN/32; ++t){
      int idx = tid + t*256;
      int row = idx >> 3, kc = (idx & 7) << 3;
      *(short8*)&Bls[row][kc] = *(const short8*)(Bt + (long)(c0+row)*K + k0 + kc);
    }
    __syncthreads();
    #pragma unroll
    for (int kk = 0; kk < 2; ++kk){
      short8 af[FM], bq[FN];
      #pragma unroll
      for (int m = 0; m < FM; ++m)
        af[m] = *(const short8*)&Als[wr*FM*16 + m*16 + lrow][kk*32 + kg*8];
      #pragma unroll
      for (int n = 0; n < FN; ++n)
        bq[n] = *(const short8*)&Bls[wc*FN*16 + n*16 + lrow][kk*32 + kg*8];
      #pragma unroll
      for (int m = 0; m < FM; ++m)
        #pragma unroll
        for (int n = 0; n < FN; ++n)
          acc[m][n] = __builtin_amdgcn_mfma_f32_16x16x32_bf16(
              __builtin_bit_cast(bf16x8, af[m]), __builtin_bit_cast(bf16x8, bq[n]),
              acc[m][n], 0, 0, 0);
    }
    __syncthreads();
  }
  // epilogue: C/D layout col=lane&15, row=(lane>>4)*4+reg  [m89]
  #pragma unroll
  for (int m = 0; m < FM; ++m){
    #pragma unroll
    for (int n = 0; n < FN; ++n){
      #pragma unroll
      for (int j = 0; j < 4; ++j){
        int row = bm + wr*FM*16 + m*16 + kg*4 + j;
        if (row >= M) continue;
        int col = wc*FN*16 + n*16 + lrow;
        float v = acc[m][n][j];
        if (bias) v += bias[col];
        if (doRelu) v = fmaxf(v, 0.f);
        stE(C, (long)row*ldc + col, v);
      }
    }
  }
}

// ---------------- naive GEMM (f32 A) for the tiny encoders ----------------
template<typename TA, typename TC>
__global__ __launch_bounds__(256) void k_gemm(
    const TA* __restrict__ A, const float* __restrict__ B, TC* __restrict__ C,
    int M, int N, int K, int ldb, const float* __restrict__ bias, int doRelu)
{
  __shared__ float As[16][64];
  __shared__ float Bs[16][64];
  const int bm = blockIdx.y*64, bn = blockIdx.x*64;
  const int tid = threadIdx.x;
  const int ty = tid >> 4, tx = tid & 15;
  const int ar = tid >> 2;
  const int ac = (tid & 3) << 2;
  const int br = tid >> 4;
  const int bc = (tid & 15) << 2;
  float acc[4][4] = {};
  for (int k0 = 0; k0 < K; k0 += 16){
    int row = bm + ar;
    float4 av = make_float4(0.f,0.f,0.f,0.f);
    if (row < M) av = ld4E(A, (long)row*K + k0 + ac);
    As[ac+0][ar]=av.x; As[ac+1][ar]=av.y; As[ac+2][ar]=av.z; As[ac+3][ar]=av.w;
    float4 bv = make_float4(0.f,0.f,0.f,0.f);
    if (bn + bc + 3 < N) bv = *(const float4*)(B + (long)(k0+br)*ldb + bn + bc);
    *(float4*)&Bs[br][bc] = bv;
    __syncthreads();
    #pragma unroll
    for (int kk = 0; kk < 16; ++kk){
      float a[4], b[4];
      #pragma unroll
      for (int x = 0; x < 4; ++x){ a[x]=As[kk][ty*4+x]; b[x]=Bs[kk][tx*4+x]; }
      #pragma unroll
      for (int y = 0; y < 4; ++y)
        #pragma unroll
        for (int x = 0; x < 4; ++x) acc[y][x] += a[y]*b[x];
    }
    __syncthreads();
  }
  #pragma unroll
  for (int y = 0; y < 4; ++y){
    int row = bm + ty*4 + y;
    if (row >= M) continue;
    #pragma unroll
    for (int x = 0; x < 4; ++x){
      int col = bn + tx*4 + x;
      if (col >= N) continue;
      float v = acc[y][x];
      if (bias) v += bias[col];
      if (doRelu) v = fmaxf(v, 0.f);
      stE(C, (long)row*N + col, v);
    }
  }
}

// ---------------- fold F[h*Din+k] = sum_c W[k*512 + h*128 + c]*att[h*128+c]
__global__ void k_fold(const float* __restrict__ W, const float* __restrict__ att,
                       float* __restrict__ F, int Din)
{
  int idx = blockIdx.x*blockDim.x + threadIdx.x;
  if (idx >= 4*Din) return;
  int h = idx / Din, k = idx % Din;
  float s = 0.f;
  const float* wr = W + (long)k*512 + h*128;
  const float* ar = att + h*128;
  for (int c = 0; c < 128; ++c) s += wr[c]*ar[c];
  F[h*Din + k] = s;
}

// ---------------- score: 4 nodes per wave, all 4 heads --------------------
__global__ __launch_bounds__(256) void k_score4(
    const BF16* __restrict__ X, const float* __restrict__ F,
    float* __restrict__ out, int N, int Din)
{
  __shared__ float Fs[2048];
  for (int i = threadIdx.x; i < 4*Din; i += 256) Fs[i] = F[i];
  __syncthreads();
  int wave = threadIdx.x >> 6, lane = threadIdx.x & 63;
  int base = lane*8;
  bool act = base < Din;
  float f0[8], f1[8], f2[8], f3[8];
  if (act){
    #pragma unroll
    for (int j = 0; j < 8; ++j){
      f0[j] = Fs[0*Din + base + j];
      f1[j] = Fs[1*Din + base + j];
      f2[j] = Fs[2*Din + base + j];
      f3[j] = Fs[3*Din + base + j];
    }
  }
  #pragma unroll
  for (int t = 0; t < 4; ++t){
    int node = blockIdx.x*16 + wave*4 + t;
    if (node >= N) break;
    float p0=0.f, p1=0.f, p2=0.f, p3=0.f;
    if (act){
      short8 v = *(const short8*)(X + (long)node*Din + base);
      #pragma unroll
      for (int j = 0; j < 8; ++j){
        float x = bf2f(v[j]);
        p0 += x*f0[j]; p1 += x*f1[j]; p2 += x*f2[j]; p3 += x*f3[j];
      }
    }
    #pragma unroll
    for (int off = 32; off; off >>= 1){
      p0 += __shfl_down(p0, off, 64);
      p1 += __shfl_down(p1, off, 64);
      p2 += __shfl_down(p2, off, 64);
      p3 += __shfl_down(p3, off, 64);
    }
    if (lane == 0){
      out[(long)node*4 + 0] = p0;
      out[(long)node*4 + 1] = p1;
      out[(long)node*4 + 2] = p2;
      out[(long)node*4 + 3] = p3;
    }
  }
}

// ---------------- CSR build ----------------
__global__ void k_hist(const int* __restrict__ dst, int* __restrict__ counts, int E, int nd){
  int e = blockIdx.x*blockDim.x + threadIdx.x;
  if (e >= E) return;
  int d = dst[e];
  if ((unsigned)d < (unsigned)nd) atomicAdd(&counts[d], 1);
}
__global__ void k_scan1(const int* __restrict__ counts, int* __restrict__ indptr,
                        int* __restrict__ bsums, int n)
{
  __shared__ int sm[256];
  int i = blockIdx.x*256 + threadIdx.x;
  int v = (i < n) ? counts[i] : 0;
  sm[threadIdx.x] = v; __syncthreads();
  for (int off = 1; off < 256; off <<= 1){
    int t = (threadIdx.x >= off) ? sm[threadIdx.x - off] : 0;
    __syncthreads();
    sm[threadIdx.x] += t;
    __syncthreads();
  }
  if (i < n) indptr[i+1] = sm[threadIdx.x];
  if (threadIdx.x == 255) bsums[blockIdx.x] = sm[255];
  if (blockIdx.x == 0 && threadIdx.x == 0) indptr[0] = 0;
}
__global__ void k_scan2(int* __restrict__ bsums, int nb){
  __shared__ int sm[1024];
  int t = threadIdx.x;
  int v = (t < nb) ? bsums[t] : 0;
  sm[t] = v; __syncthreads();
  for (int off = 1; off < 1024; off <<= 1){
    int x = (t >= off) ? sm[t - off] : 0;
    __syncthreads();
    sm[t] += x;
    __syncthreads();
  }
  if (t < nb) bsums[t] = sm[t];
}
__global__ void k_scan3(int* __restrict__ indptr, const int* __restrict__ bsums, int n){
  if (blockIdx.x == 0) return;
  int i = blockIdx.x*256 + threadIdx.x;
  int add = bsums[blockIdx.x - 1];
  if (i < n) indptr[i+1] += add;
}
__global__ void k_scatter(const int* __restrict__ src, const int* __restrict__ dst,
                          const int* __restrict__ indptr, int* __restrict__ cursor,
                          int* __restrict__ esrc, int E, int nd, int ns)
{
  int e = blockIdx.x*blockDim.x + threadIdx.x;
  if (e >= E) return;
  int d = dst[e];
  if ((unsigned)d >= (unsigned)nd) return;
  int s = src[e];
  if ((unsigned)s >= (unsigned)ns) s = 0;
  int pos = indptr[d] + atomicAdd(&cursor[d], 1);
  if (pos >= 0 && pos < E) esrc[pos] = s;
}

// ---------------- per-edge alpha: one wave per dst node -------------------
__global__ __launch_bounds__(256) void k_alpha(
    const float* __restrict__ ss, const float* __restrict__ sd,
    const int* __restrict__ indptr, const int* __restrict__ esrc,
    float* __restrict__ alpha, int n_dst, int E, int ns)
{
  int wid = (blockIdx.x*blockDim.x + threadIdx.x) >> 6;
  int lane = threadIdx.x & 63;
  if (wid >= n_dst) return;
  int e0 = indptr[wid], e1 = indptr[wid+1];
  e0 = max(0, min(e0, E)); e1 = max(e0, min(e1, E));
  if (e0 >= e1) return;
  int h = lane >> 4, g = lane & 15;
  float sdl = sd[(long)wid*4 + h];
  float m = -INFINITY;
  for (int e = e0 + g; e < e1; e += 16){
    int s = esrc[e]; if ((unsigned)s >= (unsigned)ns) s = 0;
    m = fmaxf(m, lrelu(ss[(long)s*4 + h] + sdl));
  }
  #pragma unroll
  for (int o = 1; o < 16; o <<= 1) m = fmaxf(m, __shfl_xor(m, o, 16));
  float den = 0.f;
  for (int e = e0 + g; e < e1; e += 16){
    int s = esrc[e]; if ((unsigned)s >= (unsigned)ns) s = 0;
    den += __expf(lrelu(ss[(long)s*4 + h] + sdl) - m);
  }
  #pragma unroll
  for (int o = 1; o < 16; o <<= 1) den += __shfl_xor(den, o, 16);
  float inv = 1.f/(den + 1e-16f);
  for (int e = e0 + g; e < e1; e += 16){
    int s = esrc[e]; if ((unsigned)s >= (unsigned)ns) s = 0;
    alpha[(long)e*4 + h] = __expf(lrelu(ss[(long)s*4 + h] + sdl) - m) * inv;
  }
}

// ---------------- tiled aggregation: one wave per dst ---------------------
// out[d, c0w+col] (+)= sum_e alpha[e, head(col)] * Zt[src_e, col], col<TW.
// NJ = TW/64 accumulators per lane; tile spans heads head0..head0+(TW>128).
template<int NJ>
__global__ __launch_bounds__(256) void k_agg(
    const BF16* __restrict__ Zt, const float* __restrict__ alpha,
    const int* __restrict__ indptr, const int* __restrict__ esrc,
    BF16* __restrict__ out, int ldc, int c0w, int TW, int head0,
    int accum, int n_dst, int E, int ns)
{
  int wid = (blockIdx.x*blockDim.x + threadIdx.x) >> 6;
  int lane = threadIdx.x & 63;
  if (wid >= n_dst) return;
  int e0 = indptr[wid], e1 = indptr[wid+1];
  e0 = max(0, min(e0, E)); e1 = max(e0, min(e1, E));
  float acc[NJ];
  #pragma unroll
  for (int j = 0; j < NJ; ++j) acc[j] = 0.f;
  for (int e = e0; e < e1; ++e){
    int s = esrc[e]; if ((unsigned)s >= (unsigned)ns) s = 0;
    float aA = alpha[(long)e*4 + head0];
    float aB = (NJ == 4) ? alpha[(long)e*4 + head0 + 1] : aA;
    const BF16* zr = Zt + (long)s*TW;
    #pragma unroll
    for (int j = 0; j < NJ; ++j){
      int col = lane + 64*j;
      if (col < TW){
        float a = (NJ == 4 && j >= 2) ? aB : aA;
        acc[j] += a * ldE(zr, col);
      }
    }
  }
  #pragma unroll
  for (int j = 0; j < NJ; ++j){
    int col = lane + 64*j;
    if (col < TW){
      long idx = (long)wid*ldc + c0w + col;
      float v = acc[j];
      if (accum) v += ldE(out, idx);
      stE(out, idx, v);
    }
  }
}

// ---------------- BN stats over nw_tile [N, TW] bf16 ----------------------
__global__ void k_bnp(const BF16* __restrict__ nw, float* __restrict__ bnp,
                      int N, int TW, int P)
{
  int col  = threadIdx.x & (TW - 1);
  int slot = threadIdx.x / TW;
  int rpb  = 256 / TW;
  int p    = blockIdx.x*rpb + slot;
  float s = 0.f, s2 = 0.f;
  for (long r = p; r < N; r += P){
    float v = ldE(nw, r*TW + col);
    s += v; s2 += v*v;
  }
  bnp[(long)p*2*TW + col]      = s;
  bnp[(long)p*2*TW + TW + col] = s2;
}
__global__ void k_bnf(const float* __restrict__ bnp, float* __restrict__ bns,
                      int P, int TW)
{
  for (int c = threadIdx.x; c < 2*TW; c += 256){
    float s = 0.f;
    for (int p = 0; p < P; ++p) s += bnp[(long)p*2*TW + c];
    bns[c] = s;
  }
}
__global__ void k_bn_apply(const BF16* __restrict__ nw, const float* __restrict__ bns,
                           const float* __restrict__ g, const float* __restrict__ b,
                           BF16* __restrict__ A, int N, int TW, int c0, int res)
{
  long total = (long)N*TW;
  for (long i = (long)blockIdx.x*blockDim.x + threadIdx.x; i < total;
       i += (long)gridDim.x*blockDim.x){
    int col = (int)(i % TW);
    long r  = i / TW;
    float mu  = bns[col] / (float)N;
    float var = bns[TW + col] / (float)N - mu*mu;
    int gc = c0 + col;
    float sc = g[gc] * rsqrtf(var + 1e-5f);
    float sh = b[gc] - mu*sc;
    float v = fmaxf(ldE(nw, i)*sc + sh, 0.f);
    long ai = r*512 + gc;
    if (res) v += ldE(A, ai);
    stE(A, ai, v);
  }
}

// ---------------- acc/mer update ----------------
__global__ void k_update(const BF16* __restrict__ B, const float* __restrict__ ab1,
                         const float* __restrict__ ab2, BF16* __restrict__ A,
                         long n512, int res)
{
  for (long i = (long)blockIdx.x*blockDim.x + threadIdx.x; i < n512;
       i += (long)gridDim.x*blockDim.x){
    int c = (int)(i & 511);
    float v = ldE(B, i) + ab1[c] + (ab2 ? ab2[c] : 0.f);
    v = fmaxf(v, 0.f);
    if (res) v += ldE(A, i);
    stE(A, i, v);
  }
}

// ---------------- head logits (hidden in bf16) ----------------
__global__ void k_logits(const BF16* __restrict__ Hid, const float* __restrict__ Wh2,
                         const float* __restrict__ bh2, float* __restrict__ out, int N)
{
  int node = (blockIdx.x*blockDim.x + threadIdx.x) >> 6;
  int lane = threadIdx.x & 63;
  if (node >= N) return;
  float v = ldE(Hid, (long)node*64 + lane) * Wh2[lane];
  #pragma unroll
  for (int off = 32; off; off >>= 1) v += __shfl_down(v, off, 64);
  if (lane == 0) out[node] = v + bh2[0];
}

// ---------------------------------------------------------------------------
struct Arena {
  BF16 *A[3];
  BF16 *Bst[3];
  BF16 *Zt;        // [maxN, TW]
  BF16 *nwtile;    // [nTx, TW]
  BF16 *hidden;    // [nTx, 64]
  float *alpha;    // 3 x [E,4]
  float *ss, *sd, *fs, *fd, *bnp, *bns;
  int *counts, *bsums;
  int *indptr[6], *esrc[6];
  BF16 *Wt0[6], *WtL[2][6], *Wh1t;
  size_t total;
};

extern "C" void kernel_launch(void* const* d_in, const int* in_sizes, int n_in,
                              void* d_out, int out_size, void* d_ws, size_t ws_size,
                              hipStream_t stream)
{
  const float* x_tx  = (const float*)d_in[0];
  const float* x_acc = (const float*)d_in[1];
  const float* x_mer = (const float*)d_in[2];
  const float* Wtx = (const float*)d_in[3];  const float* btx  = (const float*)d_in[4];
  const float* Wacc= (const float*)d_in[5];  const float* bacc = (const float*)d_in[6];
  const float* Wmer= (const float*)d_in[7];  const float* bmer = (const float*)d_in[8];
  const float* W0   = (const float*)d_in[9];
  const float* Wrest= (const float*)d_in[10];
  const float* att_s= (const float*)d_in[11];
  const float* att_d= (const float*)d_in[12];
  const float* att_b= (const float*)d_in[13];
  const float* bn_g = (const float*)d_in[14];
  const float* bn_b = (const float*)d_in[15];
  const float* Wh1  = (const float*)d_in[16]; const float* bh1 = (const float*)d_in[17];
  const float* Wh2  = (const float*)d_in[18]; const float* bh2 = (const float*)d_in[19];
  const int*   edges= (const int*)d_in[20];

  const int E    = in_sizes[20] / 12;
  const int nTx  = in_sizes[0] / 64;
  const int nAcc = in_sizes[1] / 32;
  const int nMer = in_sizes[2] / 32;
  const int nOf[3]   = {nTx, nAcc, nMer};
  const int SRC_T[6] = {0,0,0,1,1,2};
  const int DST_T[6] = {1,1,2,0,0,0};
  const int maxN = max(nTx, max(nAcc, nMer));
  (void)n_in;

  auto layout = [&](int TW)->Arena{
    Arena P{};
    size_t off = 0;
    auto a = [&](size_t bytes)->char*{
      char* p = (char*)d_ws + off;
      off += (bytes + 255) & ~(size_t)255;
      return p;
    };
    auto al = [](size_t b){ return (b + 255) & ~(size_t)255; };
    P.A[0]   = (BF16*)a((size_t)nTx *512*2);
    P.A[1]   = (BF16*)a((size_t)nAcc*512*2);
    P.A[2]   = (BF16*)a((size_t)nMer*512*2);
    P.Bst[1] = (BF16*)a((size_t)nAcc*512*2);
    P.Bst[2] = (BF16*)a((size_t)nMer*512*2);
    size_t zB  = al((size_t)maxN*TW*2);
    size_t nwB = al((size_t)nTx*TW*2);
    size_t hidB= al((size_t)nTx*64*2);
    size_t scr = zB + nwB;
    char* scrBase = a(scr > hidB ? scr : hidB);
    P.Zt     = (BF16*)scrBase;
    P.nwtile = (BF16*)(scrBase + zB);
    P.hidden = (BF16*)scrBase;
    P.alpha  = (float*)a((size_t)3*E*4*4);
    P.ss     = (float*)a((size_t)maxN*4*4);
    P.sd     = (float*)a((size_t)maxN*4*4);
    P.fs     = (float*)a(4*512*4);
    P.fd     = (float*)a(4*512*4);
    P.bnp    = (float*)a(262144);
    P.bns    = (float*)a(4096);
    P.counts = (int*)a((size_t)maxN*4);
    P.bsums  = (int*)a(4096);
    for (int r = 0; r < 6; ++r){
      P.indptr[r] = (int*)a((size_t)(nOf[DST_T[r]]+1)*4);
      P.esrc[r]   = (int*)a((size_t)E*4);
    }
    for (int r = 0; r < 6; ++r) P.Wt0[r] = (BF16*)a((size_t)512*128*2);
    for (int l = 0; l < 2; ++l)
      for (int r = 0; r < 6; ++r) P.WtL[l][r] = (BF16*)a((size_t)512*512*2);
    P.Wh1t = (BF16*)a((size_t)64*512*2);
    P.total = off;
    return P;
  };

  int TW = 0;
  Arena P{};
  for (int cand : {256, 128, 64, 32}){
    P = layout(cand);
    if (P.total <= ws_size){ TW = cand; break; }
  }
  if (TW == 0){
    float sentinel = 10000.0f + (float)(ws_size >> 20);
    k_fill_f32<<<dim3((out_size+255)/256), dim3(256), 0, stream>>>((float*)d_out, (long)out_size, sentinel);
    return;
  }
  const int nTiles = 512 / TW;
  const int rpb = 256 / TW, PBX = 128, Pp = PBX * rpb;
  dim3 b256(256);

  // ---- 0. weight prep: transpose+convert to bf16 [outcol][K] ----
  for (int r = 0; r < 6; ++r)
    k_wt<<<dim3(16,4), b256, 0, stream>>>(W0 + (size_t)r*128*512, P.Wt0[r], 128, 512);
  for (int l = 0; l < 2; ++l)
    for (int r = 0; r < 6; ++r)
      k_wt<<<dim3(16,16), b256, 0, stream>>>(Wrest + ((size_t)l*6 + r)*512*512, P.WtL[l][r], 512, 512);
  k_wt<<<dim3(2,16), b256, 0, stream>>>(Wh1, P.Wh1t, 512, 64);

  // MFMA proj: C[M][0..TW) (ldc=TW) = A[M][K] @ Wt[c0..c0+TW, :]^T
  auto mfma_gemm = [&](const BF16* A, const BF16* Bt, BF16* Cp, int M, int K, int c0){
    dim3 g(1, (M+127)/128);
    if (TW >= 128){
      for (int ch = 0; ch < TW; ch += 128)
        k_mfma<128,2,2,4,4,BF16><<<g,b256,0,stream>>>(A, Bt, Cp + ch, M, K, c0 + ch, TW, (const float*)nullptr, 0);
    } else if (TW == 64){
      k_mfma<64,4,1,2,4,BF16><<<g,b256,0,stream>>>(A, Bt, Cp, M, K, c0, TW, (const float*)nullptr, 0);
    } else {
      k_mfma<32,4,1,2,2,BF16><<<g,b256,0,stream>>>(A, Bt, Cp, M, K, c0, TW, (const float*)nullptr, 0);
    }
  };
  // aggregation dispatch (NJ = accumulators per lane)
  auto agg = [&](const BF16* Zt, const float* al, const int* ip, const int* es,
                 BF16* out, int ldc, int c0w, int head0, int accum, int nd, int ns){
    dim3 g((nd+3)/4);
    if (TW == 256)      k_agg<4><<<g,b256,0,stream>>>(Zt, al, ip, es, out, ldc, c0w, TW, head0, accum, nd, E, ns);
    else if (TW == 128) k_agg<2><<<g,b256,0,stream>>>(Zt, al, ip, es, out, ldc, c0w, TW, head0, accum, nd, E, ns);
    else                k_agg<1><<<g,b256,0,stream>>>(Zt, al, ip, es, out, ldc, c0w, TW, head0, accum, nd, E, ns);
  };

  // ---- 1. CSR build ----
  for (int r = 0; r < 6; ++r){
    int nd = nOf[DST_T[r]], ns = nOf[SRC_T[r]];
    const int* srcP = edges + (size_t)r*2*E;
    const int* dstP = srcP + E;
    int nb = (nd + 255)/256;
    k_zero   <<<dim3(nb),          b256, 0, stream>>>(P.counts, (long)nd);
    k_hist   <<<dim3((E+255)/256), b256, 0, stream>>>(dstP, P.counts, E, nd);
    k_scan1  <<<dim3(nb),          b256, 0, stream>>>(P.counts, P.indptr[r], P.bsums, nd);
    k_scan2  <<<dim3(1),           dim3(1024),0, stream>>>(P.bsums, nb);
    k_scan3  <<<dim3(nb),          b256, 0, stream>>>(P.indptr[r], P.bsums, nd);
    k_zero   <<<dim3(nb),          b256, 0, stream>>>(P.counts, (long)nd);
    k_scatter<<<dim3((E+255)/256), b256, 0, stream>>>(srcP, dstP, P.indptr[r], P.counts, P.esrc[r], E, nd, ns);
  }

  // ---- 2. encoders (naive f32 GEMM, tiny) ----
  k_gemm<float,BF16><<<dim3(2,(nTx +63)/64), b256, 0, stream>>>(x_tx,  Wtx,  P.A[0], nTx,  128, 64, 128, btx,  1);
  k_gemm<float,BF16><<<dim3(2,(nAcc+63)/64), b256, 0, stream>>>(x_acc, Wacc, P.A[1], nAcc, 128, 32, 128, bacc, 1);
  k_gemm<float,BF16><<<dim3(2,(nMer+63)/64), b256, 0, stream>>>(x_mer, Wmer, P.A[2], nMer, 128, 32, 128, bmer, 1);

  // ---- 3. layers ----
  for (int i = 0; i < 3; ++i){
    const int Din = (i == 0) ? 128 : 512;
    const int res = (i > 0) ? 1 : 0;
    auto Wof = [&](int r)->const float*{
      return (i == 0) ? (W0 + (size_t)r*128*512)
                      : (Wrest + ((size_t)(i-1)*6 + r)*512*512);
    };
    auto Wtof = [&](int r)->const BF16*{
      return (i == 0) ? P.Wt0[r] : P.WtL[i-1][r];
    };
    // Phase 1: dst=acc (r=0,1), dst=mer (r=2); src=tx
    for (int r = 0; r < 3; ++r){
      int dt = DST_T[r];
      int nd = nOf[dt];
      const float* as_ = att_s + ((size_t)(i*6 + r))*4*128;
      const float* ad_ = att_d + ((size_t)(i*6 + r))*4*128;
      k_fold<<<dim3((4*Din+255)/256), b256, 0, stream>>>(Wof(r), as_, P.fs, Din);
      k_fold<<<dim3((4*Din+255)/256), b256, 0, stream>>>(Wof(r), ad_, P.fd, Din);
      k_score4<<<dim3((nTx+15)/16), b256, 0, stream>>>(P.A[0], P.fs, P.ss, nTx, Din);
      k_score4<<<dim3((nd+15)/16),  b256, 0, stream>>>(P.A[dt], P.fd, P.sd, nd, Din);
      k_alpha<<<dim3((nd+3)/4), b256, 0, stream>>>(P.ss, P.sd, P.indptr[r], P.esrc[r],
                                                   P.alpha, nd, E, nTx);
      int accF = (r == 1) ? 1 : 0;
      for (int t = 0; t < nTiles; ++t){
        int c0 = t*TW;
        mfma_gemm(P.A[0], Wtof(r), P.Zt, nTx, Din, c0);
        agg(P.Zt, P.alpha, P.indptr[r], P.esrc[r], P.Bst[dt], 512, c0, c0 >> 7, accF, nd, nTx);
      }
    }
    // Phase 2: dst=tx (r=3,4,5; src=acc,acc,mer)
    for (int r = 3; r < 6; ++r){
      int st = SRC_T[r];
      int ns = nOf[st];
      const float* as_ = att_s + ((size_t)(i*6 + r))*4*128;
      const float* ad_ = att_d + ((size_t)(i*6 + r))*4*128;
      k_fold<<<dim3((4*Din+255)/256), b256, 0, stream>>>(Wof(r), as_, P.fs, Din);
      k_fold<<<dim3((4*Din+255)/256), b256, 0, stream>>>(Wof(r), ad_, P.fd, Din);
      k_score4<<<dim3((ns+15)/16),  b256, 0, stream>>>(P.A[st], P.fs, P.ss, ns, Din);
      k_score4<<<dim3((nTx+15)/16), b256, 0, stream>>>(P.A[0],  P.fd, P.sd, nTx, Din);  // OLD A_tx
      k_alpha<<<dim3((nTx+3)/4), b256, 0, stream>>>(P.ss, P.sd, P.indptr[r], P.esrc[r],
                                                    P.alpha + (size_t)(r-3)*E*4, nTx, E, ns);
    }
    for (int t = 0; t < nTiles; ++t){
      int c0 = t*TW;
      for (int r = 3; r < 6; ++r){
        int st = SRC_T[r], ns = nOf[st];
        mfma_gemm(P.A[st], Wtof(r), P.Zt, ns, Din, c0);
        agg(P.Zt, P.alpha + (size_t)(r-3)*E*4, P.indptr[r], P.esrc[r],
            P.nwtile, TW, 0, c0 >> 7, (r > 3) ? 1 : 0, nTx, ns);
      }
      k_bnp<<<dim3(PBX), b256, 0, stream>>>(P.nwtile, P.bnp, nTx, TW, Pp);
      k_bnf<<<dim3(1),   b256, 0, stream>>>(P.bnp, P.bns, Pp, TW);
      k_bn_apply<<<dim3(2048), b256, 0, stream>>>(P.nwtile, P.bns,
          bn_g + (size_t)i*512, bn_b + (size_t)i*512, P.A[0], nTx, TW, c0, res);
    }
    // Phase 3: acc/mer update
    const float* ab0 = att_b + ((size_t)(i*6 + 0))*512;
    const float* ab1 = att_b + ((size_t)(i*6 + 1))*512;
    const float* ab2 = att_b + ((size_t)(i*6 + 2))*512;
    k_update<<<dim3(2048), b256, 0, stream>>>(P.Bst[1], ab0, ab1, P.A[1], (long)nAcc*512, res);
    k_update<<<dim3(256),  b256, 0, stream>>>(P.Bst[2], ab2, (const float*)nullptr, P.A[2], (long)nMer*512, res);
  }

  // ---- 4. head: hidden = relu(h_tx @ Wh1 + bh1) via MFMA (N=64, bf16) ----
  k_mfma<64,4,1,2,4,BF16><<<dim3(1,(nTx+127)/128), b256, 0, stream>>>(
      P.A[0], P.Wh1t, P.hidden, nTx, 512, 0, 64, bh1, 1);
  k_logits<<<dim3((nTx+3)/4), b256, 0, stream>>>(P.hidden, Wh2, bh2, (float*)d_out, nTx);
}

// Round 11
// 11540.635 us; speedup vs baseline: 2.2498x; 1.0533x over previous
//
#include <hip/hip_runtime.h>
#include <math.h>

// ---------------------------------------------------------------------------
// FraudGAT: bf16 storage, MFMA projections, pre-transposed bf16 weights.
// R11 = R10 resubmitted unchanged (R10 failed on infra, no signal).
// R10 = R9 with the Phase-1 score-lifetime bug fixed: ALL alphas are computed
// before any GEMM clobbers the score overlay (scores share scratch with Zt).
// ---------------------------------------------------------------------------

typedef unsigned short BF16;
typedef short short8 __attribute__((ext_vector_type(8)));
typedef float f32x4 __attribute__((ext_vector_type(4)));
typedef __bf16 bf16x8 __attribute__((ext_vector_type(8)));

static __device__ __forceinline__ float lrelu(float x){ return x > 0.f ? x : 0.2f*x; }

__device__ __forceinline__ float ldE(const float* p, long i){ return p[i]; }
__device__ __forceinline__ float ldE(const BF16* p, long i){
  return __uint_as_float((unsigned)p[i] << 16);
}
__device__ __forceinline__ void stE(float* p, long i, float v){ p[i] = v; }
__device__ __forceinline__ void stE(BF16* p, long i, float v){
  unsigned u = __float_as_uint(v);
  p[i] = (BF16)((u + 0x7FFFu + ((u >> 16) & 1u)) >> 16);
}
__device__ __forceinline__ BF16 f2bf(float v){
  unsigned u = __float_as_uint(v);
  return (BF16)((u + 0x7FFFu + ((u >> 16) & 1u)) >> 16);
}
__device__ __forceinline__ float bf2f(short s){
  return __uint_as_float((unsigned)(unsigned short)s << 16);
}
__device__ __forceinline__ float4 ld4E(const float* p, long i){ return *(const float4*)(p + i); }
__device__ __forceinline__ float4 ld4E(const BF16* p, long i){
  ushort4 s = *(const ushort4*)(p + i);
  return make_float4(__uint_as_float((unsigned)s.x<<16), __uint_as_float((unsigned)s.y<<16),
                     __uint_as_float((unsigned)s.z<<16), __uint_as_float((unsigned)s.w<<16));
}

// ---------------- utility ----------------
__global__ void k_zero(int* __restrict__ p, long n){
  long i = (long)blockIdx.x*blockDim.x + threadIdx.x;
  if (i < n) p[i] = 0;
}
__global__ void k_fill_f32(float* __restrict__ p, long n, float v){
  long i = (long)blockIdx.x*blockDim.x + threadIdx.x;
  if (i < n) p[i] = v;
}

// ---------------- weight transpose+convert: in[K][N] f32 -> out[N][K] bf16
__global__ __launch_bounds__(256) void k_wt(const float* __restrict__ in, BF16* __restrict__ out,
                                            int K, int N)
{
  __shared__ float t[32][33];
  int kb = blockIdx.y*32, nb = blockIdx.x*32;
  int tx = threadIdx.x & 31, ty8 = threadIdx.x >> 5;
  for (int j = ty8; j < 32; j += 8){
    int k = kb + j, n = nb + tx;
    t[j][tx] = (k < K && n < N) ? in[(long)k*N + n] : 0.f;
  }
  __syncthreads();
  for (int j = ty8; j < 32; j += 8){
    int n = nb + j, k = kb + tx;
    if (n < N && k < K) out[(long)n*K + k] = f2bf(t[tx][j]);
  }
}

// ---------------- fold ALL 12 tables in one launch ------------------------
// F[((r*2+sd)*4+h)*Din + k] = sum_c W_r[k*512 + h*128 + c] * att_{sd}[r*512 + h*128 + c]
__global__ __launch_bounds__(256) void k_foldAll(
    const float* __restrict__ Wbase, long wstride,
    const float* __restrict__ atts, const float* __restrict__ attd,
    float* __restrict__ F, int Din)
{
  int w = (blockIdx.x*256 + threadIdx.x) >> 6;
  int lane = threadIdx.x & 63;
  int total = 48*Din;
  if (w >= total) return;
  int k = w % Din;
  int rem = w / Din;
  int h = rem & 3, sd = (rem >> 2) & 1, r = rem >> 3;
  const float* wr = Wbase + (long)r*wstride + (long)k*512 + h*128;
  const float* ar = (sd ? attd : atts) + r*512 + h*128;
  float p = wr[lane]*ar[lane] + wr[lane+64]*ar[lane+64];
  #pragma unroll
  for (int off = 32; off; off >>= 1) p += __shfl_down(p, off, 64);
  if (lane == 0) F[(long)((r*2+sd)*4 + h)*Din + k] = p;
}

// ---------------- MFMA GEMM: C[:, chunk] = A[M,K](bf16) @ Bt[cols,K]^T -----
template<int BN, int WM, int WN, int FM, int FN, typename TC>
__global__ __launch_bounds__(256) void k_mfma(
    const BF16* __restrict__ A, const BF16* __restrict__ Bt, TC* __restrict__ C,
    int M, int K, int c0, int ldc, const float* __restrict__ bias, int doRelu)
{
  constexpr int BM = 128;
  constexpr int LSTR = 72;
  __shared__ __attribute__((aligned(16))) short Als[BM][LSTR];
  __shared__ __attribute__((aligned(16))) short Bls[BN][LSTR];
  const int bn0 = blockIdx.x * BN;
  const int bm = blockIdx.y*BM;
  const int tid = threadIdx.x;
  const int wave = tid >> 6, lane = tid & 63;
  const int wr = wave / WN, wc = wave % WN;
  const int lrow = lane & 15, kg = lane >> 4;
  f32x4 acc[FM][FN] = {};
  for (int k0 = 0; k0 < K; k0 += 64){
    #pragma unroll
    for (int t = 0; t < 4; ++t){
      int idx = tid + t*256;
      int row = idx >> 3, kc = (idx & 7) << 3;
      int gr = bm + row;
      short8 v = {};
      if (gr < M) v = *(const short8*)(A + (long)gr*K + k0 + kc);
      *(short8*)&Als[row][kc] = v;
    }
    #pragma unroll
    for (int t = 0; t < BN/32; ++t){
      int idx = tid + t*256;
      int row = idx >> 3, kc = (idx & 7) << 3;
      *(short8*)&Bls[row][kc] = *(const short8*)(Bt + (long)(c0+bn0+row)*K + k0 + kc);
    }
    __syncthreads();
    #pragma unroll
    for (int kk = 0; kk < 2; ++kk){
      short8 af[FM], bq[FN];
      #pragma unroll
      for (int m = 0; m < FM; ++m)
        af[m] = *(const short8*)&Als[wr*FM*16 + m*16 + lrow][kk*32 + kg*8];
      #pragma unroll
      for (int n = 0; n < FN; ++n)
        bq[n] = *(const short8*)&Bls[wc*FN*16 + n*16 + lrow][kk*32 + kg*8];
      #pragma unroll
      for (int m = 0; m < FM; ++m)
        #pragma unroll
        for (int n = 0; n < FN; ++n)
          acc[m][n] = __builtin_amdgcn_mfma_f32_16x16x32_bf16(
              __builtin_bit_cast(bf16x8, af[m]), __builtin_bit_cast(bf16x8, bq[n]),
              acc[m][n], 0, 0, 0);
    }
    __syncthreads();
  }
  // epilogue: C/D layout col=lane&15, row=(lane>>4)*4+reg  [m89]
  #pragma unroll
  for (int m = 0; m < FM; ++m){
    #pragma unroll
    for (int n = 0; n < FN; ++n){
      #pragma unroll
      for (int j = 0; j < 4; ++j){
        int row = bm + wr*FM*16 + m*16 + kg*4 + j;
        if (row >= M) continue;
        int col = wc*FN*16 + n*16 + lrow;
        float v = acc[m][n][j];
        if (bias) v += bias[bn0 + col];
        if (doRelu) v = fmaxf(v, 0.f);
        stE(C, (long)row*ldc + bn0 + col, v);
      }
    }
  }
}

// ---------------- naive GEMM (f32 A) for the tiny encoders ----------------
template<typename TA, typename TC>
__global__ __launch_bounds__(256) void k_gemm(
    const TA* __restrict__ A, const float* __restrict__ B, TC* __restrict__ C,
    int M, int N, int K, int ldb, const float* __restrict__ bias, int doRelu)
{
  __shared__ float As[16][64];
  __shared__ float Bs[16][64];
  const int bm = blockIdx.y*64, bn = blockIdx.x*64;
  const int tid = threadIdx.x;
  const int ty = tid >> 4, tx = tid & 15;
  const int ar = tid >> 2;
  const int ac = (tid & 3) << 2;
  const int br = tid >> 4;
  const int bc = (tid & 15) << 2;
  float acc[4][4] = {};
  for (int k0 = 0; k0 < K; k0 += 16){
    int row = bm + ar;
    float4 av = make_float4(0.f,0.f,0.f,0.f);
    if (row < M) av = ld4E(A, (long)row*K + k0 + ac);
    As[ac+0][ar]=av.x; As[ac+1][ar]=av.y; As[ac+2][ar]=av.z; As[ac+3][ar]=av.w;
    float4 bv = make_float4(0.f,0.f,0.f,0.f);
    if (bn + bc + 3 < N) bv = *(const float4*)(B + (long)(k0+br)*ldb + bn + bc);
    *(float4*)&Bs[br][bc] = bv;
    __syncthreads();
    #pragma unroll
    for (int kk = 0; kk < 16; ++kk){
      float a[4], b[4];
      #pragma unroll
      for (int x = 0; x < 4; ++x){ a[x]=As[kk][ty*4+x]; b[x]=Bs[kk][tx*4+x]; }
      #pragma unroll
      for (int y = 0; y < 4; ++y)
        #pragma unroll
        for (int x = 0; x < 4; ++x) acc[y][x] += a[y]*b[x];
    }
    __syncthreads();
  }
  #pragma unroll
  for (int y = 0; y < 4; ++y){
    int row = bm + ty*4 + y;
    if (row >= M) continue;
    #pragma unroll
    for (int x = 0; x < 4; ++x){
      int col = bn + tx*4 + x;
      if (col >= N) continue;
      float v = acc[y][x];
      if (bias) v += bias[col];
      if (doRelu) v = fmaxf(v, 0.f);
      stE(C, (long)row*N + col, v);
    }
  }
}

// ---------------- merged scores: R relations, one pass over X -------------
template<int R>
__global__ __launch_bounds__(256) void k_scoreM(
    const BF16* __restrict__ X, const float* __restrict__ Ftab, long fstride,
    float* __restrict__ out, long ostride, int N, int Din)
{
  int wave = threadIdx.x >> 6, lane = threadIdx.x & 63;
  int node0 = blockIdx.x*16 + wave*4;
  if (node0 >= N) return;
  int base = lane*8;
  bool act = base < Din;
  float x[4][8];
  #pragma unroll
  for (int t = 0; t < 4; ++t){
    int node = node0 + t;
    if (act && node < N){
      short8 v = *(const short8*)(X + (long)node*Din + base);
      #pragma unroll
      for (int j = 0; j < 8; ++j) x[t][j] = bf2f(v[j]);
    } else {
      #pragma unroll
      for (int j = 0; j < 8; ++j) x[t][j] = 0.f;
    }
  }
  #pragma unroll
  for (int r = 0; r < R; ++r){
    const float* F = Ftab + (long)r*fstride;
    float p[4][4] = {};
    #pragma unroll
    for (int h = 0; h < 4; ++h){
      float f[8];
      if (act){
        float4 fa = *(const float4*)(F + h*Din + base);
        float4 fb = *(const float4*)(F + h*Din + base + 4);
        f[0]=fa.x; f[1]=fa.y; f[2]=fa.z; f[3]=fa.w;
        f[4]=fb.x; f[5]=fb.y; f[6]=fb.z; f[7]=fb.w;
      } else {
        #pragma unroll
        for (int j = 0; j < 8; ++j) f[j] = 0.f;
      }
      #pragma unroll
      for (int t = 0; t < 4; ++t)
        #pragma unroll
        for (int j = 0; j < 8; ++j) p[t][h] += x[t][j]*f[j];
    }
    #pragma unroll
    for (int t = 0; t < 4; ++t)
      #pragma unroll
      for (int h = 0; h < 4; ++h)
        #pragma unroll
        for (int off = 32; off; off >>= 1)
          p[t][h] += __shfl_down(p[t][h], off, 64);
    if (lane == 0){
      #pragma unroll
      for (int t = 0; t < 4; ++t){
        int node = node0 + t;
        if (node < N){
          #pragma unroll
          for (int h = 0; h < 4; ++h)
            out[(long)r*ostride + (long)node*4 + h] = p[t][h];
        }
      }
    }
  }
}

// ---------------- CSR build ----------------
__global__ void k_hist(const int* __restrict__ dst, int* __restrict__ counts, int E, int nd){
  int e = blockIdx.x*blockDim.x + threadIdx.x;
  if (e >= E) return;
  int d = dst[e];
  if ((unsigned)d < (unsigned)nd) atomicAdd(&counts[d], 1);
}
__global__ void k_scan1(const int* __restrict__ counts, int* __restrict__ indptr,
                        int* __restrict__ bsums, int n)
{
  __shared__ int sm[256];
  int i = blockIdx.x*256 + threadIdx.x;
  int v = (i < n) ? counts[i] : 0;
  sm[threadIdx.x] = v; __syncthreads();
  for (int off = 1; off < 256; off <<= 1){
    int t = (threadIdx.x >= off) ? sm[threadIdx.x - off] : 0;
    __syncthreads();
    sm[threadIdx.x] += t;
    __syncthreads();
  }
  if (i < n) indptr[i+1] = sm[threadIdx.x];
  if (threadIdx.x == 255) bsums[blockIdx.x] = sm[255];
  if (blockIdx.x == 0 && threadIdx.x == 0) indptr[0] = 0;
}
__global__ void k_scan2(int* __restrict__ bsums, int nb){
  __shared__ int sm[1024];
  int t = threadIdx.x;
  int v = (t < nb) ? bsums[t] : 0;
  sm[t] = v; __syncthreads();
  for (int off = 1; off < 1024; off <<= 1){
    int x = (t >= off) ? sm[t - off] : 0;
    __syncthreads();
    sm[t] += x;
    __syncthreads();
  }
  if (t < nb) bsums[t] = sm[t];
}
__global__ void k_scan3(int* __restrict__ indptr, const int* __restrict__ bsums, int n){
  if (blockIdx.x == 0) return;
  int i = blockIdx.x*256 + threadIdx.x;
  int add = bsums[blockIdx.x - 1];
  if (i < n) indptr[i+1] += add;
}
__global__ void k_scatter(const int* __restrict__ src, const int* __restrict__ dst,
                          const int* __restrict__ indptr, int* __restrict__ cursor,
                          int* __restrict__ esrc, int E, int nd, int ns)
{
  int e = blockIdx.x*blockDim.x + threadIdx.x;
  if (e >= E) return;
  int d = dst[e];
  if ((unsigned)d >= (unsigned)nd) return;
  int s = src[e];
  if ((unsigned)s >= (unsigned)ns) s = 0;
  int pos = indptr[d] + atomicAdd(&cursor[d], 1);
  if (pos >= 0 && pos < E) esrc[pos] = s;
}

// ---------------- per-edge alpha: one wave per dst node -------------------
__global__ __launch_bounds__(256) void k_alpha(
    const float* __restrict__ ss, const float* __restrict__ sd,
    const int* __restrict__ indptr, const int* __restrict__ esrc,
    float* __restrict__ alpha, int n_dst, int E, int ns)
{
  int wid = (blockIdx.x*blockDim.x + threadIdx.x) >> 6;
  int lane = threadIdx.x & 63;
  if (wid >= n_dst) return;
  int e0 = indptr[wid], e1 = indptr[wid+1];
  e0 = max(0, min(e0, E)); e1 = max(e0, min(e1, E));
  if (e0 >= e1) return;
  int h = lane >> 4, g = lane & 15;
  float sdl = sd[(long)wid*4 + h];
  float m = -INFINITY;
  for (int e = e0 + g; e < e1; e += 16){
    int s = esrc[e]; if ((unsigned)s >= (unsigned)ns) s = 0;
    m = fmaxf(m, lrelu(ss[(long)s*4 + h] + sdl));
  }
  #pragma unroll
  for (int o = 1; o < 16; o <<= 1) m = fmaxf(m, __shfl_xor(m, o, 16));
  float den = 0.f;
  for (int e = e0 + g; e < e1; e += 16){
    int s = esrc[e]; if ((unsigned)s >= (unsigned)ns) s = 0;
    den += __expf(lrelu(ss[(long)s*4 + h] + sdl) - m);
  }
  #pragma unroll
  for (int o = 1; o < 16; o <<= 1) den += __shfl_xor(den, o, 16);
  float inv = 1.f/(den + 1e-16f);
  for (int e = e0 + g; e < e1; e += 16){
    int s = esrc[e]; if ((unsigned)s >= (unsigned)ns) s = 0;
    alpha[(long)e*4 + h] = __expf(lrelu(ss[(long)s*4 + h] + sdl) - m) * inv;
  }
}

// ---------------- aggregation bodies ----------------
__device__ __forceinline__ void agg_body(
    const BF16* __restrict__ Zt, const float* __restrict__ alpha,
    const int* __restrict__ indptr, const int* __restrict__ esrc,
    float* acc, int NJ, int wid, int lane, int TW, int head0, int E, int ns)
{
  int e0 = indptr[wid], e1 = indptr[wid+1];
  e0 = max(0, min(e0, E)); e1 = max(e0, min(e1, E));
  for (int e = e0; e < e1; ++e){
    int s = esrc[e]; if ((unsigned)s >= (unsigned)ns) s = 0;
    float aA = alpha[(long)e*4 + head0];
    float aB = (NJ == 4) ? alpha[(long)e*4 + head0 + 1] : aA;
    const BF16* zr = Zt + (long)s*TW;
    #pragma unroll 4
    for (int j = 0; j < NJ; ++j){
      int col = lane + 64*j;
      if (col < TW) acc[j] += ((NJ == 4 && j >= 2) ? aB : aA) * ldE(zr, col);
    }
  }
}
template<int NJ>
__global__ __launch_bounds__(256) void k_agg(
    const BF16* __restrict__ Zt, const float* __restrict__ alpha,
    const int* __restrict__ indptr, const int* __restrict__ esrc,
    BF16* __restrict__ out, int ldc, int c0w, int TW, int head0,
    int accum, int n_dst, int E, int ns)
{
  int wid = (blockIdx.x*blockDim.x + threadIdx.x) >> 6;
  int lane = threadIdx.x & 63;
  if (wid >= n_dst) return;
  float acc[NJ];
  #pragma unroll
  for (int j = 0; j < NJ; ++j) acc[j] = 0.f;
  agg_body(Zt, alpha, indptr, esrc, acc, NJ, wid, lane, TW, head0, E, ns);
  #pragma unroll
  for (int j = 0; j < NJ; ++j){
    int col = lane + 64*j;
    if (col < TW){
      long idx = (long)wid*ldc + c0w + col;
      float v = acc[j];
      if (accum) v += ldE(out, idx);
      stE(out, idx, v);
    }
  }
}

// ---------------- fused 3-relation aggregation (phase 2, dst=tx) ----------
template<int NJ>
__global__ __launch_bounds__(256) void k_agg3(
    const BF16* __restrict__ Z0, const BF16* __restrict__ Z1, const BF16* __restrict__ Z2,
    const float* __restrict__ a0, const float* __restrict__ a1, const float* __restrict__ a2,
    const int* __restrict__ ip0, const int* __restrict__ ip1, const int* __restrict__ ip2,
    const int* __restrict__ es0, const int* __restrict__ es1, const int* __restrict__ es2,
    BF16* __restrict__ out, int ldc, int TW, int head0,
    int n_dst, int E, int ns0, int ns1, int ns2)
{
  int wid = (blockIdx.x*blockDim.x + threadIdx.x) >> 6;
  int lane = threadIdx.x & 63;
  if (wid >= n_dst) return;
  float acc[NJ];
  #pragma unroll
  for (int j = 0; j < NJ; ++j) acc[j] = 0.f;
  agg_body(Z0, a0, ip0, es0, acc, NJ, wid, lane, TW, head0, E, ns0);
  agg_body(Z1, a1, ip1, es1, acc, NJ, wid, lane, TW, head0, E, ns1);
  agg_body(Z2, a2, ip2, es2, acc, NJ, wid, lane, TW, head0, E, ns2);
  #pragma unroll
  for (int j = 0; j < NJ; ++j){
    int col = lane + 64*j;
    if (col < TW) stE(out, (long)wid*ldc + col, acc[j]);
  }
}

// ---------------- BN stats over nw_tile [N, TW] bf16 ----------------------
__global__ void k_bnp(const BF16* __restrict__ nw, float* __restrict__ bnp,
                      int N, int TW, int P)
{
  int col  = threadIdx.x & (TW - 1);
  int slot = threadIdx.x / TW;
  int rpb  = 256 / TW;
  int p    = blockIdx.x*rpb + slot;
  float s = 0.f, s2 = 0.f;
  for (long r = p; r < N; r += P){
    float v = ldE(nw, r*TW + col);
    s += v; s2 += v*v;
  }
  bnp[(long)p*2*TW + col]      = s;
  bnp[(long)p*2*TW + TW + col] = s2;
}
__global__ void k_bnf(const float* __restrict__ bnp, float* __restrict__ bns,
                      int P, int TW)
{
  int c = blockIdx.x*256 + threadIdx.x;
  if (c >= 2*TW) return;
  float s = 0.f;
  for (int p = 0; p < P; ++p) s += bnp[(long)p*2*TW + c];
  bns[c] = s;
}
__global__ void k_bn_apply(const BF16* __restrict__ nw, const float* __restrict__ bns,
                           const float* __restrict__ g, const float* __restrict__ b,
                           BF16* __restrict__ A, int N, int TW, int c0, int res)
{
  long total = (long)N*TW;
  for (long i = (long)blockIdx.x*blockDim.x + threadIdx.x; i < total;
       i += (long)gridDim.x*blockDim.x){
    int col = (int)(i % TW);
    long r  = i / TW;
    float mu  = bns[col] / (float)N;
    float var = bns[TW + col] / (float)N - mu*mu;
    int gc = c0 + col;
    float sc = g[gc] * rsqrtf(var + 1e-5f);
    float sh = b[gc] - mu*sc;
    float v = fmaxf(ldE(nw, i)*sc + sh, 0.f);
    long ai = r*512 + gc;
    if (res) v += ldE(A, ai);
    stE(A, ai, v);
  }
}

// ---------------- acc/mer update ----------------
__global__ void k_update(const BF16* __restrict__ B, const float* __restrict__ ab1,
                         const float* __restrict__ ab2, BF16* __restrict__ A,
                         long n512, int res)
{
  for (long i = (long)blockIdx.x*blockDim.x + threadIdx.x; i < n512;
       i += (long)gridDim.x*blockDim.x){
    int c = (int)(i & 511);
    float v = ldE(B, i) + ab1[c] + (ab2 ? ab2[c] : 0.f);
    v = fmaxf(v, 0.f);
    if (res) v += ldE(A, i);
    stE(A, i, v);
  }
}

// ---------------- head logits ----------------
__global__ void k_logits(const BF16* __restrict__ Hid, const float* __restrict__ Wh2,
                         const float* __restrict__ bh2, float* __restrict__ out, int N)
{
  int node = (blockIdx.x*blockDim.x + threadIdx.x) >> 6;
  int lane = threadIdx.x & 63;
  if (node >= N) return;
  float v = ldE(Hid, (long)node*64 + lane) * Wh2[lane];
  #pragma unroll
  for (int off = 32; off; off >>= 1) v += __shfl_down(v, off, 64);
  if (lane == 0) out[node] = v + bh2[0];
}

// ---------------------------------------------------------------------------
struct Arena {
  BF16 *A[3];
  BF16 *Bst[3];
  BF16 *Zt;        // scratch: phase1 [maxN,TW]; phase2 Z3/Z4/Z5 sub-blocks
  BF16 *nwtile;    // [nTx, TW]
  BF16 *hidden;    // [nTx, 64]
  float *scoreS, *scoreD;  // 3 slots each, overlaid on scratch
  float *alpha;    // 3 x [E,4]
  float *Fbuf;     // 6*8*512 f32 fold tables
  float *bnp, *bns;
  int *counts, *bsums;
  int *indptr[6], *esrc[6];
  BF16 *Wt0[6], *WtL[2][6], *Wh1t;
  size_t total;
};

extern "C" void kernel_launch(void* const* d_in, const int* in_sizes, int n_in,
                              void* d_out, int out_size, void* d_ws, size_t ws_size,
                              hipStream_t stream)
{
  const float* x_tx  = (const float*)d_in[0];
  const float* x_acc = (const float*)d_in[1];
  const float* x_mer = (const float*)d_in[2];
  const float* Wtx = (const float*)d_in[3];  const float* btx  = (const float*)d_in[4];
  const float* Wacc= (const float*)d_in[5];  const float* bacc = (const float*)d_in[6];
  const float* Wmer= (const float*)d_in[7];  const float* bmer = (const float*)d_in[8];
  const float* W0   = (const float*)d_in[9];
  const float* Wrest= (const float*)d_in[10];
  const float* att_s= (const float*)d_in[11];
  const float* att_d= (const float*)d_in[12];
  const float* att_b= (const float*)d_in[13];
  const float* bn_g = (const float*)d_in[14];
  const float* bn_b = (const float*)d_in[15];
  const float* Wh1  = (const float*)d_in[16]; const float* bh1 = (const float*)d_in[17];
  const float* Wh2  = (const float*)d_in[18]; const float* bh2 = (const float*)d_in[19];
  const int*   edges= (const int*)d_in[20];

  const int E    = in_sizes[20] / 12;
  const int nTx  = in_sizes[0] / 64;
  const int nAcc = in_sizes[1] / 32;
  const int nMer = in_sizes[2] / 32;
  const int nOf[3]   = {nTx, nAcc, nMer};
  const int SRC_T[6] = {0,0,0,1,1,2};
  const int DST_T[6] = {1,1,2,0,0,0};
  const int maxN = max(nTx, max(nAcc, nMer));
  (void)n_in;

  auto layout = [&](int TW)->Arena{
    Arena P{};
    size_t off = 0;
    auto a = [&](size_t bytes)->char*{
      char* p = (char*)d_ws + off;
      off += (bytes + 255) & ~(size_t)255;
      return p;
    };
    auto al = [](size_t b){ return (b + 255) & ~(size_t)255; };
    P.A[0]   = (BF16*)a((size_t)nTx *512*2);
    P.A[1]   = (BF16*)a((size_t)nAcc*512*2);
    P.A[2]   = (BF16*)a((size_t)nMer*512*2);
    P.Bst[1] = (BF16*)a((size_t)nAcc*512*2);
    P.Bst[2] = (BF16*)a((size_t)nMer*512*2);
    size_t zrows = (size_t)maxN > (size_t)2*nAcc + nMer ? (size_t)maxN : (size_t)2*nAcc + nMer;
    size_t zB  = al(zrows*TW*2);
    size_t nwB = al((size_t)nTx*TW*2);
    size_t scoreB = al((size_t)3*maxN*4*4)*2;       // scoreS + scoreD overlay
    size_t hidB= al((size_t)nTx*64*2);
    size_t scr = zB + nwB;
    if (scr < scoreB) scr = scoreB;
    if (scr < hidB)   scr = hidB;
    char* scrBase = a(scr);
    P.Zt     = (BF16*)scrBase;
    P.nwtile = (BF16*)(scrBase + zB);
    P.scoreS = (float*)scrBase;          // valid only BEFORE Zt writes (alphas hoisted)
    P.scoreD = (float*)(scrBase + al((size_t)3*maxN*4*4));
    P.hidden = (BF16*)scrBase;
    P.alpha  = (float*)a((size_t)3*E*4*4);
    P.Fbuf   = (float*)a((size_t)6*8*512*4);
    P.bnp    = (float*)a(262144);
    P.bns    = (float*)a(4096);
    P.counts = (int*)a((size_t)maxN*4);
    P.bsums  = (int*)a(4096);
    for (int r = 0; r < 6; ++r){
      P.indptr[r] = (int*)a((size_t)(nOf[DST_T[r]]+1)*4);
      P.esrc[r]   = (int*)a((size_t)E*4);
    }
    for (int r = 0; r < 6; ++r) P.Wt0[r] = (BF16*)a((size_t)512*128*2);
    for (int l = 0; l < 2; ++l)
      for (int r = 0; r < 6; ++r) P.WtL[l][r] = (BF16*)a((size_t)512*512*2);
    P.Wh1t = (BF16*)a((size_t)64*512*2);
    P.total = off;
    return P;
  };

  int TW = 0;
  Arena P{};
  for (int cand : {256, 128, 64}){
    P = layout(cand);
    if (P.total <= ws_size){ TW = cand; break; }
  }
  if (TW == 0){
    float sentinel = 10000.0f + (float)(ws_size >> 20);
    k_fill_f32<<<dim3((out_size+255)/256), dim3(256), 0, stream>>>((float*)d_out, (long)out_size, sentinel);
    return;
  }
  const int nTiles = 512 / TW;
  const int NJv = TW/64;
  const int rpb = 256 / TW, PBX = 128, Pp = PBX * rpb;
  dim3 b256(256);

  // ---- 0. weight prep ----
  for (int r = 0; r < 6; ++r)
    k_wt<<<dim3(16,4), b256, 0, stream>>>(W0 + (size_t)r*128*512, P.Wt0[r], 128, 512);
  for (int l = 0; l < 2; ++l)
    for (int r = 0; r < 6; ++r)
      k_wt<<<dim3(16,16), b256, 0, stream>>>(Wrest + ((size_t)l*6 + r)*512*512, P.WtL[l][r], 512, 512);
  k_wt<<<dim3(2,16), b256, 0, stream>>>(Wh1, P.Wh1t, 512, 64);

  auto mfma_gemm = [&](const BF16* A, const BF16* Bt, BF16* Cp, int M, int K, int c0, int ldc){
    if (TW >= 128)
      k_mfma<128,2,2,4,4,BF16><<<dim3(TW/128,(M+127)/128),b256,0,stream>>>(A, Bt, Cp, M, K, c0, ldc, (const float*)nullptr, 0);
    else
      k_mfma<64,4,1,2,4,BF16><<<dim3(1,(M+127)/128),b256,0,stream>>>(A, Bt, Cp, M, K, c0, ldc, (const float*)nullptr, 0);
  };
  auto agg1 = [&](const BF16* Zt, const float* al, const int* ip, const int* es,
                  BF16* out, int ldc, int c0w, int head0, int accum, int nd, int ns){
    dim3 g((nd+3)/4);
    if (NJv == 4)      k_agg<4><<<g,b256,0,stream>>>(Zt, al, ip, es, out, ldc, c0w, TW, head0, accum, nd, E, ns);
    else if (NJv == 2) k_agg<2><<<g,b256,0,stream>>>(Zt, al, ip, es, out, ldc, c0w, TW, head0, accum, nd, E, ns);
    else               k_agg<1><<<g,b256,0,stream>>>(Zt, al, ip, es, out, ldc, c0w, TW, head0, accum, nd, E, ns);
  };

  // ---- 1. CSR build ----
  for (int r = 0; r < 6; ++r){
    int nd = nOf[DST_T[r]], ns = nOf[SRC_T[r]];
    const int* srcP = edges + (size_t)r*2*E;
    const int* dstP = srcP + E;
    int nb = (nd + 255)/256;
    k_zero   <<<dim3(nb),          b256, 0, stream>>>(P.counts, (long)nd);
    k_hist   <<<dim3((E+255)/256), b256, 0, stream>>>(dstP, P.counts, E, nd);
    k_scan1  <<<dim3(nb),          b256, 0, stream>>>(P.counts, P.indptr[r], P.bsums, nd);
    k_scan2  <<<dim3(1),           dim3(1024),0, stream>>>(P.bsums, nb);
    k_scan3  <<<dim3(nb),          b256, 0, stream>>>(P.indptr[r], P.bsums, nd);
    k_zero   <<<dim3(nb),          b256, 0, stream>>>(P.counts, (long)nd);
    k_scatter<<<dim3((E+255)/256), b256, 0, stream>>>(srcP, dstP, P.indptr[r], P.counts, P.esrc[r], E, nd, ns);
  }

  // ---- 2. encoders ----
  k_gemm<float,BF16><<<dim3(2,(nTx +63)/64), b256, 0, stream>>>(x_tx,  Wtx,  P.A[0], nTx,  128, 64, 128, btx,  1);
  k_gemm<float,BF16><<<dim3(2,(nAcc+63)/64), b256, 0, stream>>>(x_acc, Wacc, P.A[1], nAcc, 128, 32, 128, bacc, 1);
  k_gemm<float,BF16><<<dim3(2,(nMer+63)/64), b256, 0, stream>>>(x_mer, Wmer, P.A[2], nMer, 128, 32, 128, bmer, 1);

  const long mS = (long)maxN*4;   // score slot stride (elems)
  // ---- 3. layers ----
  for (int i = 0; i < 3; ++i){
    const int Din = (i == 0) ? 128 : 512;
    const int res = (i > 0) ? 1 : 0;
    const long fstr = 8L*Din;
    const float* WbaseL = (i == 0) ? W0 : (Wrest + (size_t)(i-1)*6*512*512);
    const long wstride = (i == 0) ? 128L*512 : 512L*512;
    auto Wtof = [&](int r)->const BF16*{ return (i == 0) ? P.Wt0[r] : P.WtL[i-1][r]; };

    // fold all 12 tables (1 launch)
    k_foldAll<<<dim3(48*Din/4), b256, 0, stream>>>(WbaseL, wstride,
        att_s + (size_t)i*6*512, att_d + (size_t)i*6*512, P.Fbuf, Din);

    // ---- Phase 1 (dst=acc r=0,1; dst=mer r=2; src=tx) ----
    // scores, then ALL alphas (scores live in the Zt-overlay; must finish
    // before the first GEMM clobbers them -- this was R9's bug)
    k_scoreM<3><<<dim3((nTx+15)/16), b256, 0, stream>>>(P.A[0], P.Fbuf,           fstr, P.scoreS, mS, nTx, Din);
    k_scoreM<2><<<dim3((nAcc+15)/16), b256, 0, stream>>>(P.A[1], P.Fbuf + 4*Din,  fstr, P.scoreD, mS, nAcc, Din);
    k_scoreM<1><<<dim3((nMer+15)/16), b256, 0, stream>>>(P.A[2], P.Fbuf + 20*Din, fstr, P.scoreD + 2*mS, 0, nMer, Din);
    for (int r = 0; r < 3; ++r){
      int nd = nOf[DST_T[r]];
      k_alpha<<<dim3((nd+3)/4), b256, 0, stream>>>(P.scoreS + r*mS, P.scoreD + r*mS,
          P.indptr[r], P.esrc[r], P.alpha + (size_t)r*E*4, nd, E, nTx);
    }
    for (int r = 0; r < 3; ++r){
      int dt = DST_T[r], nd = nOf[dt];
      int accF = (r == 1) ? 1 : 0;
      for (int t = 0; t < nTiles; ++t){
        int c0 = t*TW;
        mfma_gemm(P.A[0], Wtof(r), P.Zt, nTx, Din, c0, TW);
        agg1(P.Zt, P.alpha + (size_t)r*E*4, P.indptr[r], P.esrc[r],
             P.Bst[dt], 512, c0, c0 >> 7, accF, nd, nTx);
      }
    }

    // ---- Phase 2 (dst=tx; src=acc r=3,4; mer r=5) ----
    k_scoreM<2><<<dim3((nAcc+15)/16), b256, 0, stream>>>(P.A[1], P.Fbuf + 24*Din, fstr, P.scoreS, mS, nAcc, Din);
    k_scoreM<1><<<dim3((nMer+15)/16), b256, 0, stream>>>(P.A[2], P.Fbuf + 40*Din, fstr, P.scoreS + 2*mS, 0, nMer, Din);
    k_scoreM<3><<<dim3((nTx+15)/16), b256, 0, stream>>>(P.A[0], P.Fbuf + 28*Din, fstr, P.scoreD, mS, nTx, Din);
    for (int q = 0; q < 3; ++q){
      int r = 3 + q;
      k_alpha<<<dim3((nTx+3)/4), b256, 0, stream>>>(P.scoreS + q*mS, P.scoreD + q*mS,
          P.indptr[r], P.esrc[r], P.alpha + (size_t)q*E*4, nTx, E, nOf[SRC_T[r]]);
    }
    BF16* Z3 = P.Zt;
    BF16* Z4 = P.Zt + (size_t)nAcc*TW;
    BF16* Z5 = P.Zt + (size_t)2*nAcc*TW;
    for (int t = 0; t < nTiles; ++t){
      int c0 = t*TW;
      mfma_gemm(P.A[1], Wtof(3), Z3, nAcc, Din, c0, TW);
      mfma_gemm(P.A[1], Wtof(4), Z4, nAcc, Din, c0, TW);
      mfma_gemm(P.A[2], Wtof(5), Z5, nMer, Din, c0, TW);
      dim3 ga((nTx+3)/4);
      if (NJv == 4)
        k_agg3<4><<<ga,b256,0,stream>>>(Z3,Z4,Z5, P.alpha, P.alpha+(size_t)E*4, P.alpha+(size_t)2*E*4,
            P.indptr[3],P.indptr[4],P.indptr[5], P.esrc[3],P.esrc[4],P.esrc[5],
            P.nwtile, TW, TW, c0>>7, nTx, E, nAcc, nAcc, nMer);
      else if (NJv == 2)
        k_agg3<2><<<ga,b256,0,stream>>>(Z3,Z4,Z5, P.alpha, P.alpha+(size_t)E*4, P.alpha+(size_t)2*E*4,
            P.indptr[3],P.indptr[4],P.indptr[5], P.esrc[3],P.esrc[4],P.esrc[5],
            P.nwtile, TW, TW, c0>>7, nTx, E, nAcc, nAcc, nMer);
      else
        k_agg3<1><<<ga,b256,0,stream>>>(Z3,Z4,Z5, P.alpha, P.alpha+(size_t)E*4, P.alpha+(size_t)2*E*4,
            P.indptr[3],P.indptr[4],P.indptr[5], P.esrc[3],P.esrc[4],P.esrc[5],
            P.nwtile, TW, TW, c0>>7, nTx, E, nAcc, nAcc, nMer);
      k_bnp<<<dim3(PBX), b256, 0, stream>>>(P.nwtile, P.bnp, nTx, TW, Pp);
      k_bnf<<<dim3((2*TW+255)/256), b256, 0, stream>>>(P.bnp, P.bns, Pp, TW);
      k_bn_apply<<<dim3(2048), b256, 0, stream>>>(P.nwtile, P.bns,
          bn_g + (size_t)i*512, bn_b + (size_t)i*512, P.A[0], nTx, TW, c0, res);
    }
    // ---- Phase 3 ----
    const float* ab0 = att_b + ((size_t)(i*6 + 0))*512;
    const float* ab1 = att_b + ((size_t)(i*6 + 1))*512;
    const float* ab2 = att_b + ((size_t)(i*6 + 2))*512;
    k_update<<<dim3(2048), b256, 0, stream>>>(P.Bst[1], ab0, ab1, P.A[1], (long)nAcc*512, res);
    k_update<<<dim3(256),  b256, 0, stream>>>(P.Bst[2], ab2, (const float*)nullptr, P.A[2], (long)nMer*512, res);
  }

  // ---- 4. head ----
  k_mfma<64,4,1,2,4,BF16><<<dim3(1,(nTx+127)/128), b256, 0, stream>>>(
      P.A[0], P.Wh1t, P.hidden, nTx, 512, 0, 64, bh1, 1);
  k_logits<<<dim3((nTx+3)/4), b256, 0, stream>>>(P.hidden, Wh2, bh2, (float*)d_out, nTx);
}

// Round 13
// 10727.578 us; speedup vs baseline: 2.4203x; 1.0758x over previous
//
#include <hip/hip_runtime.h>
#include <math.h>

// ---------------------------------------------------------------------------
// FraudGAT: bf16 storage, MFMA projections, pre-transposed bf16 weights.
// R13 = R12 resubmitted unchanged (R12 failed on infra, no signal).
// R12 = R11 + (a) relation tx->mer aggregated FIRST in input space
// (G[d,h,:] = sum alpha*A[src]; out = G_h @ W cols h) -- GEMM M drops
// 100k -> 5k for that relation; (b) fused 2-relation agg2 for dst=acc
// (no accumulate read-back). Footprint unchanged (~227 MB, TW=128 tier).
// ---------------------------------------------------------------------------

typedef unsigned short BF16;
typedef short short8 __attribute__((ext_vector_type(8)));
typedef float f32x4 __attribute__((ext_vector_type(4)));
typedef __bf16 bf16x8 __attribute__((ext_vector_type(8)));

static __device__ __forceinline__ float lrelu(float x){ return x > 0.f ? x : 0.2f*x; }

__device__ __forceinline__ float ldE(const float* p, long i){ return p[i]; }
__device__ __forceinline__ float ldE(const BF16* p, long i){
  return __uint_as_float((unsigned)p[i] << 16);
}
__device__ __forceinline__ void stE(float* p, long i, float v){ p[i] = v; }
__device__ __forceinline__ void stE(BF16* p, long i, float v){
  unsigned u = __float_as_uint(v);
  p[i] = (BF16)((u + 0x7FFFu + ((u >> 16) & 1u)) >> 16);
}
__device__ __forceinline__ BF16 f2bf(float v){
  unsigned u = __float_as_uint(v);
  return (BF16)((u + 0x7FFFu + ((u >> 16) & 1u)) >> 16);
}
__device__ __forceinline__ float bf2f(short s){
  return __uint_as_float((unsigned)(unsigned short)s << 16);
}
__device__ __forceinline__ float4 ld4E(const float* p, long i){ return *(const float4*)(p + i); }
__device__ __forceinline__ float4 ld4E(const BF16* p, long i){
  ushort4 s = *(const ushort4*)(p + i);
  return make_float4(__uint_as_float((unsigned)s.x<<16), __uint_as_float((unsigned)s.y<<16),
                     __uint_as_float((unsigned)s.z<<16), __uint_as_float((unsigned)s.w<<16));
}

// ---------------- utility ----------------
__global__ void k_zero(int* __restrict__ p, long n){
  long i = (long)blockIdx.x*blockDim.x + threadIdx.x;
  if (i < n) p[i] = 0;
}
__global__ void k_fill_f32(float* __restrict__ p, long n, float v){
  long i = (long)blockIdx.x*blockDim.x + threadIdx.x;
  if (i < n) p[i] = v;
}

// ---------------- weight transpose+convert: in[K][N] f32 -> out[N][K] bf16
__global__ __launch_bounds__(256) void k_wt(const float* __restrict__ in, BF16* __restrict__ out,
                                            int K, int N)
{
  __shared__ float t[32][33];
  int kb = blockIdx.y*32, nb = blockIdx.x*32;
  int tx = threadIdx.x & 31, ty8 = threadIdx.x >> 5;
  for (int j = ty8; j < 32; j += 8){
    int k = kb + j, n = nb + tx;
    t[j][tx] = (k < K && n < N) ? in[(long)k*N + n] : 0.f;
  }
  __syncthreads();
  for (int j = ty8; j < 32; j += 8){
    int n = nb + j, k = kb + tx;
    if (n < N && k < K) out[(long)n*K + k] = f2bf(t[tx][j]);
  }
}

// ---------------- fold ALL 12 tables in one launch ------------------------
__global__ __launch_bounds__(256) void k_foldAll(
    const float* __restrict__ Wbase, long wstride,
    const float* __restrict__ atts, const float* __restrict__ attd,
    float* __restrict__ F, int Din)
{
  int w = (blockIdx.x*256 + threadIdx.x) >> 6;
  int lane = threadIdx.x & 63;
  int total = 48*Din;
  if (w >= total) return;
  int k = w % Din;
  int rem = w / Din;
  int h = rem & 3, sd = (rem >> 2) & 1, r = rem >> 3;
  const float* wr = Wbase + (long)r*wstride + (long)k*512 + h*128;
  const float* ar = (sd ? attd : atts) + r*512 + h*128;
  float p = wr[lane]*ar[lane] + wr[lane+64]*ar[lane+64];
  #pragma unroll
  for (int off = 32; off; off >>= 1) p += __shfl_down(p, off, 64);
  if (lane == 0) F[(long)((r*2+sd)*4 + h)*Din + k] = p;
}

// ---------------- MFMA GEMM: C[:, chunk] = A[M,K](bf16) @ Bt[cols,K]^T -----
// A row stride = lda. C row stride = ldc, col offset bn0. Optional accumulate.
template<int BN, int WM, int WN, int FM, int FN, typename TC>
__global__ __launch_bounds__(256) void k_mfma(
    const BF16* __restrict__ A, const BF16* __restrict__ Bt, TC* __restrict__ C,
    int M, int K, int c0, int ldc, int lda, const float* __restrict__ bias,
    int doRelu, int accum)
{
  constexpr int BM = 128;
  constexpr int LSTR = 72;
  __shared__ __attribute__((aligned(16))) short Als[BM][LSTR];
  __shared__ __attribute__((aligned(16))) short Bls[BN][LSTR];
  const int bn0 = blockIdx.x * BN;
  const int bm = blockIdx.y*BM;
  const int tid = threadIdx.x;
  const int wave = tid >> 6, lane = tid & 63;
  const int wr = wave / WN, wc = wave % WN;
  const int lrow = lane & 15, kg = lane >> 4;
  f32x4 acc[FM][FN] = {};
  for (int k0 = 0; k0 < K; k0 += 64){
    #pragma unroll
    for (int t = 0; t < 4; ++t){
      int idx = tid + t*256;
      int row = idx >> 3, kc = (idx & 7) << 3;
      int gr = bm + row;
      short8 v = {};
      if (gr < M) v = *(const short8*)(A + (long)gr*lda + k0 + kc);
      *(short8*)&Als[row][kc] = v;
    }
    #pragma unroll
    for (int t = 0; t < BN/32; ++t){
      int idx = tid + t*256;
      int row = idx >> 3, kc = (idx & 7) << 3;
      *(short8*)&Bls[row][kc] = *(const short8*)(Bt + (long)(c0+bn0+row)*K + k0 + kc);
    }
    __syncthreads();
    #pragma unroll
    for (int kk = 0; kk < 2; ++kk){
      short8 af[FM], bq[FN];
      #pragma unroll
      for (int m = 0; m < FM; ++m)
        af[m] = *(const short8*)&Als[wr*FM*16 + m*16 + lrow][kk*32 + kg*8];
      #pragma unroll
      for (int n = 0; n < FN; ++n)
        bq[n] = *(const short8*)&Bls[wc*FN*16 + n*16 + lrow][kk*32 + kg*8];
      #pragma unroll
      for (int m = 0; m < FM; ++m)
        #pragma unroll
        for (int n = 0; n < FN; ++n)
          acc[m][n] = __builtin_amdgcn_mfma_f32_16x16x32_bf16(
              __builtin_bit_cast(bf16x8, af[m]), __builtin_bit_cast(bf16x8, bq[n]),
              acc[m][n], 0, 0, 0);
    }
    __syncthreads();
  }
  // epilogue: C/D layout col=lane&15, row=(lane>>4)*4+reg  [m89]
  #pragma unroll
  for (int m = 0; m < FM; ++m){
    #pragma unroll
    for (int n = 0; n < FN; ++n){
      #pragma unroll
      for (int j = 0; j < 4; ++j){
        int row = bm + wr*FM*16 + m*16 + kg*4 + j;
        if (row >= M) continue;
        int col = wc*FN*16 + n*16 + lrow;
        float v = acc[m][n][j];
        if (bias) v += bias[bn0 + col];
        if (doRelu) v = fmaxf(v, 0.f);
        long idx = (long)row*ldc + bn0 + col;
        if (accum) v += ldE(C, idx);
        stE(C, idx, v);
      }
    }
  }
}

// ---------------- naive GEMM (f32 A) for the tiny encoders ----------------
template<typename TA, typename TC>
__global__ __launch_bounds__(256) void k_gemm(
    const TA* __restrict__ A, const float* __restrict__ B, TC* __restrict__ C,
    int M, int N, int K, int ldb, const float* __restrict__ bias, int doRelu)
{
  __shared__ float As[16][64];
  __shared__ float Bs[16][64];
  const int bm = blockIdx.y*64, bn = blockIdx.x*64;
  const int tid = threadIdx.x;
  const int ty = tid >> 4, tx = tid & 15;
  const int ar = tid >> 2;
  const int ac = (tid & 3) << 2;
  const int br = tid >> 4;
  const int bc = (tid & 15) << 2;
  float acc[4][4] = {};
  for (int k0 = 0; k0 < K; k0 += 16){
    int row = bm + ar;
    float4 av = make_float4(0.f,0.f,0.f,0.f);
    if (row < M) av = ld4E(A, (long)row*K + k0 + ac);
    As[ac+0][ar]=av.x; As[ac+1][ar]=av.y; As[ac+2][ar]=av.z; As[ac+3][ar]=av.w;
    float4 bv = make_float4(0.f,0.f,0.f,0.f);
    if (bn + bc + 3 < N) bv = *(const float4*)(B + (long)(k0+br)*ldb + bn + bc);
    *(float4*)&Bs[br][bc] = bv;
    __syncthreads();
    #pragma unroll
    for (int kk = 0; kk < 16; ++kk){
      float a[4], b[4];
      #pragma unroll
      for (int x = 0; x < 4; ++x){ a[x]=As[kk][ty*4+x]; b[x]=Bs[kk][tx*4+x]; }
      #pragma unroll
      for (int y = 0; y < 4; ++y)
        #pragma unroll
        for (int x = 0; x < 4; ++x) acc[y][x] += a[y]*b[x];
    }
    __syncthreads();
  }
  #pragma unroll
  for (int y = 0; y < 4; ++y){
    int row = bm + ty*4 + y;
    if (row >= M) continue;
    #pragma unroll
    for (int x = 0; x < 4; ++x){
      int col = bn + tx*4 + x;
      if (col >= N) continue;
      float v = acc[y][x];
      if (bias) v += bias[col];
      if (doRelu) v = fmaxf(v, 0.f);
      stE(C, (long)row*N + col, v);
    }
  }
}

// ---------------- merged scores: R relations, one pass over X -------------
template<int R>
__global__ __launch_bounds__(256) void k_scoreM(
    const BF16* __restrict__ X, const float* __restrict__ Ftab, long fstride,
    float* __restrict__ out, long ostride, int N, int Din)
{
  int wave = threadIdx.x >> 6, lane = threadIdx.x & 63;
  int node0 = blockIdx.x*16 + wave*4;
  if (node0 >= N) return;
  int base = lane*8;
  bool act = base < Din;
  float x[4][8];
  #pragma unroll
  for (int t = 0; t < 4; ++t){
    int node = node0 + t;
    if (act && node < N){
      short8 v = *(const short8*)(X + (long)node*Din + base);
      #pragma unroll
      for (int j = 0; j < 8; ++j) x[t][j] = bf2f(v[j]);
    } else {
      #pragma unroll
      for (int j = 0; j < 8; ++j) x[t][j] = 0.f;
    }
  }
  #pragma unroll
  for (int r = 0; r < R; ++r){
    const float* F = Ftab + (long)r*fstride;
    float p[4][4] = {};
    #pragma unroll
    for (int h = 0; h < 4; ++h){
      float f[8];
      if (act){
        float4 fa = *(const float4*)(F + h*Din + base);
        float4 fb = *(const float4*)(F + h*Din + base + 4);
        f[0]=fa.x; f[1]=fa.y; f[2]=fa.z; f[3]=fa.w;
        f[4]=fb.x; f[5]=fb.y; f[6]=fb.z; f[7]=fb.w;
      } else {
        #pragma unroll
        for (int j = 0; j < 8; ++j) f[j] = 0.f;
      }
      #pragma unroll
      for (int t = 0; t < 4; ++t)
        #pragma unroll
        for (int j = 0; j < 8; ++j) p[t][h] += x[t][j]*f[j];
    }
    #pragma unroll
    for (int t = 0; t < 4; ++t)
      #pragma unroll
      for (int h = 0; h < 4; ++h)
        #pragma unroll
        for (int off = 32; off; off >>= 1)
          p[t][h] += __shfl_down(p[t][h], off, 64);
    if (lane == 0){
      #pragma unroll
      for (int t = 0; t < 4; ++t){
        int node = node0 + t;
        if (node < N){
          #pragma unroll
          for (int h = 0; h < 4; ++h)
            out[(long)r*ostride + (long)node*4 + h] = p[t][h];
        }
      }
    }
  }
}

// ---------------- CSR build ----------------
__global__ void k_hist(const int* __restrict__ dst, int* __restrict__ counts, int E, int nd){
  int e = blockIdx.x*blockDim.x + threadIdx.x;
  if (e >= E) return;
  int d = dst[e];
  if ((unsigned)d < (unsigned)nd) atomicAdd(&counts[d], 1);
}
__global__ void k_scan1(const int* __restrict__ counts, int* __restrict__ indptr,
                        int* __restrict__ bsums, int n)
{
  __shared__ int sm[256];
  int i = blockIdx.x*256 + threadIdx.x;
  int v = (i < n) ? counts[i] : 0;
  sm[threadIdx.x] = v; __syncthreads();
  for (int off = 1; off < 256; off <<= 1){
    int t = (threadIdx.x >= off) ? sm[threadIdx.x - off] : 0;
    __syncthreads();
    sm[threadIdx.x] += t;
    __syncthreads();
  }
  if (i < n) indptr[i+1] = sm[threadIdx.x];
  if (threadIdx.x == 255) bsums[blockIdx.x] = sm[255];
  if (blockIdx.x == 0 && threadIdx.x == 0) indptr[0] = 0;
}
__global__ void k_scan2(int* __restrict__ bsums, int nb){
  __shared__ int sm[1024];
  int t = threadIdx.x;
  int v = (t < nb) ? bsums[t] : 0;
  sm[t] = v; __syncthreads();
  for (int off = 1; off < 1024; off <<= 1){
    int x = (t >= off) ? sm[t - off] : 0;
    __syncthreads();
    sm[t] += x;
    __syncthreads();
  }
  if (t < nb) bsums[t] = sm[t];
}
__global__ void k_scan3(int* __restrict__ indptr, const int* __restrict__ bsums, int n){
  if (blockIdx.x == 0) return;
  int i = blockIdx.x*256 + threadIdx.x;
  int add = bsums[blockIdx.x - 1];
  if (i < n) indptr[i+1] += add;
}
__global__ void k_scatter(const int* __restrict__ src, const int* __restrict__ dst,
                          const int* __restrict__ indptr, int* __restrict__ cursor,
                          int* __restrict__ esrc, int E, int nd, int ns)
{
  int e = blockIdx.x*blockDim.x + threadIdx.x;
  if (e >= E) return;
  int d = dst[e];
  if ((unsigned)d >= (unsigned)nd) return;
  int s = src[e];
  if ((unsigned)s >= (unsigned)ns) s = 0;
  int pos = indptr[d] + atomicAdd(&cursor[d], 1);
  if (pos >= 0 && pos < E) esrc[pos] = s;
}

// ---------------- per-edge alpha: one wave per dst node -------------------
__global__ __launch_bounds__(256) void k_alpha(
    const float* __restrict__ ss, const float* __restrict__ sd,
    const int* __restrict__ indptr, const int* __restrict__ esrc,
    float* __restrict__ alpha, int n_dst, int E, int ns)
{
  int wid = (blockIdx.x*blockDim.x + threadIdx.x) >> 6;
  int lane = threadIdx.x & 63;
  if (wid >= n_dst) return;
  int e0 = indptr[wid], e1 = indptr[wid+1];
  e0 = max(0, min(e0, E)); e1 = max(e0, min(e1, E));
  if (e0 >= e1) return;
  int h = lane >> 4, g = lane & 15;
  float sdl = sd[(long)wid*4 + h];
  float m = -INFINITY;
  for (int e = e0 + g; e < e1; e += 16){
    int s = esrc[e]; if ((unsigned)s >= (unsigned)ns) s = 0;
    m = fmaxf(m, lrelu(ss[(long)s*4 + h] + sdl));
  }
  #pragma unroll
  for (int o = 1; o < 16; o <<= 1) m = fmaxf(m, __shfl_xor(m, o, 16));
  float den = 0.f;
  for (int e = e0 + g; e < e1; e += 16){
    int s = esrc[e]; if ((unsigned)s >= (unsigned)ns) s = 0;
    den += __expf(lrelu(ss[(long)s*4 + h] + sdl) - m);
  }
  #pragma unroll
  for (int o = 1; o < 16; o <<= 1) den += __shfl_xor(den, o, 16);
  float inv = 1.f/(den + 1e-16f);
  for (int e = e0 + g; e < e1; e += 16){
    int s = esrc[e]; if ((unsigned)s >= (unsigned)ns) s = 0;
    alpha[(long)e*4 + h] = __expf(lrelu(ss[(long)s*4 + h] + sdl) - m) * inv;
  }
}

// ---------------- aggregate-FIRST gather (r=2, all 4 heads, one pass) -----
// G[(d*4+h)*Din + c] = sum_e alpha[e*4+h] * A[src_e, c]
template<int NJ>
__global__ __launch_bounds__(256) void k_gather4(
    const BF16* __restrict__ A, const float* __restrict__ alpha,
    const int* __restrict__ indptr, const int* __restrict__ esrc,
    BF16* __restrict__ G, int n_dst, int Din, int E, int ns)
{
  int wid = (blockIdx.x*blockDim.x + threadIdx.x) >> 6;
  int lane = threadIdx.x & 63;
  if (wid >= n_dst) return;
  int e0 = indptr[wid], e1 = indptr[wid+1];
  e0 = max(0, min(e0, E)); e1 = max(e0, min(e1, E));
  float acc[4][NJ];
  #pragma unroll
  for (int h = 0; h < 4; ++h)
    #pragma unroll
    for (int j = 0; j < NJ; ++j) acc[h][j] = 0.f;
  for (int e = e0; e < e1; ++e){
    int s = esrc[e]; if ((unsigned)s >= (unsigned)ns) s = 0;
    float a0 = alpha[(long)e*4 + 0], a1 = alpha[(long)e*4 + 1];
    float a2 = alpha[(long)e*4 + 2], a3 = alpha[(long)e*4 + 3];
    const BF16* ar = A + (long)s*Din;
    #pragma unroll
    for (int j = 0; j < NJ; ++j){
      float x = ldE(ar, lane + 64*j);
      acc[0][j] += a0*x; acc[1][j] += a1*x; acc[2][j] += a2*x; acc[3][j] += a3*x;
    }
  }
  #pragma unroll
  for (int h = 0; h < 4; ++h)
    #pragma unroll
    for (int j = 0; j < NJ; ++j)
      stE(G, ((long)wid*4 + h)*Din + lane + 64*j, acc[h][j]);
}

// ---------------- aggregation bodies ----------------
__device__ __forceinline__ void agg_body(
    const BF16* __restrict__ Zt, const float* __restrict__ alpha,
    const int* __restrict__ indptr, const int* __restrict__ esrc,
    float* acc, int NJ, int wid, int lane, int TW, int head0, int E, int ns)
{
  int e0 = indptr[wid], e1 = indptr[wid+1];
  e0 = max(0, min(e0, E)); e1 = max(e0, min(e1, E));
  for (int e = e0; e < e1; ++e){
    int s = esrc[e]; if ((unsigned)s >= (unsigned)ns) s = 0;
    float aA = alpha[(long)e*4 + head0];
    float aB = (NJ == 4) ? alpha[(long)e*4 + head0 + 1] : aA;
    const BF16* zr = Zt + (long)s*TW;
    #pragma unroll 4
    for (int j = 0; j < NJ; ++j){
      int col = lane + 64*j;
      if (col < TW) acc[j] += ((NJ == 4 && j >= 2) ? aB : aA) * ldE(zr, col);
    }
  }
}

// ---------------- fused 2-relation aggregation (phase 1, dst=acc) ---------
template<int NJ>
__global__ __launch_bounds__(256) void k_agg2(
    const BF16* __restrict__ Z0, const BF16* __restrict__ Z1,
    const float* __restrict__ a0, const float* __restrict__ a1,
    const int* __restrict__ ip0, const int* __restrict__ ip1,
    const int* __restrict__ es0, const int* __restrict__ es1,
    BF16* __restrict__ out, int ldc, int c0w, int TW, int head0,
    int n_dst, int E, int ns0, int ns1)
{
  int wid = (blockIdx.x*blockDim.x + threadIdx.x) >> 6;
  int lane = threadIdx.x & 63;
  if (wid >= n_dst) return;
  float acc[NJ];
  #pragma unroll
  for (int j = 0; j < NJ; ++j) acc[j] = 0.f;
  agg_body(Z0, a0, ip0, es0, acc, NJ, wid, lane, TW, head0, E, ns0);
  agg_body(Z1, a1, ip1, es1, acc, NJ, wid, lane, TW, head0, E, ns1);
  #pragma unroll
  for (int j = 0; j < NJ; ++j){
    int col = lane + 64*j;
    if (col < TW) stE(out, (long)wid*ldc + c0w + col, acc[j]);
  }
}

// ---------------- fused 3-relation aggregation (phase 2, dst=tx) ----------
template<int NJ>
__global__ __launch_bounds__(256) void k_agg3(
    const BF16* __restrict__ Z0, const BF16* __restrict__ Z1, const BF16* __restrict__ Z2,
    const float* __restrict__ a0, const float* __restrict__ a1, const float* __restrict__ a2,
    const int* __restrict__ ip0, const int* __restrict__ ip1, const int* __restrict__ ip2,
    const int* __restrict__ es0, const int* __restrict__ es1, const int* __restrict__ es2,
    BF16* __restrict__ out, int ldc, int TW, int head0,
    int n_dst, int E, int ns0, int ns1, int ns2)
{
  int wid = (blockIdx.x*blockDim.x + threadIdx.x) >> 6;
  int lane = threadIdx.x & 63;
  if (wid >= n_dst) return;
  float acc[NJ];
  #pragma unroll
  for (int j = 0; j < NJ; ++j) acc[j] = 0.f;
  agg_body(Z0, a0, ip0, es0, acc, NJ, wid, lane, TW, head0, E, ns0);
  agg_body(Z1, a1, ip1, es1, acc, NJ, wid, lane, TW, head0, E, ns1);
  agg_body(Z2, a2, ip2, es2, acc, NJ, wid, lane, TW, head0, E, ns2);
  #pragma unroll
  for (int j = 0; j < NJ; ++j){
    int col = lane + 64*j;
    if (col < TW) stE(out, (long)wid*ldc + col, acc[j]);
  }
}

// ---------------- BN stats over nw_tile [N, TW] bf16 ----------------------
__global__ void k_bnp(const BF16* __restrict__ nw, float* __restrict__ bnp,
                      int N, int TW, int P)
{
  int col  = threadIdx.x & (TW - 1);
  int slot = threadIdx.x / TW;
  int rpb  = 256 / TW;
  int p    = blockIdx.x*rpb + slot;
  float s = 0.f, s2 = 0.f;
  for (long r = p; r < N; r += P){
    float v = ldE(nw, r*TW + col);
    s += v; s2 += v*v;
  }
  bnp[(long)p*2*TW + col]      = s;
  bnp[(long)p*2*TW + TW + col] = s2;
}
__global__ void k_bnf(const float* __restrict__ bnp, float* __restrict__ bns,
                      int P, int TW)
{
  int c = blockIdx.x*256 + threadIdx.x;
  if (c >= 2*TW) return;
  float s = 0.f;
  for (int p = 0; p < P; ++p) s += bnp[(long)p*2*TW + c];
  bns[c] = s;
}
__global__ void k_bn_apply(const BF16* __restrict__ nw, const float* __restrict__ bns,
                           const float* __restrict__ g, const float* __restrict__ b,
                           BF16* __restrict__ A, int N, int TW, int c0, int res)
{
  long total = (long)N*TW;
  for (long i = (long)blockIdx.x*blockDim.x + threadIdx.x; i < total;
       i += (long)gridDim.x*blockDim.x){
    int col = (int)(i % TW);
    long r  = i / TW;
    float mu  = bns[col] / (float)N;
    float var = bns[TW + col] / (float)N - mu*mu;
    int gc = c0 + col;
    float sc = g[gc] * rsqrtf(var + 1e-5f);
    float sh = b[gc] - mu*sc;
    float v = fmaxf(ldE(nw, i)*sc + sh, 0.f);
    long ai = r*512 + gc;
    if (res) v += ldE(A, ai);
    stE(A, ai, v);
  }
}

// ---------------- acc/mer update ----------------
__global__ void k_update(const BF16* __restrict__ B, const float* __restrict__ ab1,
                         const float* __restrict__ ab2, BF16* __restrict__ A,
                         long n512, int res)
{
  for (long i = (long)blockIdx.x*blockDim.x + threadIdx.x; i < n512;
       i += (long)gridDim.x*blockDim.x){
    int c = (int)(i & 511);
    float v = ldE(B, i) + ab1[c] + (ab2 ? ab2[c] : 0.f);
    v = fmaxf(v, 0.f);
    if (res) v += ldE(A, i);
    stE(A, i, v);
  }
}

// ---------------- head logits ----------------
__global__ void k_logits(const BF16* __restrict__ Hid, const float* __restrict__ Wh2,
                         const float* __restrict__ bh2, float* __restrict__ out, int N)
{
  int node = (blockIdx.x*blockDim.x + threadIdx.x) >> 6;
  int lane = threadIdx.x & 63;
  if (node >= N) return;
  float v = ldE(Hid, (long)node*64 + lane) * Wh2[lane];
  #pragma unroll
  for (int off = 32; off; off >>= 1) v += __shfl_down(v, off, 64);
  if (lane == 0) out[node] = v + bh2[0];
}

// ---------------------------------------------------------------------------
struct Arena {
  BF16 *A[3];
  BF16 *Bst[3];
  BF16 *Zt;        // blockA: phase1 Z_r0 / phase2 Z3/Z4/Z5
  BF16 *blkB;      // blockB: phase1 Z_r1 & G_mer / phase2 nw (lifetimes disjoint)
  BF16 *hidden;
  float *scoreS, *scoreD;  // overlay on blockA (valid until first Z write)
  float *alpha;    // 3 x [E,4]
  float *Fbuf;
  float *bnp, *bns;
  int *counts, *bsums;
  int *indptr[6], *esrc[6];
  BF16 *Wt0[6], *WtL[2][6], *Wh1t;
  size_t total;
};

extern "C" void kernel_launch(void* const* d_in, const int* in_sizes, int n_in,
                              void* d_out, int out_size, void* d_ws, size_t ws_size,
                              hipStream_t stream)
{
  const float* x_tx  = (const float*)d_in[0];
  const float* x_acc = (const float*)d_in[1];
  const float* x_mer = (const float*)d_in[2];
  const float* Wtx = (const float*)d_in[3];  const float* btx  = (const float*)d_in[4];
  const float* Wacc= (const float*)d_in[5];  const float* bacc = (const float*)d_in[6];
  const float* Wmer= (const float*)d_in[7];  const float* bmer = (const float*)d_in[8];
  const float* W0   = (const float*)d_in[9];
  const float* Wrest= (const float*)d_in[10];
  const float* att_s= (const float*)d_in[11];
  const float* att_d= (const float*)d_in[12];
  const float* att_b= (const float*)d_in[13];
  const float* bn_g = (const float*)d_in[14];
  const float* bn_b = (const float*)d_in[15];
  const float* Wh1  = (const float*)d_in[16]; const float* bh1 = (const float*)d_in[17];
  const float* Wh2  = (const float*)d_in[18]; const float* bh2 = (const float*)d_in[19];
  const int*   edges= (const int*)d_in[20];

  const int E    = in_sizes[20] / 12;
  const int nTx  = in_sizes[0] / 64;
  const int nAcc = in_sizes[1] / 32;
  const int nMer = in_sizes[2] / 32;
  const int nOf[3]   = {nTx, nAcc, nMer};
  const int SRC_T[6] = {0,0,0,1,1,2};
  const int DST_T[6] = {1,1,2,0,0,0};
  const int maxN = max(nTx, max(nAcc, nMer));
  (void)n_in;

  auto layout = [&](int TW)->Arena{
    Arena P{};
    size_t off = 0;
    auto a = [&](size_t bytes)->char*{
      char* p = (char*)d_ws + off;
      off += (bytes + 255) & ~(size_t)255;
      return p;
    };
    auto al = [](size_t b){ return (b + 255) & ~(size_t)255; };
    P.A[0]   = (BF16*)a((size_t)nTx *512*2);
    P.A[1]   = (BF16*)a((size_t)nAcc*512*2);
    P.A[2]   = (BF16*)a((size_t)nMer*512*2);
    P.Bst[1] = (BF16*)a((size_t)nAcc*512*2);
    P.Bst[2] = (BF16*)a((size_t)nMer*512*2);
    // blockA: max(phase2 Z3/4/5 rows, phase1 Z_r0 rows=nTx) x TW
    size_t zrowsA = (size_t)maxN > (size_t)2*nAcc + nMer ? (size_t)maxN : (size_t)2*nAcc + nMer;
    size_t blkA = al(zrowsA*TW*2);
    // blockB: max(nw [nTx,TW], Z_r1 [nTx,TW], G_mer [nMer*4,512])
    size_t blkBsz = al((size_t)nTx*TW*2);
    size_t gB = al((size_t)nMer*4*512*2);
    if (gB > blkBsz) blkBsz = gB;
    size_t scoreB = al((size_t)3*maxN*4*4)*2;
    size_t hidB = al((size_t)nTx*64*2);
    size_t scr = blkA + blkBsz;
    if (scr < scoreB) scr = scoreB;
    if (scr < hidB)   scr = hidB;
    char* scrBase = a(scr);
    P.Zt     = (BF16*)scrBase;
    P.blkB   = (BF16*)(scrBase + blkA);
    P.scoreS = (float*)scrBase;
    P.scoreD = (float*)(scrBase + al((size_t)3*maxN*4*4));
    P.hidden = (BF16*)scrBase;
    P.alpha  = (float*)a((size_t)3*E*4*4);
    P.Fbuf   = (float*)a((size_t)6*8*512*4);
    P.bnp    = (float*)a(262144);
    P.bns    = (float*)a(4096);
    P.counts = (int*)a((size_t)maxN*4);
    P.bsums  = (int*)a(4096);
    for (int r = 0; r < 6; ++r){
      P.indptr[r] = (int*)a((size_t)(nOf[DST_T[r]]+1)*4);
      P.esrc[r]   = (int*)a((size_t)E*4);
    }
    for (int r = 0; r < 6; ++r) P.Wt0[r] = (BF16*)a((size_t)512*128*2);
    for (int l = 0; l < 2; ++l)
      for (int r = 0; r < 6; ++r) P.WtL[l][r] = (BF16*)a((size_t)512*512*2);
    P.Wh1t = (BF16*)a((size_t)64*512*2);
    P.total = off;
    return P;
  };

  int TW = 0;
  Arena P{};
  for (int cand : {128, 64}){
    P = layout(cand);
    if (P.total <= ws_size){ TW = cand; break; }
  }
  if (TW == 0){
    float sentinel = 10000.0f + (float)(ws_size >> 20);
    k_fill_f32<<<dim3((out_size+255)/256), dim3(256), 0, stream>>>((float*)d_out, (long)out_size, sentinel);
    return;
  }
  const int nTiles = 512 / TW;
  const int NJv = TW/64;
  const int rpb = 256 / TW, PBX = 128, Pp = PBX * rpb;
  dim3 b256(256);

  // ---- 0. weight prep ----
  for (int r = 0; r < 6; ++r)
    k_wt<<<dim3(16,4), b256, 0, stream>>>(W0 + (size_t)r*128*512, P.Wt0[r], 128, 512);
  for (int l = 0; l < 2; ++l)
    for (int r = 0; r < 6; ++r)
      k_wt<<<dim3(16,16), b256, 0, stream>>>(Wrest + ((size_t)l*6 + r)*512*512, P.WtL[l][r], 512, 512);
  k_wt<<<dim3(2,16), b256, 0, stream>>>(Wh1, P.Wh1t, 512, 64);

  auto mfma_gemm = [&](const BF16* A, const BF16* Bt, BF16* Cp, int M, int K, int c0, int ldc){
    if (TW >= 128)
      k_mfma<128,2,2,4,4,BF16><<<dim3(TW/128,(M+127)/128),b256,0,stream>>>(A, Bt, Cp, M, K, c0, ldc, K, (const float*)nullptr, 0, 0);
    else
      k_mfma<64,4,1,2,4,BF16><<<dim3(1,(M+127)/128),b256,0,stream>>>(A, Bt, Cp, M, K, c0, ldc, K, (const float*)nullptr, 0, 0);
  };

  // ---- 1. CSR build ----
  for (int r = 0; r < 6; ++r){
    int nd = nOf[DST_T[r]], ns = nOf[SRC_T[r]];
    const int* srcP = edges + (size_t)r*2*E;
    const int* dstP = srcP + E;
    int nb = (nd + 255)/256;
    k_zero   <<<dim3(nb),          b256, 0, stream>>>(P.counts, (long)nd);
    k_hist   <<<dim3((E+255)/256), b256, 0, stream>>>(dstP, P.counts, E, nd);
    k_scan1  <<<dim3(nb),          b256, 0, stream>>>(P.counts, P.indptr[r], P.bsums, nd);
    k_scan2  <<<dim3(1),           dim3(1024),0, stream>>>(P.bsums, nb);
    k_scan3  <<<dim3(nb),          b256, 0, stream>>>(P.indptr[r], P.bsums, nd);
    k_zero   <<<dim3(nb),          b256, 0, stream>>>(P.counts, (long)nd);
    k_scatter<<<dim3((E+255)/256), b256, 0, stream>>>(srcP, dstP, P.indptr[r], P.counts, P.esrc[r], E, nd, ns);
  }

  // ---- 2. encoders ----
  k_gemm<float,BF16><<<dim3(2,(nTx +63)/64), b256, 0, stream>>>(x_tx,  Wtx,  P.A[0], nTx,  128, 64, 128, btx,  1);
  k_gemm<float,BF16><<<dim3(2,(nAcc+63)/64), b256, 0, stream>>>(x_acc, Wacc, P.A[1], nAcc, 128, 32, 128, bacc, 1);
  k_gemm<float,BF16><<<dim3(2,(nMer+63)/64), b256, 0, stream>>>(x_mer, Wmer, P.A[2], nMer, 128, 32, 128, bmer, 1);

  const long mS = (long)maxN*4;
  // ---- 3. layers ----
  for (int i = 0; i < 3; ++i){
    const int Din = (i == 0) ? 128 : 512;
    const int res = (i > 0) ? 1 : 0;
    const long fstr = 8L*Din;
    const float* WbaseL = (i == 0) ? W0 : (Wrest + (size_t)(i-1)*6*512*512);
    const long wstride = (i == 0) ? 128L*512 : 512L*512;
    auto Wtof = [&](int r)->const BF16*{ return (i == 0) ? P.Wt0[r] : P.WtL[i-1][r]; };

    k_foldAll<<<dim3(48*Din/4), b256, 0, stream>>>(WbaseL, wstride,
        att_s + (size_t)i*6*512, att_d + (size_t)i*6*512, P.Fbuf, Din);

    // ---- Phase 1: scores then ALL alphas (scores live in blockA overlay) ----
    k_scoreM<3><<<dim3((nTx+15)/16), b256, 0, stream>>>(P.A[0], P.Fbuf,           fstr, P.scoreS, mS, nTx, Din);
    k_scoreM<2><<<dim3((nAcc+15)/16), b256, 0, stream>>>(P.A[1], P.Fbuf + 4*Din,  fstr, P.scoreD, mS, nAcc, Din);
    k_scoreM<1><<<dim3((nMer+15)/16), b256, 0, stream>>>(P.A[2], P.Fbuf + 20*Din, fstr, P.scoreD + 2*mS, 0, nMer, Din);
    for (int r = 0; r < 3; ++r){
      int nd = nOf[DST_T[r]];
      k_alpha<<<dim3((nd+3)/4), b256, 0, stream>>>(P.scoreS + r*mS, P.scoreD + r*mS,
          P.indptr[r], P.esrc[r], P.alpha + (size_t)r*E*4, nd, E, nTx);
    }
    // r=2 (tx->mer): aggregate-FIRST. G in blockB; 4 head-GEMMs M=nMer.
    {
      BF16* Gm = P.blkB;
      if (Din == 512)
        k_gather4<8><<<dim3((nMer+3)/4), b256, 0, stream>>>(P.A[0], P.alpha + (size_t)2*E*4,
            P.indptr[2], P.esrc[2], Gm, nMer, Din, E, nTx);
      else
        k_gather4<2><<<dim3((nMer+3)/4), b256, 0, stream>>>(P.A[0], P.alpha + (size_t)2*E*4,
            P.indptr[2], P.esrc[2], Gm, nMer, Din, E, nTx);
      for (int h = 0; h < 4; ++h)
        k_mfma<128,2,2,4,4,BF16><<<dim3(1,(nMer+127)/128), b256, 0, stream>>>(
            Gm + (size_t)h*Din, Wtof(2), P.Bst[2] + (size_t)h*128,
            nMer, Din, h*128, 512, 4*Din, (const float*)nullptr, 0, 0);
    }
    // r=0,1 (tx->acc): aggregate-last, fused agg2 per tile.
    {
      BF16* Zr0 = P.Zt;
      BF16* Zr1 = P.blkB;   // G_mer dead by now
      for (int t = 0; t < nTiles; ++t){
        int c0 = t*TW;
        mfma_gemm(P.A[0], Wtof(0), Zr0, nTx, Din, c0, TW);
        mfma_gemm(P.A[0], Wtof(1), Zr1, nTx, Din, c0, TW);
        dim3 ga((nAcc+3)/4);
        if (NJv == 2)
          k_agg2<2><<<ga,b256,0,stream>>>(Zr0, Zr1, P.alpha, P.alpha + (size_t)E*4,
              P.indptr[0], P.indptr[1], P.esrc[0], P.esrc[1],
              P.Bst[1], 512, c0, TW, c0>>7, nAcc, E, nTx, nTx);
        else
          k_agg2<1><<<ga,b256,0,stream>>>(Zr0, Zr1, P.alpha, P.alpha + (size_t)E*4,
              P.indptr[0], P.indptr[1], P.esrc[0], P.esrc[1],
              P.Bst[1], 512, c0, TW, c0>>7, nAcc, E, nTx, nTx);
      }
    }

    // ---- Phase 2 (dst=tx; src=acc r=3,4; mer r=5) ----
    k_scoreM<2><<<dim3((nAcc+15)/16), b256, 0, stream>>>(P.A[1], P.Fbuf + 24*Din, fstr, P.scoreS, mS, nAcc, Din);
    k_scoreM<1><<<dim3((nMer+15)/16), b256, 0, stream>>>(P.A[2], P.Fbuf + 40*Din, fstr, P.scoreS + 2*mS, 0, nMer, Din);
    k_scoreM<3><<<dim3((nTx+15)/16), b256, 0, stream>>>(P.A[0], P.Fbuf + 28*Din, fstr, P.scoreD, mS, nTx, Din);
    for (int q = 0; q < 3; ++q){
      int r = 3 + q;
      k_alpha<<<dim3((nTx+3)/4), b256, 0, stream>>>(P.scoreS + q*mS, P.scoreD + q*mS,
          P.indptr[r], P.esrc[r], P.alpha + (size_t)q*E*4, nTx, E, nOf[SRC_T[r]]);
    }
    BF16* Z3 = P.Zt;
    BF16* Z4 = P.Zt + (size_t)nAcc*TW;
    BF16* Z5 = P.Zt + (size_t)2*nAcc*TW;
    BF16* nw = P.blkB;
    for (int t = 0; t < nTiles; ++t){
      int c0 = t*TW;
      mfma_gemm(P.A[1], Wtof(3), Z3, nAcc, Din, c0, TW);
      mfma_gemm(P.A[1], Wtof(4), Z4, nAcc, Din, c0, TW);
      mfma_gemm(P.A[2], Wtof(5), Z5, nMer, Din, c0, TW);
      dim3 ga((nTx+3)/4);
      if (NJv == 2)
        k_agg3<2><<<ga,b256,0,stream>>>(Z3,Z4,Z5, P.alpha, P.alpha+(size_t)E*4, P.alpha+(size_t)2*E*4,
            P.indptr[3],P.indptr[4],P.indptr[5], P.esrc[3],P.esrc[4],P.esrc[5],
            nw, TW, TW, c0>>7, nTx, E, nAcc, nAcc, nMer);
      else
        k_agg3<1><<<ga,b256,0,stream>>>(Z3,Z4,Z5, P.alpha, P.alpha+(size_t)E*4, P.alpha+(size_t)2*E*4,
            P.indptr[3],P.indptr[4],P.indptr[5], P.esrc[3],P.esrc[4],P.esrc[5],
            nw, TW, TW, c0>>7, nTx, E, nAcc, nAcc, nMer);
      k_bnp<<<dim3(PBX), b256, 0, stream>>>(nw, P.bnp, nTx, TW, Pp);
      k_bnf<<<dim3((2*TW+255)/256), b256, 0, stream>>>(P.bnp, P.bns, Pp, TW);
      k_bn_apply<<<dim3(2048), b256, 0, stream>>>(nw, P.bns,
          bn_g + (size_t)i*512, bn_b + (size_t)i*512, P.A[0], nTx, TW, c0, res);
    }
    // ---- Phase 3 ----
    const float* ab0 = att_b + ((size_t)(i*6 + 0))*512;
    const float* ab1 = att_b + ((size_t)(i*6 + 1))*512;
    const float* ab2 = att_b + ((size_t)(i*6 + 2))*512;
    k_update<<<dim3(2048), b256, 0, stream>>>(P.Bst[1], ab0, ab1, P.A[1], (long)nAcc*512, res);
    k_update<<<dim3(256),  b256, 0, stream>>>(P.Bst[2], ab2, (const float*)nullptr, P.A[2], (long)nMer*512, res);
  }

  // ---- 4. head ----
  k_mfma<64,4,1,2,4,BF16><<<dim3(1,(nTx+127)/128), b256, 0, stream>>>(
      P.A[0], P.Wh1t, P.hidden, nTx, 512, 0, 64, 512, bh1, 1, 0);
  k_logits<<<dim3((nTx+3)/4), b256, 0, stream>>>(P.hidden, Wh2, bh2, (float*)d_out, nTx);
}

// Round 15
// 10486.845 us; speedup vs baseline: 2.4758x; 1.0230x over previous
//
#include <hip/hip_runtime.h>
#include <math.h>

// ---------------------------------------------------------------------------
// FraudGAT: bf16 storage, MFMA projections, pre-transposed bf16 weights.
// R15 = R13 base (known good) + ONLY the verified batchings from R14:
//   - z-batched weight transpose (19 -> 3 launches)
//   - z-batched GEMM pair/quad launches (memory layout identical to R13)
//   - batched alpha (grid.y=3; 18 -> 6 launches)
// CSR build reverted to R13's per-relation version (R14's fused CSR is the
// prime suspect for the absmax-1.89 corruption and is excluded).
// ---------------------------------------------------------------------------

typedef unsigned short BF16;
typedef short short8 __attribute__((ext_vector_type(8)));
typedef float f32x4 __attribute__((ext_vector_type(4)));
typedef __bf16 bf16x8 __attribute__((ext_vector_type(8)));

static __device__ __forceinline__ float lrelu(float x){ return x > 0.f ? x : 0.2f*x; }

__device__ __forceinline__ float ldE(const float* p, long i){ return p[i]; }
__device__ __forceinline__ float ldE(const BF16* p, long i){
  return __uint_as_float((unsigned)p[i] << 16);
}
__device__ __forceinline__ void stE(float* p, long i, float v){ p[i] = v; }
__device__ __forceinline__ void stE(BF16* p, long i, float v){
  unsigned u = __float_as_uint(v);
  p[i] = (BF16)((u + 0x7FFFu + ((u >> 16) & 1u)) >> 16);
}
__device__ __forceinline__ BF16 f2bf(float v){
  unsigned u = __float_as_uint(v);
  return (BF16)((u + 0x7FFFu + ((u >> 16) & 1u)) >> 16);
}
__device__ __forceinline__ float bf2f(short s){
  return __uint_as_float((unsigned)(unsigned short)s << 16);
}
__device__ __forceinline__ float4 ld4E(const float* p, long i){ return *(const float4*)(p + i); }
__device__ __forceinline__ float4 ld4E(const BF16* p, long i){
  ushort4 s = *(const ushort4*)(p + i);
  return make_float4(__uint_as_float((unsigned)s.x<<16), __uint_as_float((unsigned)s.y<<16),
                     __uint_as_float((unsigned)s.z<<16), __uint_as_float((unsigned)s.w<<16));
}

// ---------------- utility ----------------
__global__ void k_zero(int* __restrict__ p, long n){
  long i = (long)blockIdx.x*blockDim.x + threadIdx.x;
  if (i < n) p[i] = 0;
}
__global__ void k_fill_f32(float* __restrict__ p, long n, float v){
  long i = (long)blockIdx.x*blockDim.x + threadIdx.x;
  if (i < n) p[i] = v;
}

// ---------------- weight transpose+convert (z-batched) --------------------
__global__ __launch_bounds__(256) void k_wt(const float* __restrict__ in, BF16* __restrict__ out,
                                            int K, int N)
{
  in  += (long)blockIdx.z*K*N;
  out += (long)blockIdx.z*N*K;
  __shared__ float t[32][33];
  int kb = blockIdx.y*32, nb = blockIdx.x*32;
  int tx = threadIdx.x & 31, ty8 = threadIdx.x >> 5;
  for (int j = ty8; j < 32; j += 8){
    int k = kb + j, n = nb + tx;
    t[j][tx] = (k < K && n < N) ? in[(long)k*N + n] : 0.f;
  }
  __syncthreads();
  for (int j = ty8; j < 32; j += 8){
    int n = nb + j, k = kb + tx;
    if (n < N && k < K) out[(long)n*K + k] = f2bf(t[tx][j]);
  }
}

// ---------------- fold ALL 12 tables in one launch ------------------------
__global__ __launch_bounds__(256) void k_foldAll(
    const float* __restrict__ Wbase, long wstride,
    const float* __restrict__ atts, const float* __restrict__ attd,
    float* __restrict__ F, int Din)
{
  int w = (blockIdx.x*256 + threadIdx.x) >> 6;
  int lane = threadIdx.x & 63;
  int total = 48*Din;
  if (w >= total) return;
  int k = w % Din;
  int rem = w / Din;
  int h = rem & 3, sd = (rem >> 2) & 1, r = rem >> 3;
  const float* wr = Wbase + (long)r*wstride + (long)k*512 + h*128;
  const float* ar = (sd ? attd : atts) + r*512 + h*128;
  float p = wr[lane]*ar[lane] + wr[lane+64]*ar[lane+64];
  #pragma unroll
  for (int off = 32; off; off >>= 1) p += __shfl_down(p, off, 64);
  if (lane == 0) F[(long)((r*2+sd)*4 + h)*Din + k] = p;
}

// ---------------- MFMA GEMM (optionally z-batched) ------------------------
// C[:, chunk] = A[M,K](bf16) @ Bt[cols,K]^T.  Per z: A += z*aZst (elems),
// C += z*cZst (elems), c0 += z*c0Zst, Bt = (z>=1 && Bt1) ? Bt1 : Bt.
template<int BN, int WM, int WN, int FM, int FN, typename TC>
__global__ __launch_bounds__(256) void k_mfma(
    const BF16* __restrict__ A, const BF16* __restrict__ Bt, TC* __restrict__ C,
    int M, int K, int c0, int ldc, int lda, const float* __restrict__ bias,
    int doRelu, int accum, long aZst, long cZst, int c0Zst, const BF16* __restrict__ Bt1)
{
  constexpr int BM = 128;
  constexpr int LSTR = 72;
  __shared__ __attribute__((aligned(16))) short Als[BM][LSTR];
  __shared__ __attribute__((aligned(16))) short Bls[BN][LSTR];
  const int z = blockIdx.z;
  A += (long)z*aZst;
  C += (long)z*cZst;
  c0 += z*c0Zst;
  if (z >= 1 && Bt1) Bt = Bt1;
  const int bn0 = blockIdx.x * BN;
  const int bm = blockIdx.y*BM;
  const int tid = threadIdx.x;
  const int wave = tid >> 6, lane = tid & 63;
  const int wr = wave / WN, wc = wave % WN;
  const int lrow = lane & 15, kg = lane >> 4;
  f32x4 acc[FM][FN] = {};
  for (int k0 = 0; k0 < K; k0 += 64){
    #pragma unroll
    for (int t = 0; t < 4; ++t){
      int idx = tid + t*256;
      int row = idx >> 3, kc = (idx & 7) << 3;
      int gr = bm + row;
      short8 v = {};
      if (gr < M) v = *(const short8*)(A + (long)gr*lda + k0 + kc);
      *(short8*)&Als[row][kc] = v;
    }
    #pragma unroll
    for (int t = 0; t < BN/32; ++t){
      int idx = tid + t*256;
      int row = idx >> 3, kc = (idx & 7) << 3;
      *(short8*)&Bls[row][kc] = *(const short8*)(Bt + (long)(c0+bn0+row)*K + k0 + kc);
    }
    __syncthreads();
    #pragma unroll
    for (int kk = 0; kk < 2; ++kk){
      short8 af[FM], bq[FN];
      #pragma unroll
      for (int m = 0; m < FM; ++m)
        af[m] = *(const short8*)&Als[wr*FM*16 + m*16 + lrow][kk*32 + kg*8];
      #pragma unroll
      for (int n = 0; n < FN; ++n)
        bq[n] = *(const short8*)&Bls[wc*FN*16 + n*16 + lrow][kk*32 + kg*8];
      #pragma unroll
      for (int m = 0; m < FM; ++m)
        #pragma unroll
        for (int n = 0; n < FN; ++n)
          acc[m][n] = __builtin_amdgcn_mfma_f32_16x16x32_bf16(
              __builtin_bit_cast(bf16x8, af[m]), __builtin_bit_cast(bf16x8, bq[n]),
              acc[m][n], 0, 0, 0);
    }
    __syncthreads();
  }
  // epilogue: C/D layout col=lane&15, row=(lane>>4)*4+reg  [m89]
  #pragma unroll
  for (int m = 0; m < FM; ++m){
    #pragma unroll
    for (int n = 0; n < FN; ++n){
      #pragma unroll
      for (int j = 0; j < 4; ++j){
        int row = bm + wr*FM*16 + m*16 + kg*4 + j;
        if (row >= M) continue;
        int col = wc*FN*16 + n*16 + lrow;
        float v = acc[m][n][j];
        if (bias) v += bias[bn0 + col];
        if (doRelu) v = fmaxf(v, 0.f);
        long idx = (long)row*ldc + bn0 + col;
        if (accum) v += ldE(C, idx);
        stE(C, idx, v);
      }
    }
  }
}

// ---------------- naive GEMM (f32 A) for the tiny encoders ----------------
template<typename TA, typename TC>
__global__ __launch_bounds__(256) void k_gemm(
    const TA* __restrict__ A, const float* __restrict__ B, TC* __restrict__ C,
    int M, int N, int K, int ldb, const float* __restrict__ bias, int doRelu)
{
  __shared__ float As[16][64];
  __shared__ float Bs[16][64];
  const int bm = blockIdx.y*64, bn = blockIdx.x*64;
  const int tid = threadIdx.x;
  const int ty = tid >> 4, tx = tid & 15;
  const int ar = tid >> 2;
  const int ac = (tid & 3) << 2;
  const int br = tid >> 4;
  const int bc = (tid & 15) << 2;
  float acc[4][4] = {};
  for (int k0 = 0; k0 < K; k0 += 16){
    int row = bm + ar;
    float4 av = make_float4(0.f,0.f,0.f,0.f);
    if (row < M) av = ld4E(A, (long)row*K + k0 + ac);
    As[ac+0][ar]=av.x; As[ac+1][ar]=av.y; As[ac+2][ar]=av.z; As[ac+3][ar]=av.w;
    float4 bv = make_float4(0.f,0.f,0.f,0.f);
    if (bn + bc + 3 < N) bv = *(const float4*)(B + (long)(k0+br)*ldb + bn + bc);
    *(float4*)&Bs[br][bc] = bv;
    __syncthreads();
    #pragma unroll
    for (int kk = 0; kk < 16; ++kk){
      float a[4], b[4];
      #pragma unroll
      for (int x = 0; x < 4; ++x){ a[x]=As[kk][ty*4+x]; b[x]=Bs[kk][tx*4+x]; }
      #pragma unroll
      for (int y = 0; y < 4; ++y)
        #pragma unroll
        for (int x = 0; x < 4; ++x) acc[y][x] += a[y]*b[x];
    }
    __syncthreads();
  }
  #pragma unroll
  for (int y = 0; y < 4; ++y){
    int row = bm + ty*4 + y;
    if (row >= M) continue;
    #pragma unroll
    for (int x = 0; x < 4; ++x){
      int col = bn + tx*4 + x;
      if (col >= N) continue;
      float v = acc[y][x];
      if (bias) v += bias[col];
      if (doRelu) v = fmaxf(v, 0.f);
      stE(C, (long)row*N + col, v);
    }
  }
}

// ---------------- merged scores: R relations, one pass over X -------------
template<int R>
__global__ __launch_bounds__(256) void k_scoreM(
    const BF16* __restrict__ X, const float* __restrict__ Ftab, long fstride,
    float* __restrict__ out, long ostride, int N, int Din)
{
  int wave = threadIdx.x >> 6, lane = threadIdx.x & 63;
  int node0 = blockIdx.x*16 + wave*4;
  if (node0 >= N) return;
  int base = lane*8;
  bool act = base < Din;
  float x[4][8];
  #pragma unroll
  for (int t = 0; t < 4; ++t){
    int node = node0 + t;
    if (act && node < N){
      short8 v = *(const short8*)(X + (long)node*Din + base);
      #pragma unroll
      for (int j = 0; j < 8; ++j) x[t][j] = bf2f(v[j]);
    } else {
      #pragma unroll
      for (int j = 0; j < 8; ++j) x[t][j] = 0.f;
    }
  }
  #pragma unroll
  for (int r = 0; r < R; ++r){
    const float* F = Ftab + (long)r*fstride;
    float p[4][4] = {};
    #pragma unroll
    for (int h = 0; h < 4; ++h){
      float f[8];
      if (act){
        float4 fa = *(const float4*)(F + h*Din + base);
        float4 fb = *(const float4*)(F + h*Din + base + 4);
        f[0]=fa.x; f[1]=fa.y; f[2]=fa.z; f[3]=fa.w;
        f[4]=fb.x; f[5]=fb.y; f[6]=fb.z; f[7]=fb.w;
      } else {
        #pragma unroll
        for (int j = 0; j < 8; ++j) f[j] = 0.f;
      }
      #pragma unroll
      for (int t = 0; t < 4; ++t)
        #pragma unroll
        for (int j = 0; j < 8; ++j) p[t][h] += x[t][j]*f[j];
    }
    #pragma unroll
    for (int t = 0; t < 4; ++t)
      #pragma unroll
      for (int h = 0; h < 4; ++h)
        #pragma unroll
        for (int off = 32; off; off >>= 1)
          p[t][h] += __shfl_down(p[t][h], off, 64);
    if (lane == 0){
      #pragma unroll
      for (int t = 0; t < 4; ++t){
        int node = node0 + t;
        if (node < N){
          #pragma unroll
          for (int h = 0; h < 4; ++h)
            out[(long)r*ostride + (long)node*4 + h] = p[t][h];
        }
      }
    }
  }
}

// ---------------- CSR build (per-relation, as R13) ------------------------
__global__ void k_hist(const int* __restrict__ dst, int* __restrict__ counts, int E, int nd){
  int e = blockIdx.x*blockDim.x + threadIdx.x;
  if (e >= E) return;
  int d = dst[e];
  if ((unsigned)d < (unsigned)nd) atomicAdd(&counts[d], 1);
}
__global__ void k_scan1(const int* __restrict__ counts, int* __restrict__ indptr,
                        int* __restrict__ bsums, int n)
{
  __shared__ int sm[256];
  int i = blockIdx.x*256 + threadIdx.x;
  int v = (i < n) ? counts[i] : 0;
  sm[threadIdx.x] = v; __syncthreads();
  for (int off = 1; off < 256; off <<= 1){
    int t = (threadIdx.x >= off) ? sm[threadIdx.x - off] : 0;
    __syncthreads();
    sm[threadIdx.x] += t;
    __syncthreads();
  }
  if (i < n) indptr[i+1] = sm[threadIdx.x];
  if (threadIdx.x == 255) bsums[blockIdx.x] = sm[255];
  if (blockIdx.x == 0 && threadIdx.x == 0) indptr[0] = 0;
}
__global__ void k_scan2(int* __restrict__ bsums, int nb){
  __shared__ int sm[1024];
  int t = threadIdx.x;
  int v = (t < nb) ? bsums[t] : 0;
  sm[t] = v; __syncthreads();
  for (int off = 1; off < 1024; off <<= 1){
    int x = (t >= off) ? sm[t - off] : 0;
    __syncthreads();
    sm[t] += x;
    __syncthreads();
  }
  if (t < nb) bsums[t] = sm[t];
}
__global__ void k_scan3(int* __restrict__ indptr, const int* __restrict__ bsums, int n){
  if (blockIdx.x == 0) return;
  int i = blockIdx.x*256 + threadIdx.x;
  int add = bsums[blockIdx.x - 1];
  if (i < n) indptr[i+1] += add;
}
__global__ void k_scatter(const int* __restrict__ src, const int* __restrict__ dst,
                          const int* __restrict__ indptr, int* __restrict__ cursor,
                          int* __restrict__ esrc, int E, int nd, int ns)
{
  int e = blockIdx.x*blockDim.x + threadIdx.x;
  if (e >= E) return;
  int d = dst[e];
  if ((unsigned)d >= (unsigned)nd) return;
  int s = src[e];
  if ((unsigned)s >= (unsigned)ns) s = 0;
  int pos = indptr[d] + atomicAdd(&cursor[d], 1);
  if (pos >= 0 && pos < E) esrc[pos] = s;
}

// ---------------- batched per-edge alpha (3 relations, grid.y) ------------
struct AlphaArgs {
  const float* ss[3]; const float* sd[3];
  const int* ip[3]; const int* es[3];
  float* al[3]; int nd[3]; int ns[3];
};
__global__ __launch_bounds__(256) void k_alpha3b(AlphaArgs a, int E){
  int r = blockIdx.y;
  int wid = (blockIdx.x*blockDim.x + threadIdx.x) >> 6;
  int lane = threadIdx.x & 63;
  if (wid >= a.nd[r]) return;
  const int* indptr = a.ip[r];
  const int* esrc = a.es[r];
  const float* ss = a.ss[r];
  int ns = a.ns[r];
  int e0 = indptr[wid], e1 = indptr[wid+1];
  e0 = max(0, min(e0, E)); e1 = max(e0, min(e1, E));
  if (e0 >= e1) return;
  int h = lane >> 4, g = lane & 15;
  float sdl = a.sd[r][(long)wid*4 + h];
  float* alpha = a.al[r];
  float m = -INFINITY;
  for (int e = e0 + g; e < e1; e += 16){
    int s = esrc[e]; if ((unsigned)s >= (unsigned)ns) s = 0;
    m = fmaxf(m, lrelu(ss[(long)s*4 + h] + sdl));
  }
  #pragma unroll
  for (int o = 1; o < 16; o <<= 1) m = fmaxf(m, __shfl_xor(m, o, 16));
  float den = 0.f;
  for (int e = e0 + g; e < e1; e += 16){
    int s = esrc[e]; if ((unsigned)s >= (unsigned)ns) s = 0;
    den += __expf(lrelu(ss[(long)s*4 + h] + sdl) - m);
  }
  #pragma unroll
  for (int o = 1; o < 16; o <<= 1) den += __shfl_xor(den, o, 16);
  float inv = 1.f/(den + 1e-16f);
  for (int e = e0 + g; e < e1; e += 16){
    int s = esrc[e]; if ((unsigned)s >= (unsigned)ns) s = 0;
    alpha[(long)e*4 + h] = __expf(lrelu(ss[(long)s*4 + h] + sdl) - m) * inv;
  }
}

// ---------------- aggregate-FIRST gather (r=2, all 4 heads) ---------------
template<int NJ>
__global__ __launch_bounds__(256) void k_gather4(
    const BF16* __restrict__ A, const float* __restrict__ alpha,
    const int* __restrict__ indptr, const int* __restrict__ esrc,
    BF16* __restrict__ G, int n_dst, int Din, int E, int ns)
{
  int wid = (blockIdx.x*blockDim.x + threadIdx.x) >> 6;
  int lane = threadIdx.x & 63;
  if (wid >= n_dst) return;
  int e0 = indptr[wid], e1 = indptr[wid+1];
  e0 = max(0, min(e0, E)); e1 = max(e0, min(e1, E));
  float acc[4][NJ];
  #pragma unroll
  for (int h = 0; h < 4; ++h)
    #pragma unroll
    for (int j = 0; j < NJ; ++j) acc[h][j] = 0.f;
  for (int e = e0; e < e1; ++e){
    int s = esrc[e]; if ((unsigned)s >= (unsigned)ns) s = 0;
    float a0 = alpha[(long)e*4 + 0], a1 = alpha[(long)e*4 + 1];
    float a2 = alpha[(long)e*4 + 2], a3 = alpha[(long)e*4 + 3];
    const BF16* ar = A + (long)s*Din;
    #pragma unroll
    for (int j = 0; j < NJ; ++j){
      float x = ldE(ar, lane + 64*j);
      acc[0][j] += a0*x; acc[1][j] += a1*x; acc[2][j] += a2*x; acc[3][j] += a3*x;
    }
  }
  #pragma unroll
  for (int h = 0; h < 4; ++h)
    #pragma unroll
    for (int j = 0; j < NJ; ++j)
      stE(G, ((long)wid*4 + h)*Din + lane + 64*j, acc[h][j]);
}

// ---------------- aggregation bodies ----------------
__device__ __forceinline__ void agg_body(
    const BF16* __restrict__ Zt, const float* __restrict__ alpha,
    const int* __restrict__ indptr, const int* __restrict__ esrc,
    float* acc, int NJ, int wid, int lane, int TW, int head0, int E, int ns)
{
  int e0 = indptr[wid], e1 = indptr[wid+1];
  e0 = max(0, min(e0, E)); e1 = max(e0, min(e1, E));
  for (int e = e0; e < e1; ++e){
    int s = esrc[e]; if ((unsigned)s >= (unsigned)ns) s = 0;
    float aA = alpha[(long)e*4 + head0];
    float aB = (NJ == 4) ? alpha[(long)e*4 + head0 + 1] : aA;
    const BF16* zr = Zt + (long)s*TW;
    #pragma unroll 4
    for (int j = 0; j < NJ; ++j){
      int col = lane + 64*j;
      if (col < TW) acc[j] += ((NJ == 4 && j >= 2) ? aB : aA) * ldE(zr, col);
    }
  }
}

// ---------------- fused 2-relation aggregation (phase 1, dst=acc) ---------
template<int NJ>
__global__ __launch_bounds__(256) void k_agg2(
    const BF16* __restrict__ Z0, const BF16* __restrict__ Z1,
    const float* __restrict__ a0, const float* __restrict__ a1,
    const int* __restrict__ ip0, const int* __restrict__ ip1,
    const int* __restrict__ es0, const int* __restrict__ es1,
    BF16* __restrict__ out, int ldc, int c0w, int TW, int head0,
    int n_dst, int E, int ns0, int ns1)
{
  int wid = (blockIdx.x*blockDim.x + threadIdx.x) >> 6;
  int lane = threadIdx.x & 63;
  if (wid >= n_dst) return;
  float acc[NJ];
  #pragma unroll
  for (int j = 0; j < NJ; ++j) acc[j] = 0.f;
  agg_body(Z0, a0, ip0, es0, acc, NJ, wid, lane, TW, head0, E, ns0);
  agg_body(Z1, a1, ip1, es1, acc, NJ, wid, lane, TW, head0, E, ns1);
  #pragma unroll
  for (int j = 0; j < NJ; ++j){
    int col = lane + 64*j;
    if (col < TW) stE(out, (long)wid*ldc + c0w + col, acc[j]);
  }
}

// ---------------- fused 3-relation aggregation (phase 2, dst=tx) ----------
template<int NJ>
__global__ __launch_bounds__(256) void k_agg3(
    const BF16* __restrict__ Z0, const BF16* __restrict__ Z1, const BF16* __restrict__ Z2,
    const float* __restrict__ a0, const float* __restrict__ a1, const float* __restrict__ a2,
    const int* __restrict__ ip0, const int* __restrict__ ip1, const int* __restrict__ ip2,
    const int* __restrict__ es0, const int* __restrict__ es1, const int* __restrict__ es2,
    BF16* __restrict__ out, int ldc, int TW, int head0,
    int n_dst, int E, int ns0, int ns1, int ns2)
{
  int wid = (blockIdx.x*blockDim.x + threadIdx.x) >> 6;
  int lane = threadIdx.x & 63;
  if (wid >= n_dst) return;
  float acc[NJ];
  #pragma unroll
  for (int j = 0; j < NJ; ++j) acc[j] = 0.f;
  agg_body(Z0, a0, ip0, es0, acc, NJ, wid, lane, TW, head0, E, ns0);
  agg_body(Z1, a1, ip1, es1, acc, NJ, wid, lane, TW, head0, E, ns1);
  agg_body(Z2, a2, ip2, es2, acc, NJ, wid, lane, TW, head0, E, ns2);
  #pragma unroll
  for (int j = 0; j < NJ; ++j){
    int col = lane + 64*j;
    if (col < TW) stE(out, (long)wid*ldc + col, acc[j]);
  }
}

// ---------------- BN stats over nw_tile [N, TW] bf16 ----------------------
__global__ void k_bnp(const BF16* __restrict__ nw, float* __restrict__ bnp,
                      int N, int TW, int P)
{
  int col  = threadIdx.x & (TW - 1);
  int slot = threadIdx.x / TW;
  int rpb  = 256 / TW;
  int p    = blockIdx.x*rpb + slot;
  float s = 0.f, s2 = 0.f;
  for (long r = p; r < N; r += P){
    float v = ldE(nw, r*TW + col);
    s += v; s2 += v*v;
  }
  bnp[(long)p*2*TW + col]      = s;
  bnp[(long)p*2*TW + TW + col] = s2;
}
__global__ void k_bnf(const float* __restrict__ bnp, float* __restrict__ bns,
                      int P, int TW)
{
  int c = blockIdx.x*256 + threadIdx.x;
  if (c >= 2*TW) return;
  float s = 0.f;
  for (int p = 0; p < P; ++p) s += bnp[(long)p*2*TW + c];
  bns[c] = s;
}
__global__ void k_bn_apply(const BF16* __restrict__ nw, const float* __restrict__ bns,
                           const float* __restrict__ g, const float* __restrict__ b,
                           BF16* __restrict__ A, int N, int TW, int c0, int res)
{
  long total = (long)N*TW;
  for (long i = (long)blockIdx.x*blockDim.x + threadIdx.x; i < total;
       i += (long)gridDim.x*blockDim.x){
    int col = (int)(i % TW);
    long r  = i / TW;
    float mu  = bns[col] / (float)N;
    float var = bns[TW + col] / (float)N - mu*mu;
    int gc = c0 + col;
    float sc = g[gc] * rsqrtf(var + 1e-5f);
    float sh = b[gc] - mu*sc;
    float v = fmaxf(ldE(nw, i)*sc + sh, 0.f);
    long ai = r*512 + gc;
    if (res) v += ldE(A, ai);
    stE(A, ai, v);
  }
}

// ---------------- acc/mer update ----------------
__global__ void k_update(const BF16* __restrict__ B, const float* __restrict__ ab1,
                         const float* __restrict__ ab2, BF16* __restrict__ A,
                         long n512, int res)
{
  for (long i = (long)blockIdx.x*blockDim.x + threadIdx.x; i < n512;
       i += (long)gridDim.x*blockDim.x){
    int c = (int)(i & 511);
    float v = ldE(B, i) + ab1[c] + (ab2 ? ab2[c] : 0.f);
    v = fmaxf(v, 0.f);
    if (res) v += ldE(A, i);
    stE(A, i, v);
  }
}

// ---------------- head logits ----------------
__global__ void k_logits(const BF16* __restrict__ Hid, const float* __restrict__ Wh2,
                         const float* __restrict__ bh2, float* __restrict__ out, int N)
{
  int node = (blockIdx.x*blockDim.x + threadIdx.x) >> 6;
  int lane = threadIdx.x & 63;
  if (node >= N) return;
  float v = ldE(Hid, (long)node*64 + lane) * Wh2[lane];
  #pragma unroll
  for (int off = 32; off; off >>= 1) v += __shfl_down(v, off, 64);
  if (lane == 0) out[node] = v + bh2[0];
}

// ---------------------------------------------------------------------------
struct Arena {
  BF16 *A[3];
  BF16 *Bst[3];
  BF16 *Zt;        // blockA: phase1 Zr0 / phase2 Z3/Z4/Z5
  BF16 *blkB;      // blockB: phase1 Zr1 & G_mer / phase2 nw (lifetimes disjoint)
  BF16 *hidden;
  float *scoreS, *scoreD;
  float *alpha;
  float *Fbuf;
  float *bnp, *bns;
  int *counts, *bsums;
  int *indptr[6], *esrc[6];
  BF16 *Wt0[6], *WtL[2][6], *Wh1t;
  size_t total;
};

extern "C" void kernel_launch(void* const* d_in, const int* in_sizes, int n_in,
                              void* d_out, int out_size, void* d_ws, size_t ws_size,
                              hipStream_t stream)
{
  const float* x_tx  = (const float*)d_in[0];
  const float* x_acc = (const float*)d_in[1];
  const float* x_mer = (const float*)d_in[2];
  const float* Wtx = (const float*)d_in[3];  const float* btx  = (const float*)d_in[4];
  const float* Wacc= (const float*)d_in[5];  const float* bacc = (const float*)d_in[6];
  const float* Wmer= (const float*)d_in[7];  const float* bmer = (const float*)d_in[8];
  const float* W0   = (const float*)d_in[9];
  const float* Wrest= (const float*)d_in[10];
  const float* att_s= (const float*)d_in[11];
  const float* att_d= (const float*)d_in[12];
  const float* att_b= (const float*)d_in[13];
  const float* bn_g = (const float*)d_in[14];
  const float* bn_b = (const float*)d_in[15];
  const float* Wh1  = (const float*)d_in[16]; const float* bh1 = (const float*)d_in[17];
  const float* Wh2  = (const float*)d_in[18]; const float* bh2 = (const float*)d_in[19];
  const int*   edges= (const int*)d_in[20];

  const int E    = in_sizes[20] / 12;
  const int nTx  = in_sizes[0] / 64;
  const int nAcc = in_sizes[1] / 32;
  const int nMer = in_sizes[2] / 32;
  const int nOf[3]   = {nTx, nAcc, nMer};
  const int SRC_T[6] = {0,0,0,1,1,2};
  const int DST_T[6] = {1,1,2,0,0,0};
  const int maxN = max(nTx, max(nAcc, nMer));
  (void)n_in;

  auto layout = [&](int TW)->Arena{
    Arena P{};
    size_t off = 0;
    auto a = [&](size_t bytes)->char*{
      char* p = (char*)d_ws + off;
      off += (bytes + 255) & ~(size_t)255;
      return p;
    };
    auto al = [](size_t b){ return (b + 255) & ~(size_t)255; };
    P.A[0]   = (BF16*)a((size_t)nTx *512*2);
    P.A[1]   = (BF16*)a((size_t)nAcc*512*2);
    P.A[2]   = (BF16*)a((size_t)nMer*512*2);
    P.Bst[1] = (BF16*)a((size_t)nAcc*512*2);
    P.Bst[2] = (BF16*)a((size_t)nMer*512*2);
    size_t zrowsA = (size_t)maxN > (size_t)2*nAcc + nMer ? (size_t)maxN : (size_t)2*nAcc + nMer;
    size_t blkA = al(zrowsA*TW*2);
    size_t blkBsz = al((size_t)nTx*TW*2);
    size_t gB = al((size_t)nMer*4*512*2);
    if (gB > blkBsz) blkBsz = gB;
    size_t scoreB = al((size_t)3*maxN*4*4)*2;
    size_t hidB = al((size_t)nTx*64*2);
    size_t scr = blkA + blkBsz;
    if (scr < scoreB) scr = scoreB;
    if (scr < hidB)   scr = hidB;
    char* scrBase = a(scr);
    P.Zt     = (BF16*)scrBase;
    P.blkB   = (BF16*)(scrBase + blkA);
    P.scoreS = (float*)scrBase;
    P.scoreD = (float*)(scrBase + al((size_t)3*maxN*4*4));
    P.hidden = (BF16*)scrBase;
    P.alpha  = (float*)a((size_t)3*E*4*4);
    P.Fbuf   = (float*)a((size_t)6*8*512*4);
    P.bnp    = (float*)a(262144);
    P.bns    = (float*)a(4096);
    P.counts = (int*)a((size_t)maxN*4);
    P.bsums  = (int*)a(4096);
    for (int r = 0; r < 6; ++r){
      P.indptr[r] = (int*)a((size_t)(nOf[DST_T[r]]+1)*4);
      P.esrc[r]   = (int*)a((size_t)E*4);
    }
    for (int r = 0; r < 6; ++r) P.Wt0[r] = (BF16*)a((size_t)512*128*2);
    for (int l = 0; l < 2; ++l)
      for (int r = 0; r < 6; ++r) P.WtL[l][r] = (BF16*)a((size_t)512*512*2);
    P.Wh1t = (BF16*)a((size_t)64*512*2);
    P.total = off;
    return P;
  };

  int TW = 0;
  Arena P{};
  for (int cand : {128, 64}){
    P = layout(cand);
    if (P.total <= ws_size){ TW = cand; break; }
  }
  if (TW == 0){
    float sentinel = 10000.0f + (float)(ws_size >> 20);
    k_fill_f32<<<dim3((out_size+255)/256), dim3(256), 0, stream>>>((float*)d_out, (long)out_size, sentinel);
    return;
  }
  const int nTiles = 512 / TW;
  const int NJv = TW/64;
  const int rpb = 256 / TW, PBX = 128, Pp = PBX * rpb;
  dim3 b256(256);

  // ---- 0. weight prep (3 batched launches) ----
  k_wt<<<dim3(16,4,6),  b256, 0, stream>>>(W0,    P.Wt0[0],    128, 512);
  k_wt<<<dim3(16,16,12),b256, 0, stream>>>(Wrest, P.WtL[0][0], 512, 512);
  k_wt<<<dim3(2,16,1),  b256, 0, stream>>>(Wh1,   P.Wh1t,      512, 64);

  // GEMM helpers (single and z=2 pair; Zr1 address passed via cZst)
  auto mfma_gemm = [&](const BF16* A, const BF16* Bt, BF16* Cp, int M, int K, int c0, int ldc){
    if (TW >= 128)
      k_mfma<128,2,2,4,4,BF16><<<dim3(TW/128,(M+127)/128,1),b256,0,stream>>>(
          A, Bt, Cp, M, K, c0, ldc, K, (const float*)nullptr, 0, 0, 0L, 0L, 0, (const BF16*)nullptr);
    else
      k_mfma<64,4,1,2,4,BF16><<<dim3(1,(M+127)/128,1),b256,0,stream>>>(
          A, Bt, Cp, M, K, c0, ldc, K, (const float*)nullptr, 0, 0, 0L, 0L, 0, (const BF16*)nullptr);
  };
  auto mfma_pair = [&](const BF16* A, const BF16* Bt0, const BF16* Bt1p, BF16* Cp, long cZst,
                       int M, int K, int c0){
    if (TW >= 128)
      k_mfma<128,2,2,4,4,BF16><<<dim3(TW/128,(M+127)/128,2),b256,0,stream>>>(
          A, Bt0, Cp, M, K, c0, TW, K, (const float*)nullptr, 0, 0, 0L, cZst, 0, Bt1p);
    else {
      mfma_gemm(A, Bt0, Cp, M, K, c0, TW);
      mfma_gemm(A, Bt1p, Cp + cZst, M, K, c0, TW);
    }
  };

  // ---- 1. CSR build (per-relation, R13 verbatim) ----
  for (int r = 0; r < 6; ++r){
    int nd = nOf[DST_T[r]], ns = nOf[SRC_T[r]];
    const int* srcP = edges + (size_t)r*2*E;
    const int* dstP = srcP + E;
    int nb = (nd + 255)/256;
    k_zero   <<<dim3(nb),          b256, 0, stream>>>(P.counts, (long)nd);
    k_hist   <<<dim3((E+255)/256), b256, 0, stream>>>(dstP, P.counts, E, nd);
    k_scan1  <<<dim3(nb),          b256, 0, stream>>>(P.counts, P.indptr[r], P.bsums, nd);
    k_scan2  <<<dim3(1),           dim3(1024),0, stream>>>(P.bsums, nb);
    k_scan3  <<<dim3(nb),          b256, 0, stream>>>(P.indptr[r], P.bsums, nd);
    k_zero   <<<dim3(nb),          b256, 0, stream>>>(P.counts, (long)nd);
    k_scatter<<<dim3((E+255)/256), b256, 0, stream>>>(srcP, dstP, P.indptr[r], P.counts, P.esrc[r], E, nd, ns);
  }

  // ---- 2. encoders ----
  k_gemm<float,BF16><<<dim3(2,(nTx +63)/64), b256, 0, stream>>>(x_tx,  Wtx,  P.A[0], nTx,  128, 64, 128, btx,  1);
  k_gemm<float,BF16><<<dim3(2,(nAcc+63)/64), b256, 0, stream>>>(x_acc, Wacc, P.A[1], nAcc, 128, 32, 128, bacc, 1);
  k_gemm<float,BF16><<<dim3(2,(nMer+63)/64), b256, 0, stream>>>(x_mer, Wmer, P.A[2], nMer, 128, 32, 128, bmer, 1);

  const long mS = (long)maxN*4;
  // ---- 3. layers ----
  for (int i = 0; i < 3; ++i){
    const int Din = (i == 0) ? 128 : 512;
    const int res = (i > 0) ? 1 : 0;
    const long fstr = 8L*Din;
    const float* WbaseL = (i == 0) ? W0 : (Wrest + (size_t)(i-1)*6*512*512);
    const long wstride = (i == 0) ? 128L*512 : 512L*512;
    auto Wtof = [&](int r)->const BF16*{ return (i == 0) ? P.Wt0[r] : P.WtL[i-1][r]; };

    k_foldAll<<<dim3(48*Din/4), b256, 0, stream>>>(WbaseL, wstride,
        att_s + (size_t)i*6*512, att_d + (size_t)i*6*512, P.Fbuf, Din);

    // ---- Phase 1: scores, then ALL alphas (batched) ----
    k_scoreM<3><<<dim3((nTx+15)/16), b256, 0, stream>>>(P.A[0], P.Fbuf,           fstr, P.scoreS, mS, nTx, Din);
    k_scoreM<2><<<dim3((nAcc+15)/16), b256, 0, stream>>>(P.A[1], P.Fbuf + 4*Din,  fstr, P.scoreD, mS, nAcc, Din);
    k_scoreM<1><<<dim3((nMer+15)/16), b256, 0, stream>>>(P.A[2], P.Fbuf + 20*Din, fstr, P.scoreD + 2*mS, 0, nMer, Din);
    {
      AlphaArgs aa{};
      int ndMax = 0;
      for (int r = 0; r < 3; ++r){
        aa.ss[r] = P.scoreS + r*mS; aa.sd[r] = P.scoreD + r*mS;
        aa.ip[r] = P.indptr[r]; aa.es[r] = P.esrc[r];
        aa.al[r] = P.alpha + (size_t)r*E*4;
        aa.nd[r] = nOf[DST_T[r]]; aa.ns[r] = nTx;
        if (aa.nd[r] > ndMax) ndMax = aa.nd[r];
      }
      k_alpha3b<<<dim3((ndMax+3)/4,3), b256, 0, stream>>>(aa, E);
    }
    // r=2 (tx->mer): aggregate-FIRST; 4 head-GEMMs in one z=4 launch
    {
      BF16* Gm = P.blkB;
      if (Din == 512)
        k_gather4<8><<<dim3((nMer+3)/4), b256, 0, stream>>>(P.A[0], P.alpha + (size_t)2*E*4,
            P.indptr[2], P.esrc[2], Gm, nMer, Din, E, nTx);
      else
        k_gather4<2><<<dim3((nMer+3)/4), b256, 0, stream>>>(P.A[0], P.alpha + (size_t)2*E*4,
            P.indptr[2], P.esrc[2], Gm, nMer, Din, E, nTx);
      k_mfma<128,2,2,4,4,BF16><<<dim3(1,(nMer+127)/128,4), b256, 0, stream>>>(
          Gm, Wtof(2), P.Bst[2], nMer, Din, 0, 512, 4*Din,
          (const float*)nullptr, 0, 0, (long)Din, 128L, 128, (const BF16*)nullptr);
    }
    // r=0,1 (tx->acc): z=2 pair GEMM (Zr1 = blkB, via cZst) + fused agg2
    {
      BF16* Zr0 = P.Zt;
      BF16* Zr1 = P.blkB;          // G_mer dead by now (same addresses as R13)
      long zst = (long)(Zr1 - Zr0);
      for (int t = 0; t < nTiles; ++t){
        int c0 = t*TW;
        mfma_pair(P.A[0], Wtof(0), Wtof(1), Zr0, zst, nTx, Din, c0);
        dim3 ga((nAcc+3)/4);
        if (NJv == 2)
          k_agg2<2><<<ga,b256,0,stream>>>(Zr0, Zr1, P.alpha, P.alpha + (size_t)E*4,
              P.indptr[0], P.indptr[1], P.esrc[0], P.esrc[1],
              P.Bst[1], 512, c0, TW, c0>>7, nAcc, E, nTx, nTx);
        else
          k_agg2<1><<<ga,b256,0,stream>>>(Zr0, Zr1, P.alpha, P.alpha + (size_t)E*4,
              P.indptr[0], P.indptr[1], P.esrc[0], P.esrc[1],
              P.Bst[1], 512, c0, TW, c0>>7, nAcc, E, nTx, nTx);
      }
    }

    // ---- Phase 2 (dst=tx; src=acc r=3,4; mer r=5) ----
    k_scoreM<2><<<dim3((nAcc+15)/16), b256, 0, stream>>>(P.A[1], P.Fbuf + 24*Din, fstr, P.scoreS, mS, nAcc, Din);
    k_scoreM<1><<<dim3((nMer+15)/16), b256, 0, stream>>>(P.A[2], P.Fbuf + 40*Din, fstr, P.scoreS + 2*mS, 0, nMer, Din);
    k_scoreM<3><<<dim3((nTx+15)/16), b256, 0, stream>>>(P.A[0], P.Fbuf + 28*Din, fstr, P.scoreD, mS, nTx, Din);
    {
      AlphaArgs aa{};
      for (int q = 0; q < 3; ++q){
        int r = 3 + q;
        aa.ss[q] = P.scoreS + q*mS; aa.sd[q] = P.scoreD + q*mS;
        aa.ip[q] = P.indptr[r]; aa.es[q] = P.esrc[r];
        aa.al[q] = P.alpha + (size_t)q*E*4;
        aa.nd[q] = nTx; aa.ns[q] = nOf[SRC_T[r]];
      }
      k_alpha3b<<<dim3((nTx+3)/4,3), b256, 0, stream>>>(aa, E);
    }
    BF16* Z3 = P.Zt;
    BF16* Z4 = P.Zt + (size_t)nAcc*TW;
    BF16* Z5 = P.Zt + (size_t)2*nAcc*TW;
    BF16* nw = P.blkB;
    for (int t = 0; t < nTiles; ++t){
      int c0 = t*TW;
      mfma_pair(P.A[1], Wtof(3), Wtof(4), Z3, (long)nAcc*TW, nAcc, Din, c0);
      mfma_gemm(P.A[2], Wtof(5), Z5, nMer, Din, c0, TW);
      dim3 ga((nTx+3)/4);
      if (NJv == 2)
        k_agg3<2><<<ga,b256,0,stream>>>(Z3,Z4,Z5, P.alpha, P.alpha+(size_t)E*4, P.alpha+(size_t)2*E*4,
            P.indptr[3],P.indptr[4],P.indptr[5], P.esrc[3],P.esrc[4],P.esrc[5],
            nw, TW, TW, c0>>7, nTx, E, nAcc, nAcc, nMer);
      else
        k_agg3<1><<<ga,b256,0,stream>>>(Z3,Z4,Z5, P.alpha, P.alpha+(size_t)E*4, P.alpha+(size_t)2*E*4,
            P.indptr[3],P.indptr[4],P.indptr[5], P.esrc[3],P.esrc[4],P.esrc[5],
            nw, TW, TW, c0>>7, nTx, E, nAcc, nAcc, nMer);
      k_bnp<<<dim3(PBX), b256, 0, stream>>>(nw, P.bnp, nTx, TW, Pp);
      k_bnf<<<dim3((2*TW+255)/256), b256, 0, stream>>>(P.bnp, P.bns, Pp, TW);
      k_bn_apply<<<dim3(2048), b256, 0, stream>>>(nw, P.bns,
          bn_g + (size_t)i*512, bn_b + (size_t)i*512, P.A[0], nTx, TW, c0, res);
    }
    // ---- Phase 3 ----
    const float* ab0 = att_b + ((size_t)(i*6 + 0))*512;
    const float* ab1 = att_b + ((size_t)(i*6 + 1))*512;
    const float* ab2 = att_b + ((size_t)(i*6 + 2))*512;
    k_update<<<dim3(2048), b256, 0, stream>>>(P.Bst[1], ab0, ab1, P.A[1], (long)nAcc*512, res);
    k_update<<<dim3(256),  b256, 0, stream>>>(P.Bst[2], ab2, (const float*)nullptr, P.A[2], (long)nMer*512, res);
  }

  // ---- 4. head ----
  k_mfma<64,4,1,2,4,BF16><<<dim3(1,(nTx+127)/128,1), b256, 0, stream>>>(
      P.A[0], P.Wh1t, P.hidden, nTx, 512, 0, 64, 512, bh1, 1, 0,
      0L, 0L, 0, (const BF16*)nullptr);
  k_logits<<<dim3((nTx+3)/4), b256, 0, stream>>>(P.hidden, Wh2, bh2, (float*)d_out, nTx);
}

// Round 16
// 10109.668 us; speedup vs baseline: 2.5682x; 1.0373x over previous
//
#include <hip/hip_runtime.h>
#include <math.h>

// ---------------------------------------------------------------------------
// FraudGAT: bf16 storage, MFMA projections, pre-transposed bf16 weights.
// R16 = R15 + vectorization basket (no structural change):
//   - agg/gather loops: ushort2/short8 loads (half/eighth the mem instrs)
//   - bn_apply/update: short8, 8 elems per thread
//   - bnf reducer workload halved (PBX=64)
// ---------------------------------------------------------------------------

typedef unsigned short BF16;
typedef short short8 __attribute__((ext_vector_type(8)));
typedef float f32x4 __attribute__((ext_vector_type(4)));
typedef __bf16 bf16x8 __attribute__((ext_vector_type(8)));

static __device__ __forceinline__ float lrelu(float x){ return x > 0.f ? x : 0.2f*x; }

__device__ __forceinline__ float ldE(const float* p, long i){ return p[i]; }
__device__ __forceinline__ float ldE(const BF16* p, long i){
  return __uint_as_float((unsigned)p[i] << 16);
}
__device__ __forceinline__ void stE(float* p, long i, float v){ p[i] = v; }
__device__ __forceinline__ void stE(BF16* p, long i, float v){
  unsigned u = __float_as_uint(v);
  p[i] = (BF16)((u + 0x7FFFu + ((u >> 16) & 1u)) >> 16);
}
__device__ __forceinline__ BF16 f2bf(float v){
  unsigned u = __float_as_uint(v);
  return (BF16)((u + 0x7FFFu + ((u >> 16) & 1u)) >> 16);
}
__device__ __forceinline__ float bf2f(short s){
  return __uint_as_float((unsigned)(unsigned short)s << 16);
}
__device__ __forceinline__ float4 ld4E(const float* p, long i){ return *(const float4*)(p + i); }
__device__ __forceinline__ float4 ld4E(const BF16* p, long i){
  ushort4 s = *(const ushort4*)(p + i);
  return make_float4(__uint_as_float((unsigned)s.x<<16), __uint_as_float((unsigned)s.y<<16),
                     __uint_as_float((unsigned)s.z<<16), __uint_as_float((unsigned)s.w<<16));
}

// ---------------- utility ----------------
__global__ void k_zero(int* __restrict__ p, long n){
  long i = (long)blockIdx.x*blockDim.x + threadIdx.x;
  if (i < n) p[i] = 0;
}
__global__ void k_fill_f32(float* __restrict__ p, long n, float v){
  long i = (long)blockIdx.x*blockDim.x + threadIdx.x;
  if (i < n) p[i] = v;
}

// ---------------- weight transpose+convert (z-batched) --------------------
__global__ __launch_bounds__(256) void k_wt(const float* __restrict__ in, BF16* __restrict__ out,
                                            int K, int N)
{
  in  += (long)blockIdx.z*K*N;
  out += (long)blockIdx.z*N*K;
  __shared__ float t[32][33];
  int kb = blockIdx.y*32, nb = blockIdx.x*32;
  int tx = threadIdx.x & 31, ty8 = threadIdx.x >> 5;
  for (int j = ty8; j < 32; j += 8){
    int k = kb + j, n = nb + tx;
    t[j][tx] = (k < K && n < N) ? in[(long)k*N + n] : 0.f;
  }
  __syncthreads();
  for (int j = ty8; j < 32; j += 8){
    int n = nb + j, k = kb + tx;
    if (n < N && k < K) out[(long)n*K + k] = f2bf(t[tx][j]);
  }
}

// ---------------- fold ALL 12 tables in one launch ------------------------
__global__ __launch_bounds__(256) void k_foldAll(
    const float* __restrict__ Wbase, long wstride,
    const float* __restrict__ atts, const float* __restrict__ attd,
    float* __restrict__ F, int Din)
{
  int w = (blockIdx.x*256 + threadIdx.x) >> 6;
  int lane = threadIdx.x & 63;
  int total = 48*Din;
  if (w >= total) return;
  int k = w % Din;
  int rem = w / Din;
  int h = rem & 3, sd = (rem >> 2) & 1, r = rem >> 3;
  const float* wr = Wbase + (long)r*wstride + (long)k*512 + h*128;
  const float* ar = (sd ? attd : atts) + r*512 + h*128;
  float p = wr[lane]*ar[lane] + wr[lane+64]*ar[lane+64];
  #pragma unroll
  for (int off = 32; off; off >>= 1) p += __shfl_down(p, off, 64);
  if (lane == 0) F[(long)((r*2+sd)*4 + h)*Din + k] = p;
}

// ---------------- MFMA GEMM (optionally z-batched) ------------------------
template<int BN, int WM, int WN, int FM, int FN, typename TC>
__global__ __launch_bounds__(256) void k_mfma(
    const BF16* __restrict__ A, const BF16* __restrict__ Bt, TC* __restrict__ C,
    int M, int K, int c0, int ldc, int lda, const float* __restrict__ bias,
    int doRelu, int accum, long aZst, long cZst, int c0Zst, const BF16* __restrict__ Bt1)
{
  constexpr int BM = 128;
  constexpr int LSTR = 72;
  __shared__ __attribute__((aligned(16))) short Als[BM][LSTR];
  __shared__ __attribute__((aligned(16))) short Bls[BN][LSTR];
  const int z = blockIdx.z;
  A += (long)z*aZst;
  C += (long)z*cZst;
  c0 += z*c0Zst;
  if (z >= 1 && Bt1) Bt = Bt1;
  const int bn0 = blockIdx.x * BN;
  const int bm = blockIdx.y*BM;
  const int tid = threadIdx.x;
  const int wave = tid >> 6, lane = tid & 63;
  const int wr = wave / WN, wc = wave % WN;
  const int lrow = lane & 15, kg = lane >> 4;
  f32x4 acc[FM][FN] = {};
  for (int k0 = 0; k0 < K; k0 += 64){
    #pragma unroll
    for (int t = 0; t < 4; ++t){
      int idx = tid + t*256;
      int row = idx >> 3, kc = (idx & 7) << 3;
      int gr = bm + row;
      short8 v = {};
      if (gr < M) v = *(const short8*)(A + (long)gr*lda + k0 + kc);
      *(short8*)&Als[row][kc] = v;
    }
    #pragma unroll
    for (int t = 0; t < BN/32; ++t){
      int idx = tid + t*256;
      int row = idx >> 3, kc = (idx & 7) << 3;
      *(short8*)&Bls[row][kc] = *(const short8*)(Bt + (long)(c0+bn0+row)*K + k0 + kc);
    }
    __syncthreads();
    #pragma unroll
    for (int kk = 0; kk < 2; ++kk){
      short8 af[FM], bq[FN];
      #pragma unroll
      for (int m = 0; m < FM; ++m)
        af[m] = *(const short8*)&Als[wr*FM*16 + m*16 + lrow][kk*32 + kg*8];
      #pragma unroll
      for (int n = 0; n < FN; ++n)
        bq[n] = *(const short8*)&Bls[wc*FN*16 + n*16 + lrow][kk*32 + kg*8];
      #pragma unroll
      for (int m = 0; m < FM; ++m)
        #pragma unroll
        for (int n = 0; n < FN; ++n)
          acc[m][n] = __builtin_amdgcn_mfma_f32_16x16x32_bf16(
              __builtin_bit_cast(bf16x8, af[m]), __builtin_bit_cast(bf16x8, bq[n]),
              acc[m][n], 0, 0, 0);
    }
    __syncthreads();
  }
  // epilogue: C/D layout col=lane&15, row=(lane>>4)*4+reg  [m89]
  #pragma unroll
  for (int m = 0; m < FM; ++m){
    #pragma unroll
    for (int n = 0; n < FN; ++n){
      #pragma unroll
      for (int j = 0; j < 4; ++j){
        int row = bm + wr*FM*16 + m*16 + kg*4 + j;
        if (row >= M) continue;
        int col = wc*FN*16 + n*16 + lrow;
        float v = acc[m][n][j];
        if (bias) v += bias[bn0 + col];
        if (doRelu) v = fmaxf(v, 0.f);
        long idx = (long)row*ldc + bn0 + col;
        if (accum) v += ldE(C, idx);
        stE(C, idx, v);
      }
    }
  }
}

// ---------------- naive GEMM (f32 A) for the tiny encoders ----------------
template<typename TA, typename TC>
__global__ __launch_bounds__(256) void k_gemm(
    const TA* __restrict__ A, const float* __restrict__ B, TC* __restrict__ C,
    int M, int N, int K, int ldb, const float* __restrict__ bias, int doRelu)
{
  __shared__ float As[16][64];
  __shared__ float Bs[16][64];
  const int bm = blockIdx.y*64, bn = blockIdx.x*64;
  const int tid = threadIdx.x;
  const int ty = tid >> 4, tx = tid & 15;
  const int ar = tid >> 2;
  const int ac = (tid & 3) << 2;
  const int br = tid >> 4;
  const int bc = (tid & 15) << 2;
  float acc[4][4] = {};
  for (int k0 = 0; k0 < K; k0 += 16){
    int row = bm + ar;
    float4 av = make_float4(0.f,0.f,0.f,0.f);
    if (row < M) av = ld4E(A, (long)row*K + k0 + ac);
    As[ac+0][ar]=av.x; As[ac+1][ar]=av.y; As[ac+2][ar]=av.z; As[ac+3][ar]=av.w;
    float4 bv = make_float4(0.f,0.f,0.f,0.f);
    if (bn + bc + 3 < N) bv = *(const float4*)(B + (long)(k0+br)*ldb + bn + bc);
    *(float4*)&Bs[br][bc] = bv;
    __syncthreads();
    #pragma unroll
    for (int kk = 0; kk < 16; ++kk){
      float a[4], b[4];
      #pragma unroll
      for (int x = 0; x < 4; ++x){ a[x]=As[kk][ty*4+x]; b[x]=Bs[kk][tx*4+x]; }
      #pragma unroll
      for (int y = 0; y < 4; ++y)
        #pragma unroll
        for (int x = 0; x < 4; ++x) acc[y][x] += a[y]*b[x];
    }
    __syncthreads();
  }
  #pragma unroll
  for (int y = 0; y < 4; ++y){
    int row = bm + ty*4 + y;
    if (row >= M) continue;
    #pragma unroll
    for (int x = 0; x < 4; ++x){
      int col = bn + tx*4 + x;
      if (col >= N) continue;
      float v = acc[y][x];
      if (bias) v += bias[col];
      if (doRelu) v = fmaxf(v, 0.f);
      stE(C, (long)row*N + col, v);
    }
  }
}

// ---------------- merged scores: R relations, one pass over X -------------
template<int R>
__global__ __launch_bounds__(256) void k_scoreM(
    const BF16* __restrict__ X, const float* __restrict__ Ftab, long fstride,
    float* __restrict__ out, long ostride, int N, int Din)
{
  int wave = threadIdx.x >> 6, lane = threadIdx.x & 63;
  int node0 = blockIdx.x*16 + wave*4;
  if (node0 >= N) return;
  int base = lane*8;
  bool act = base < Din;
  float x[4][8];
  #pragma unroll
  for (int t = 0; t < 4; ++t){
    int node = node0 + t;
    if (act && node < N){
      short8 v = *(const short8*)(X + (long)node*Din + base);
      #pragma unroll
      for (int j = 0; j < 8; ++j) x[t][j] = bf2f(v[j]);
    } else {
      #pragma unroll
      for (int j = 0; j < 8; ++j) x[t][j] = 0.f;
    }
  }
  #pragma unroll
  for (int r = 0; r < R; ++r){
    const float* F = Ftab + (long)r*fstride;
    float p[4][4] = {};
    #pragma unroll
    for (int h = 0; h < 4; ++h){
      float f[8];
      if (act){
        float4 fa = *(const float4*)(F + h*Din + base);
        float4 fb = *(const float4*)(F + h*Din + base + 4);
        f[0]=fa.x; f[1]=fa.y; f[2]=fa.z; f[3]=fa.w;
        f[4]=fb.x; f[5]=fb.y; f[6]=fb.z; f[7]=fb.w;
      } else {
        #pragma unroll
        for (int j = 0; j < 8; ++j) f[j] = 0.f;
      }
      #pragma unroll
      for (int t = 0; t < 4; ++t)
        #pragma unroll
        for (int j = 0; j < 8; ++j) p[t][h] += x[t][j]*f[j];
    }
    #pragma unroll
    for (int t = 0; t < 4; ++t)
      #pragma unroll
      for (int h = 0; h < 4; ++h)
        #pragma unroll
        for (int off = 32; off; off >>= 1)
          p[t][h] += __shfl_down(p[t][h], off, 64);
    if (lane == 0){
      #pragma unroll
      for (int t = 0; t < 4; ++t){
        int node = node0 + t;
        if (node < N){
          #pragma unroll
          for (int h = 0; h < 4; ++h)
            out[(long)r*ostride + (long)node*4 + h] = p[t][h];
        }
      }
    }
  }
}

// ---------------- CSR build (per-relation) --------------------------------
__global__ void k_hist(const int* __restrict__ dst, int* __restrict__ counts, int E, int nd){
  int e = blockIdx.x*blockDim.x + threadIdx.x;
  if (e >= E) return;
  int d = dst[e];
  if ((unsigned)d < (unsigned)nd) atomicAdd(&counts[d], 1);
}
__global__ void k_scan1(const int* __restrict__ counts, int* __restrict__ indptr,
                        int* __restrict__ bsums, int n)
{
  __shared__ int sm[256];
  int i = blockIdx.x*256 + threadIdx.x;
  int v = (i < n) ? counts[i] : 0;
  sm[threadIdx.x] = v; __syncthreads();
  for (int off = 1; off < 256; off <<= 1){
    int t = (threadIdx.x >= off) ? sm[threadIdx.x - off] : 0;
    __syncthreads();
    sm[threadIdx.x] += t;
    __syncthreads();
  }
  if (i < n) indptr[i+1] = sm[threadIdx.x];
  if (threadIdx.x == 255) bsums[blockIdx.x] = sm[255];
  if (blockIdx.x == 0 && threadIdx.x == 0) indptr[0] = 0;
}
__global__ void k_scan2(int* __restrict__ bsums, int nb){
  __shared__ int sm[1024];
  int t = threadIdx.x;
  int v = (t < nb) ? bsums[t] : 0;
  sm[t] = v; __syncthreads();
  for (int off = 1; off < 1024; off <<= 1){
    int x = (t >= off) ? sm[t - off] : 0;
    __syncthreads();
    sm[t] += x;
    __syncthreads();
  }
  if (t < nb) bsums[t] = sm[t];
}
__global__ void k_scan3(int* __restrict__ indptr, const int* __restrict__ bsums, int n){
  if (blockIdx.x == 0) return;
  int i = blockIdx.x*256 + threadIdx.x;
  int add = bsums[blockIdx.x - 1];
  if (i < n) indptr[i+1] += add;
}
__global__ void k_scatter(const int* __restrict__ src, const int* __restrict__ dst,
                          const int* __restrict__ indptr, int* __restrict__ cursor,
                          int* __restrict__ esrc, int E, int nd, int ns)
{
  int e = blockIdx.x*blockDim.x + threadIdx.x;
  if (e >= E) return;
  int d = dst[e];
  if ((unsigned)d >= (unsigned)nd) return;
  int s = src[e];
  if ((unsigned)s >= (unsigned)ns) s = 0;
  int pos = indptr[d] + atomicAdd(&cursor[d], 1);
  if (pos >= 0 && pos < E) esrc[pos] = s;
}

// ---------------- batched per-edge alpha (3 relations, grid.y) ------------
struct AlphaArgs {
  const float* ss[3]; const float* sd[3];
  const int* ip[3]; const int* es[3];
  float* al[3]; int nd[3]; int ns[3];
};
__global__ __launch_bounds__(256) void k_alpha3b(AlphaArgs a, int E){
  int r = blockIdx.y;
  int wid = (blockIdx.x*blockDim.x + threadIdx.x) >> 6;
  int lane = threadIdx.x & 63;
  if (wid >= a.nd[r]) return;
  const int* indptr = a.ip[r];
  const int* esrc = a.es[r];
  const float* ss = a.ss[r];
  int ns = a.ns[r];
  int e0 = indptr[wid], e1 = indptr[wid+1];
  e0 = max(0, min(e0, E)); e1 = max(e0, min(e1, E));
  if (e0 >= e1) return;
  int h = lane >> 4, g = lane & 15;
  float sdl = a.sd[r][(long)wid*4 + h];
  float* alpha = a.al[r];
  float m = -INFINITY;
  for (int e = e0 + g; e < e1; e += 16){
    int s = esrc[e]; if ((unsigned)s >= (unsigned)ns) s = 0;
    m = fmaxf(m, lrelu(ss[(long)s*4 + h] + sdl));
  }
  #pragma unroll
  for (int o = 1; o < 16; o <<= 1) m = fmaxf(m, __shfl_xor(m, o, 16));
  float den = 0.f;
  for (int e = e0 + g; e < e1; e += 16){
    int s = esrc[e]; if ((unsigned)s >= (unsigned)ns) s = 0;
    den += __expf(lrelu(ss[(long)s*4 + h] + sdl) - m);
  }
  #pragma unroll
  for (int o = 1; o < 16; o <<= 1) den += __shfl_xor(den, o, 16);
  float inv = 1.f/(den + 1e-16f);
  for (int e = e0 + g; e < e1; e += 16){
    int s = esrc[e]; if ((unsigned)s >= (unsigned)ns) s = 0;
    alpha[(long)e*4 + h] = __expf(lrelu(ss[(long)s*4 + h] + sdl) - m) * inv;
  }
}

// ---------------- aggregate-FIRST gather (r=2, all 4 heads, vectorized) ---
template<int NJ>
__global__ __launch_bounds__(256) void k_gather4(
    const BF16* __restrict__ A, const float* __restrict__ alpha,
    const int* __restrict__ indptr, const int* __restrict__ esrc,
    BF16* __restrict__ G, int n_dst, int Din, int E, int ns)
{
  int wid = (blockIdx.x*blockDim.x + threadIdx.x) >> 6;
  int lane = threadIdx.x & 63;
  if (wid >= n_dst) return;
  int e0 = indptr[wid], e1 = indptr[wid+1];
  e0 = max(0, min(e0, E)); e1 = max(e0, min(e1, E));
  float acc[4][NJ];
  #pragma unroll
  for (int h = 0; h < 4; ++h)
    #pragma unroll
    for (int j = 0; j < NJ; ++j) acc[h][j] = 0.f;
  for (int e = e0; e < e1; ++e){
    int s = esrc[e]; if ((unsigned)s >= (unsigned)ns) s = 0;
    float a0 = alpha[(long)e*4 + 0], a1 = alpha[(long)e*4 + 1];
    float a2 = alpha[(long)e*4 + 2], a3 = alpha[(long)e*4 + 3];
    const BF16* ar = A + (long)s*Din;
    if (NJ == 8){
      short8 v = *(const short8*)(ar + lane*8);
      #pragma unroll
      for (int j = 0; j < NJ; ++j){
        float x = bf2f(v[j]);
        acc[0][j] += a0*x; acc[1][j] += a1*x; acc[2][j] += a2*x; acc[3][j] += a3*x;
      }
    } else {
      ushort2 v = *(const ushort2*)(ar + lane*2);
      float x0 = bf2f((short)v.x), x1 = bf2f((short)v.y);
      acc[0][0] += a0*x0; acc[1][0] += a1*x0; acc[2][0] += a2*x0; acc[3][0] += a3*x0;
      acc[0][1] += a0*x1; acc[1][1] += a1*x1; acc[2][1] += a2*x1; acc[3][1] += a3*x1;
    }
  }
  #pragma unroll
  for (int h = 0; h < 4; ++h){
    if (NJ == 8){
      short8 g;
      #pragma unroll
      for (int j = 0; j < NJ; ++j) g[j] = (short)f2bf(acc[h][j]);
      *(short8*)(G + ((long)wid*4 + h)*Din + lane*8) = g;
    } else {
      ushort2 g;
      g.x = f2bf(acc[h][0]); g.y = f2bf(acc[h][1]);
      *(ushort2*)(G + ((long)wid*4 + h)*Din + lane*2) = g;
    }
  }
}

// ---------------- aggregation body (vectorized ushort2 for NJ==2) ---------
template<int NJ>
__device__ __forceinline__ void agg_body(
    const BF16* __restrict__ Zt, const float* __restrict__ alpha,
    const int* __restrict__ indptr, const int* __restrict__ esrc,
    float* acc, int wid, int lane, int TW, int head0, int E, int ns)
{
  int e0 = indptr[wid], e1 = indptr[wid+1];
  e0 = max(0, min(e0, E)); e1 = max(e0, min(e1, E));
  for (int e = e0; e < e1; ++e){
    int s = esrc[e]; if ((unsigned)s >= (unsigned)ns) s = 0;
    float aA = alpha[(long)e*4 + head0];
    const BF16* zr = Zt + (long)s*TW;
    if (NJ == 2){
      // cols 2*lane, 2*lane+1 (same head at TW<=128)
      ushort2 z = *(const ushort2*)(zr + lane*2);
      acc[0] += aA * bf2f((short)z.x);
      acc[1] += aA * bf2f((short)z.y);
    } else {
      acc[0] += aA * ldE(zr, lane);
    }
  }
}

// ---------------- fused 2-relation aggregation (phase 1, dst=acc) ---------
template<int NJ>
__global__ __launch_bounds__(256) void k_agg2(
    const BF16* __restrict__ Z0, const BF16* __restrict__ Z1,
    const float* __restrict__ a0, const float* __restrict__ a1,
    const int* __restrict__ ip0, const int* __restrict__ ip1,
    const int* __restrict__ es0, const int* __restrict__ es1,
    BF16* __restrict__ out, int ldc, int c0w, int TW, int head0,
    int n_dst, int E, int ns0, int ns1)
{
  int wid = (blockIdx.x*blockDim.x + threadIdx.x) >> 6;
  int lane = threadIdx.x & 63;
  if (wid >= n_dst) return;
  float acc[NJ];
  #pragma unroll
  for (int j = 0; j < NJ; ++j) acc[j] = 0.f;
  agg_body<NJ>(Z0, a0, ip0, es0, acc, wid, lane, TW, head0, E, ns0);
  agg_body<NJ>(Z1, a1, ip1, es1, acc, wid, lane, TW, head0, E, ns1);
  if (NJ == 2){
    ushort2 g; g.x = f2bf(acc[0]); g.y = f2bf(acc[1]);
    *(ushort2*)(out + (long)wid*ldc + c0w + lane*2) = g;
  } else {
    stE(out, (long)wid*ldc + c0w + lane, acc[0]);
  }
}

// ---------------- fused 3-relation aggregation (phase 2, dst=tx) ----------
template<int NJ>
__global__ __launch_bounds__(256) void k_agg3(
    const BF16* __restrict__ Z0, const BF16* __restrict__ Z1, const BF16* __restrict__ Z2,
    const float* __restrict__ a0, const float* __restrict__ a1, const float* __restrict__ a2,
    const int* __restrict__ ip0, const int* __restrict__ ip1, const int* __restrict__ ip2,
    const int* __restrict__ es0, const int* __restrict__ es1, const int* __restrict__ es2,
    BF16* __restrict__ out, int ldc, int TW, int head0,
    int n_dst, int E, int ns0, int ns1, int ns2)
{
  int wid = (blockIdx.x*blockDim.x + threadIdx.x) >> 6;
  int lane = threadIdx.x & 63;
  if (wid >= n_dst) return;
  float acc[NJ];
  #pragma unroll
  for (int j = 0; j < NJ; ++j) acc[j] = 0.f;
  agg_body<NJ>(Z0, a0, ip0, es0, acc, wid, lane, TW, head0, E, ns0);
  agg_body<NJ>(Z1, a1, ip1, es1, acc, wid, lane, TW, head0, E, ns1);
  agg_body<NJ>(Z2, a2, ip2, es2, acc, wid, lane, TW, head0, E, ns2);
  if (NJ == 2){
    ushort2 g; g.x = f2bf(acc[0]); g.y = f2bf(acc[1]);
    *(ushort2*)(out + (long)wid*ldc + lane*2) = g;
  } else {
    stE(out, (long)wid*ldc + lane, acc[0]);
  }
}

// ---------------- BN stats over nw_tile [N, TW] bf16 ----------------------
__global__ void k_bnp(const BF16* __restrict__ nw, float* __restrict__ bnp,
                      int N, int TW, int P)
{
  int col  = threadIdx.x & (TW - 1);
  int slot = threadIdx.x / TW;
  int rpb  = 256 / TW;
  int p    = blockIdx.x*rpb + slot;
  float s = 0.f, s2 = 0.f;
  for (long r = p; r < N; r += P){
    float v = ldE(nw, r*TW + col);
    s += v; s2 += v*v;
  }
  bnp[(long)p*2*TW + col]      = s;
  bnp[(long)p*2*TW + TW + col] = s2;
}
__global__ void k_bnf(const float* __restrict__ bnp, float* __restrict__ bns,
                      int P, int TW)
{
  int c = blockIdx.x*256 + threadIdx.x;
  if (c >= 2*TW) return;
  float s = 0.f;
  for (int p = 0; p < P; ++p) s += bnp[(long)p*2*TW + c];
  bns[c] = s;
}
// ---------------- BN apply (short8, 8 elems/thread) -----------------------
__global__ void k_bn_apply(const BF16* __restrict__ nw, const float* __restrict__ bns,
                           const float* __restrict__ g, const float* __restrict__ b,
                           BF16* __restrict__ A, int N, int TW, int c0, int res)
{
  long total8 = (long)N*TW/8;
  for (long i8 = (long)blockIdx.x*blockDim.x + threadIdx.x; i8 < total8;
       i8 += (long)gridDim.x*blockDim.x){
    long i = i8*8;
    int col = (int)(i % TW);
    long r  = i / TW;
    short8 nv = *(const short8*)(nw + i);
    long ai = r*512 + c0 + col;
    short8 av;
    if (res) av = *(const short8*)(A + ai);
    short8 ov;
    #pragma unroll
    for (int k = 0; k < 8; ++k){
      int gc = c0 + col + k;
      float mu  = bns[col+k] / (float)N;
      float var = bns[TW + col + k] / (float)N - mu*mu;
      float sc = g[gc] * rsqrtf(var + 1e-5f);
      float sh = b[gc] - mu*sc;
      float v = fmaxf(bf2f(nv[k])*sc + sh, 0.f);
      if (res) v += bf2f(av[k]);
      ov[k] = (short)f2bf(v);
    }
    *(short8*)(A + ai) = ov;
  }
}

// ---------------- acc/mer update (short8) ----------------
__global__ void k_update(const BF16* __restrict__ B, const float* __restrict__ ab1,
                         const float* __restrict__ ab2, BF16* __restrict__ A,
                         long n512, int res)
{
  long n8 = n512/8;
  for (long i8 = (long)blockIdx.x*blockDim.x + threadIdx.x; i8 < n8;
       i8 += (long)gridDim.x*blockDim.x){
    long i = i8*8;
    int c = (int)(i & 511);
    short8 bv = *(const short8*)(B + i);
    short8 av;
    if (res) av = *(const short8*)(A + i);
    short8 ov;
    #pragma unroll
    for (int k = 0; k < 8; ++k){
      float v = bf2f(bv[k]) + ab1[c+k] + (ab2 ? ab2[c+k] : 0.f);
      v = fmaxf(v, 0.f);
      if (res) v += bf2f(av[k]);
      ov[k] = (short)f2bf(v);
    }
    *(short8*)(A + i) = ov;
  }
}

// ---------------- head logits ----------------
__global__ void k_logits(const BF16* __restrict__ Hid, const float* __restrict__ Wh2,
                         const float* __restrict__ bh2, float* __restrict__ out, int N)
{
  int node = (blockIdx.x*blockDim.x + threadIdx.x) >> 6;
  int lane = threadIdx.x & 63;
  if (node >= N) return;
  float v = ldE(Hid, (long)node*64 + lane) * Wh2[lane];
  #pragma unroll
  for (int off = 32; off; off >>= 1) v += __shfl_down(v, off, 64);
  if (lane == 0) out[node] = v + bh2[0];
}

// ---------------------------------------------------------------------------
struct Arena {
  BF16 *A[3];
  BF16 *Bst[3];
  BF16 *Zt;        // blockA: phase1 Zr0 / phase2 Z3/Z4/Z5
  BF16 *blkB;      // blockB: phase1 Zr1 & G_mer / phase2 nw
  BF16 *hidden;
  float *scoreS, *scoreD;
  float *alpha;
  float *Fbuf;
  float *bnp, *bns;
  int *counts, *bsums;
  int *indptr[6], *esrc[6];
  BF16 *Wt0[6], *WtL[2][6], *Wh1t;
  size_t total;
};

extern "C" void kernel_launch(void* const* d_in, const int* in_sizes, int n_in,
                              void* d_out, int out_size, void* d_ws, size_t ws_size,
                              hipStream_t stream)
{
  const float* x_tx  = (const float*)d_in[0];
  const float* x_acc = (const float*)d_in[1];
  const float* x_mer = (const float*)d_in[2];
  const float* Wtx = (const float*)d_in[3];  const float* btx  = (const float*)d_in[4];
  const float* Wacc= (const float*)d_in[5];  const float* bacc = (const float*)d_in[6];
  const float* Wmer= (const float*)d_in[7];  const float* bmer = (const float*)d_in[8];
  const float* W0   = (const float*)d_in[9];
  const float* Wrest= (const float*)d_in[10];
  const float* att_s= (const float*)d_in[11];
  const float* att_d= (const float*)d_in[12];
  const float* att_b= (const float*)d_in[13];
  const float* bn_g = (const float*)d_in[14];
  const float* bn_b = (const float*)d_in[15];
  const float* Wh1  = (const float*)d_in[16]; const float* bh1 = (const float*)d_in[17];
  const float* Wh2  = (const float*)d_in[18]; const float* bh2 = (const float*)d_in[19];
  const int*   edges= (const int*)d_in[20];

  const int E    = in_sizes[20] / 12;
  const int nTx  = in_sizes[0] / 64;
  const int nAcc = in_sizes[1] / 32;
  const int nMer = in_sizes[2] / 32;
  const int nOf[3]   = {nTx, nAcc, nMer};
  const int SRC_T[6] = {0,0,0,1,1,2};
  const int DST_T[6] = {1,1,2,0,0,0};
  const int maxN = max(nTx, max(nAcc, nMer));
  (void)n_in;

  auto layout = [&](int TW)->Arena{
    Arena P{};
    size_t off = 0;
    auto a = [&](size_t bytes)->char*{
      char* p = (char*)d_ws + off;
      off += (bytes + 255) & ~(size_t)255;
      return p;
    };
    auto al = [](size_t b){ return (b + 255) & ~(size_t)255; };
    P.A[0]   = (BF16*)a((size_t)nTx *512*2);
    P.A[1]   = (BF16*)a((size_t)nAcc*512*2);
    P.A[2]   = (BF16*)a((size_t)nMer*512*2);
    P.Bst[1] = (BF16*)a((size_t)nAcc*512*2);
    P.Bst[2] = (BF16*)a((size_t)nMer*512*2);
    size_t zrowsA = (size_t)maxN > (size_t)2*nAcc + nMer ? (size_t)maxN : (size_t)2*nAcc + nMer;
    size_t blkA = al(zrowsA*TW*2);
    size_t blkBsz = al((size_t)nTx*TW*2);
    size_t gB = al((size_t)nMer*4*512*2);
    if (gB > blkBsz) blkBsz = gB;
    size_t scoreB = al((size_t)3*maxN*4*4)*2;
    size_t hidB = al((size_t)nTx*64*2);
    size_t scr = blkA + blkBsz;
    if (scr < scoreB) scr = scoreB;
    if (scr < hidB)   scr = hidB;
    char* scrBase = a(scr);
    P.Zt     = (BF16*)scrBase;
    P.blkB   = (BF16*)(scrBase + blkA);
    P.scoreS = (float*)scrBase;
    P.scoreD = (float*)(scrBase + al((size_t)3*maxN*4*4));
    P.hidden = (BF16*)scrBase;
    P.alpha  = (float*)a((size_t)3*E*4*4);
    P.Fbuf   = (float*)a((size_t)6*8*512*4);
    P.bnp    = (float*)a(262144);
    P.bns    = (float*)a(4096);
    P.counts = (int*)a((size_t)maxN*4);
    P.bsums  = (int*)a(4096);
    for (int r = 0; r < 6; ++r){
      P.indptr[r] = (int*)a((size_t)(nOf[DST_T[r]]+1)*4);
      P.esrc[r]   = (int*)a((size_t)E*4);
    }
    for (int r = 0; r < 6; ++r) P.Wt0[r] = (BF16*)a((size_t)512*128*2);
    for (int l = 0; l < 2; ++l)
      for (int r = 0; r < 6; ++r) P.WtL[l][r] = (BF16*)a((size_t)512*512*2);
    P.Wh1t = (BF16*)a((size_t)64*512*2);
    P.total = off;
    return P;
  };

  int TW = 0;
  Arena P{};
  for (int cand : {128, 64}){
    P = layout(cand);
    if (P.total <= ws_size){ TW = cand; break; }
  }
  if (TW == 0){
    float sentinel = 10000.0f + (float)(ws_size >> 20);
    k_fill_f32<<<dim3((out_size+255)/256), dim3(256), 0, stream>>>((float*)d_out, (long)out_size, sentinel);
    return;
  }
  const int nTiles = 512 / TW;
  const int NJv = TW/64;
  const int rpb = 256 / TW, PBX = 64, Pp = PBX * rpb;
  dim3 b256(256);

  // ---- 0. weight prep (3 batched launches) ----
  k_wt<<<dim3(16,4,6),  b256, 0, stream>>>(W0,    P.Wt0[0],    128, 512);
  k_wt<<<dim3(16,16,12),b256, 0, stream>>>(Wrest, P.WtL[0][0], 512, 512);
  k_wt<<<dim3(2,16,1),  b256, 0, stream>>>(Wh1,   P.Wh1t,      512, 64);

  auto mfma_gemm = [&](const BF16* A, const BF16* Bt, BF16* Cp, int M, int K, int c0, int ldc){
    if (TW >= 128)
      k_mfma<128,2,2,4,4,BF16><<<dim3(TW/128,(M+127)/128,1),b256,0,stream>>>(
          A, Bt, Cp, M, K, c0, ldc, K, (const float*)nullptr, 0, 0, 0L, 0L, 0, (const BF16*)nullptr);
    else
      k_mfma<64,4,1,2,4,BF16><<<dim3(1,(M+127)/128,1),b256,0,stream>>>(
          A, Bt, Cp, M, K, c0, ldc, K, (const float*)nullptr, 0, 0, 0L, 0L, 0, (const BF16*)nullptr);
  };
  auto mfma_pair = [&](const BF16* A, const BF16* Bt0, const BF16* Bt1p, BF16* Cp, long cZst,
                       int M, int K, int c0){
    if (TW >= 128)
      k_mfma<128,2,2,4,4,BF16><<<dim3(TW/128,(M+127)/128,2),b256,0,stream>>>(
          A, Bt0, Cp, M, K, c0, TW, K, (const float*)nullptr, 0, 0, 0L, cZst, 0, Bt1p);
    else {
      mfma_gemm(A, Bt0, Cp, M, K, c0, TW);
      mfma_gemm(A, Bt1p, Cp + cZst, M, K, c0, TW);
    }
  };

  // ---- 1. CSR build (per-relation) ----
  for (int r = 0; r < 6; ++r){
    int nd = nOf[DST_T[r]], ns = nOf[SRC_T[r]];
    const int* srcP = edges + (size_t)r*2*E;
    const int* dstP = srcP + E;
    int nb = (nd + 255)/256;
    k_zero   <<<dim3(nb),          b256, 0, stream>>>(P.counts, (long)nd);
    k_hist   <<<dim3((E+255)/256), b256, 0, stream>>>(dstP, P.counts, E, nd);
    k_scan1  <<<dim3(nb),          b256, 0, stream>>>(P.counts, P.indptr[r], P.bsums, nd);
    k_scan2  <<<dim3(1),           dim3(1024),0, stream>>>(P.bsums, nb);
    k_scan3  <<<dim3(nb),          b256, 0, stream>>>(P.indptr[r], P.bsums, nd);
    k_zero   <<<dim3(nb),          b256, 0, stream>>>(P.counts, (long)nd);
    k_scatter<<<dim3((E+255)/256), b256, 0, stream>>>(srcP, dstP, P.indptr[r], P.counts, P.esrc[r], E, nd, ns);
  }

  // ---- 2. encoders ----
  k_gemm<float,BF16><<<dim3(2,(nTx +63)/64), b256, 0, stream>>>(x_tx,  Wtx,  P.A[0], nTx,  128, 64, 128, btx,  1);
  k_gemm<float,BF16><<<dim3(2,(nAcc+63)/64), b256, 0, stream>>>(x_acc, Wacc, P.A[1], nAcc, 128, 32, 128, bacc, 1);
  k_gemm<float,BF16><<<dim3(2,(nMer+63)/64), b256, 0, stream>>>(x_mer, Wmer, P.A[2], nMer, 128, 32, 128, bmer, 1);

  const long mS = (long)maxN*4;
  // ---- 3. layers ----
  for (int i = 0; i < 3; ++i){
    const int Din = (i == 0) ? 128 : 512;
    const int res = (i > 0) ? 1 : 0;
    const long fstr = 8L*Din;
    const float* WbaseL = (i == 0) ? W0 : (Wrest + (size_t)(i-1)*6*512*512);
    const long wstride = (i == 0) ? 128L*512 : 512L*512;
    auto Wtof = [&](int r)->const BF16*{ return (i == 0) ? P.Wt0[r] : P.WtL[i-1][r]; };

    k_foldAll<<<dim3(48*Din/4), b256, 0, stream>>>(WbaseL, wstride,
        att_s + (size_t)i*6*512, att_d + (size_t)i*6*512, P.Fbuf, Din);

    // ---- Phase 1: scores, then ALL alphas (batched) ----
    k_scoreM<3><<<dim3((nTx+15)/16), b256, 0, stream>>>(P.A[0], P.Fbuf,           fstr, P.scoreS, mS, nTx, Din);
    k_scoreM<2><<<dim3((nAcc+15)/16), b256, 0, stream>>>(P.A[1], P.Fbuf + 4*Din,  fstr, P.scoreD, mS, nAcc, Din);
    k_scoreM<1><<<dim3((nMer+15)/16), b256, 0, stream>>>(P.A[2], P.Fbuf + 20*Din, fstr, P.scoreD + 2*mS, 0, nMer, Din);
    {
      AlphaArgs aa{};
      int ndMax = 0;
      for (int r = 0; r < 3; ++r){
        aa.ss[r] = P.scoreS + r*mS; aa.sd[r] = P.scoreD + r*mS;
        aa.ip[r] = P.indptr[r]; aa.es[r] = P.esrc[r];
        aa.al[r] = P.alpha + (size_t)r*E*4;
        aa.nd[r] = nOf[DST_T[r]]; aa.ns[r] = nTx;
        if (aa.nd[r] > ndMax) ndMax = aa.nd[r];
      }
      k_alpha3b<<<dim3((ndMax+3)/4,3), b256, 0, stream>>>(aa, E);
    }
    // r=2 (tx->mer): aggregate-FIRST; 4 head-GEMMs in one z=4 launch
    {
      BF16* Gm = P.blkB;
      if (Din == 512)
        k_gather4<8><<<dim3((nMer+3)/4), b256, 0, stream>>>(P.A[0], P.alpha + (size_t)2*E*4,
            P.indptr[2], P.esrc[2], Gm, nMer, Din, E, nTx);
      else
        k_gather4<2><<<dim3((nMer+3)/4), b256, 0, stream>>>(P.A[0], P.alpha + (size_t)2*E*4,
            P.indptr[2], P.esrc[2], Gm, nMer, Din, E, nTx);
      k_mfma<128,2,2,4,4,BF16><<<dim3(1,(nMer+127)/128,4), b256, 0, stream>>>(
          Gm, Wtof(2), P.Bst[2], nMer, Din, 0, 512, 4*Din,
          (const float*)nullptr, 0, 0, (long)Din, 128L, 128, (const BF16*)nullptr);
    }
    // r=0,1 (tx->acc): z=2 pair GEMM + fused agg2
    {
      BF16* Zr0 = P.Zt;
      BF16* Zr1 = P.blkB;          // G_mer dead by now
      long zst = (long)(Zr1 - Zr0);
      for (int t = 0; t < nTiles; ++t){
        int c0 = t*TW;
        mfma_pair(P.A[0], Wtof(0), Wtof(1), Zr0, zst, nTx, Din, c0);
        dim3 ga((nAcc+3)/4);
        if (NJv == 2)
          k_agg2<2><<<ga,b256,0,stream>>>(Zr0, Zr1, P.alpha, P.alpha + (size_t)E*4,
              P.indptr[0], P.indptr[1], P.esrc[0], P.esrc[1],
              P.Bst[1], 512, c0, TW, c0>>7, nAcc, E, nTx, nTx);
        else
          k_agg2<1><<<ga,b256,0,stream>>>(Zr0, Zr1, P.alpha, P.alpha + (size_t)E*4,
              P.indptr[0], P.indptr[1], P.esrc[0], P.esrc[1],
              P.Bst[1], 512, c0, TW, c0>>7, nAcc, E, nTx, nTx);
      }
    }

    // ---- Phase 2 (dst=tx; src=acc r=3,4; mer r=5) ----
    k_scoreM<2><<<dim3((nAcc+15)/16), b256, 0, stream>>>(P.A[1], P.Fbuf + 24*Din, fstr, P.scoreS, mS, nAcc, Din);
    k_scoreM<1><<<dim3((nMer+15)/16), b256, 0, stream>>>(P.A[2], P.Fbuf + 40*Din, fstr, P.scoreS + 2*mS, 0, nMer, Din);
    k_scoreM<3><<<dim3((nTx+15)/16), b256, 0, stream>>>(P.A[0], P.Fbuf + 28*Din, fstr, P.scoreD, mS, nTx, Din);
    {
      AlphaArgs aa{};
      for (int q = 0; q < 3; ++q){
        int r = 3 + q;
        aa.ss[q] = P.scoreS + q*mS; aa.sd[q] = P.scoreD + q*mS;
        aa.ip[q] = P.indptr[r]; aa.es[q] = P.esrc[r];
        aa.al[q] = P.alpha + (size_t)q*E*4;
        aa.nd[q] = nTx; aa.ns[q] = nOf[SRC_T[r]];
      }
      k_alpha3b<<<dim3((nTx+3)/4,3), b256, 0, stream>>>(aa, E);
    }
    BF16* Z3 = P.Zt;
    BF16* Z4 = P.Zt + (size_t)nAcc*TW;
    BF16* Z5 = P.Zt + (size_t)2*nAcc*TW;
    BF16* nw = P.blkB;
    for (int t = 0; t < nTiles; ++t){
      int c0 = t*TW;
      mfma_pair(P.A[1], Wtof(3), Wtof(4), Z3, (long)nAcc*TW, nAcc, Din, c0);
      mfma_gemm(P.A[2], Wtof(5), Z5, nMer, Din, c0, TW);
      dim3 ga((nTx+3)/4);
      if (NJv == 2)
        k_agg3<2><<<ga,b256,0,stream>>>(Z3,Z4,Z5, P.alpha, P.alpha+(size_t)E*4, P.alpha+(size_t)2*E*4,
            P.indptr[3],P.indptr[4],P.indptr[5], P.esrc[3],P.esrc[4],P.esrc[5],
            nw, TW, TW, c0>>7, nTx, E, nAcc, nAcc, nMer);
      else
        k_agg3<1><<<ga,b256,0,stream>>>(Z3,Z4,Z5, P.alpha, P.alpha+(size_t)E*4, P.alpha+(size_t)2*E*4,
            P.indptr[3],P.indptr[4],P.indptr[5], P.esrc[3],P.esrc[4],P.esrc[5],
            nw, TW, TW, c0>>7, nTx, E, nAcc, nAcc, nMer);
      k_bnp<<<dim3(PBX), b256, 0, stream>>>(nw, P.bnp, nTx, TW, Pp);
      k_bnf<<<dim3((2*TW+255)/256), b256, 0, stream>>>(P.bnp, P.bns, Pp, TW);
      k_bn_apply<<<dim3(2048), b256, 0, stream>>>(nw, P.bns,
          bn_g + (size_t)i*512, bn_b + (size_t)i*512, P.A[0], nTx, TW, c0, res);
    }
    // ---- Phase 3 ----
    const float* ab0 = att_b + ((size_t)(i*6 + 0))*512;
    const float* ab1 = att_b + ((size_t)(i*6 + 1))*512;
    const float* ab2 = att_b + ((size_t)(i*6 + 2))*512;
    k_update<<<dim3(1024), b256, 0, stream>>>(P.Bst[1], ab0, ab1, P.A[1], (long)nAcc*512, res);
    k_update<<<dim3(128),  b256, 0, stream>>>(P.Bst[2], ab2, (const float*)nullptr, P.A[2], (long)nMer*512, res);
  }

  // ---- 4. head ----
  k_mfma<64,4,1,2,4,BF16><<<dim3(1,(nTx+127)/128,1), b256, 0, stream>>>(
      P.A[0], P.Wh1t, P.hidden, nTx, 512, 0, 64, 512, bh1, 1, 0,
      0L, 0L, 0, (const BF16*)nullptr);
  k_logits<<<dim3((nTx+3)/4), b256, 0, stream>>>(P.hidden, Wh2, bh2, (float*)d_out, nTx);
}